// Round 1
// baseline (1325.234 us; speedup 1.0000x reference)
//
#include <hip/hip_runtime.h>
#include <stdint.h>

// Problem constants (fixed shapes from reference)
#define B_ 8
#define L_ 512
#define D_ 1024
#define H_ 16
#define HD_ 64
#define BH_ (B_*H_)      // 128
#define NR_ (B_*L_)      // 4096 rows
#define ALPHA_ 0.02f

typedef unsigned int u32;
typedef unsigned short u16;

__device__ __forceinline__ u32 f2bf_rne(float f) {
    u32 x = __float_as_uint(f);
    return (x + 0x7fffu + ((x >> 16) & 1u)) >> 16;
}
__device__ __forceinline__ float bf_lo(u32 u) { return __uint_as_float(u << 16); }
__device__ __forceinline__ float bf_hi(u32 u) { return __uint_as_float(u & 0xffff0000u); }

// ---------------------------------------------------------------------------
// Generic 128x128 tiled fp32 GEMM with bias: C = A(MxK) @ W(KxN) + b
// Supports up to 3 weight sets in one launch (QKV fused) via blockIdx.y.
// ---------------------------------------------------------------------------
__global__ __launch_bounds__(256) void gemm_bias_multi(
    const float* __restrict__ A,
    const float* __restrict__ W0, const float* __restrict__ bias0,
    const float* __restrict__ W1, const float* __restrict__ bias1,
    const float* __restrict__ W2, const float* __restrict__ bias2,
    float* __restrict__ C0, float* __restrict__ C1, float* __restrict__ C2,
    int M, int N, int K)
{
    __shared__ float As[16][128];   // As[k][m]
    __shared__ float Bs[16][128];   // Bs[k][n]

    const int nb = N >> 7;
    const int which = blockIdx.y / nb;
    const int bn = blockIdx.y % nb;
    const int bm = blockIdx.x;
    const float* Wm   = (which == 0) ? W0 : (which == 1 ? W1 : W2);
    const float* bias = (which == 0) ? bias0 : (which == 1 ? bias1 : bias2);
    float* C          = (which == 0) ? C0 : (which == 1 ? C1 : C2);

    const int t  = threadIdx.x;
    const int tx = t & 15, ty = t >> 4;

    const int ar = t >> 2;          // 0..63
    const int ac = (t & 3) << 2;    // 0,4,8,12
    const int br = t >> 4;          // 0..15
    const int bc = (t & 15) << 2;   // 0..60

    float acc[8][8];
    #pragma unroll
    for (int i = 0; i < 8; ++i)
        #pragma unroll
        for (int j = 0; j < 8; ++j) acc[i][j] = 0.f;

    const int row0 = bm * 128, col0 = bn * 128;
    for (int kt = 0; kt < K; kt += 16) {
        #pragma unroll
        for (int rr = 0; rr < 2; ++rr) {
            int r = ar + rr * 64;
            float4 v = *(const float4*)&A[(size_t)(row0 + r) * K + kt + ac];
            As[ac + 0][r] = v.x; As[ac + 1][r] = v.y;
            As[ac + 2][r] = v.z; As[ac + 3][r] = v.w;
        }
        #pragma unroll
        for (int cc = 0; cc < 2; ++cc) {
            int c = bc + cc * 64;
            float4 v = *(const float4*)&Wm[(size_t)(kt + br) * N + col0 + c];
            *(float4*)&Bs[br][c] = v;
        }
        __syncthreads();
        #pragma unroll
        for (int kk = 0; kk < 16; ++kk) {
            float4 a0 = *(const float4*)&As[kk][ty * 8];
            float4 a1 = *(const float4*)&As[kk][ty * 8 + 4];
            float4 b0 = *(const float4*)&Bs[kk][tx * 8];
            float4 b1 = *(const float4*)&Bs[kk][tx * 8 + 4];
            float a[8] = {a0.x,a0.y,a0.z,a0.w,a1.x,a1.y,a1.z,a1.w};
            float b[8] = {b0.x,b0.y,b0.z,b0.w,b1.x,b1.y,b1.z,b1.w};
            #pragma unroll
            for (int i = 0; i < 8; ++i)
                #pragma unroll
                for (int j = 0; j < 8; ++j)
                    acc[i][j] = fmaf(a[i], b[j], acc[i][j]);
        }
        __syncthreads();
    }
    #pragma unroll
    for (int i = 0; i < 8; ++i) {
        size_t row = (size_t)(row0 + ty * 8 + i);
        float* crow = C + row * (size_t)N + col0 + tx * 8;
        #pragma unroll
        for (int j = 0; j < 8; ++j) crow[j] = acc[i][j] + bias[col0 + tx * 8 + j];
    }
}

// ---------------------------------------------------------------------------
// 1/max(||K_row||,eps) per (b,h,l)
// ---------------------------------------------------------------------------
__global__ __launch_bounds__(256) void knorm_kernel(
    const float* __restrict__ K, float* __restrict__ rnorm)
{
    int tid = blockIdx.x * 256 + threadIdx.x;       // 65536 = B*H*L
    int l = tid & 511;
    int h = (tid >> 9) & 15;
    int b = tid >> 13;
    const float4* row = (const float4*)(K + ((size_t)(b * 512 + l)) * 1024 + h * 64);
    float s = 0.f;
    #pragma unroll
    for (int i = 0; i < 16; ++i) {
        float4 v = row[i];
        s += v.x * v.x + v.y * v.y + v.z * v.z + v.w * v.w;
    }
    rnorm[tid] = 1.f / fmaxf(sqrtf(s), 1e-6f);
}

// ---------------------------------------------------------------------------
// Dense per-head V + W accumulator init: W = (1-alpha)*V
// ---------------------------------------------------------------------------
__global__ __launch_bounds__(256) void gather_v_winit(
    const float* __restrict__ V, float* __restrict__ Vd, float* __restrict__ Wacc)
{
    size_t tid = (size_t)blockIdx.x * 256 + threadIdx.x;   // 4M
    int d  = tid & 63;
    int l  = (tid >> 6) & 511;
    int bh = (int)(tid >> 15);
    int b = bh >> 4, h = bh & 15;
    float v = V[((size_t)(b * 512 + l)) * 1024 + h * 64 + d];
    Vd[tid] = v;
    Wacc[tid] = (1.0f - ALPHA_) * v;
}

// ---------------------------------------------------------------------------
// P[bh] = softmax(cos-sim(K,K)/8) * (1-eps) + eps/512, stored bf16.
// Block: one (b,h), 64 rows. K head staged in LDS as bf16 pairs, 33-uint rows
// (pad => bank = (row + u) % 32, conflict-free).
// ---------------------------------------------------------------------------
__global__ __launch_bounds__(256) void build_p_kernel(
    const float* __restrict__ Kg, const float* __restrict__ rnorm,
    u16* __restrict__ P)
{
    __shared__ u32 Ksh[512 * 33];
    __shared__ float fsh[512];
    const int bh = blockIdx.x;
    const int b = bh >> 4, h = bh & 15;
    const int r0 = blockIdx.y * 64;
    const int t = threadIdx.x;

    {
        const int c4 = (t & 15) << 2;
        const int uc = c4 >> 1;
        for (int it = 0; it < 32; ++it) {
            int j = it * 16 + (t >> 4);
            float4 v = *(const float4*)&Kg[((size_t)(b * 512 + j)) * 1024 + h * 64 + c4];
            Ksh[j * 33 + uc]     = f2bf_rne(v.x) | (f2bf_rne(v.y) << 16);
            Ksh[j * 33 + uc + 1] = f2bf_rne(v.z) | (f2bf_rne(v.w) << 16);
        }
        fsh[t] = rnorm[bh * 512 + t];
        fsh[t + 256] = rnorm[bh * 512 + t + 256];
    }
    __syncthreads();

    const int wave = t >> 6, lane = t & 63;
    for (int rr = 0; rr < 16; ++rr) {
        const int r = r0 + wave * 16 + rr;
        const float fr = fsh[r];
        float s[8];
        {
            float acc[8] = {0,0,0,0,0,0,0,0};
            const u32* arp = &Ksh[r * 33];
            #pragma unroll 8
            for (int u = 0; u < 32; ++u) {
                u32 av = arp[u];
                float alo = bf_lo(av), ahi = bf_hi(av);
                #pragma unroll
                for (int jj = 0; jj < 8; ++jj) {
                    u32 bv = Ksh[(jj * 64 + lane) * 33 + u];
                    acc[jj] = fmaf(alo, bf_lo(bv), acc[jj]);
                    acc[jj] = fmaf(ahi, bf_hi(bv), acc[jj]);
                }
            }
            #pragma unroll
            for (int jj = 0; jj < 8; ++jj)
                s[jj] = acc[jj] * fr * fsh[jj * 64 + lane] * 0.125f;
        }
        float m = s[0];
        #pragma unroll
        for (int jj = 1; jj < 8; ++jj) m = fmaxf(m, s[jj]);
        #pragma unroll
        for (int off = 1; off < 64; off <<= 1) m = fmaxf(m, __shfl_xor(m, off));
        float sum = 0.f;
        #pragma unroll
        for (int jj = 0; jj < 8; ++jj) { s[jj] = __expf(s[jj] - m); sum += s[jj]; }
        #pragma unroll
        for (int off = 1; off < 64; off <<= 1) sum += __shfl_xor(sum, off);
        const float inv = (1.0f - 1e-6f) / sum;
        u16* prow = P + ((size_t)bh * 512 + r) * 512;
        #pragma unroll
        for (int jj = 0; jj < 8; ++jj) {
            float p = s[jj] * inv + (1e-6f / 512.0f);
            prow[jj * 64 + lane] = (u16)f2bf_rne(p);
        }
    }
}

// ---------------------------------------------------------------------------
// Tout[bh] = P[bh](512x512,bf16) @ Tin[bh](512x64,f32); Wacc += coef*Tout
// ---------------------------------------------------------------------------
__global__ __launch_bounds__(256) void chain_kernel(
    const u16* __restrict__ P, const float* __restrict__ Tin,
    float* __restrict__ Tout, float* __restrict__ Wacc, float coef)
{
    __shared__ u32 Psh[64 * 33];
    __shared__ float Ts[64 * 65];
    const int bh = blockIdx.x;
    const int r0 = blockIdx.y * 64;
    const int t = threadIdx.x;
    const int tx = t & 15, ty = t >> 4;

    float acc[4][4];
    #pragma unroll
    for (int i = 0; i < 4; ++i)
        #pragma unroll
        for (int j = 0; j < 4; ++j) acc[i][j] = 0.f;

    const u16* Pbase = P + ((size_t)bh * 512 + r0) * 512;
    const float* Tbase = Tin + (size_t)bh * 512 * 64;

    for (int kt = 0; kt < 512; kt += 64) {
        {
            int r = t >> 2;
            int uu = (t & 3) * 8;
            const u32* src = (const u32*)(Pbase + (size_t)r * 512 + kt);
            uint4 q0 = ((const uint4*)src)[(t & 3) * 2];
            uint4 q1 = ((const uint4*)src)[(t & 3) * 2 + 1];
            u32* dst = &Psh[r * 33 + uu];
            dst[0] = q0.x; dst[1] = q0.y; dst[2] = q0.z; dst[3] = q0.w;
            dst[4] = q1.x; dst[5] = q1.y; dst[6] = q1.z; dst[7] = q1.w;
        }
        #pragma unroll
        for (int it = 0; it < 4; ++it) {
            int jr = it * 16 + (t >> 4);
            int c4 = (t & 15) << 2;
            float4 v = *(const float4*)&Tbase[(size_t)(kt + jr) * 64 + c4];
            *(float4*)&Ts[jr * 65 + c4] = v;
        }
        __syncthreads();
        #pragma unroll 4
        for (int kk = 0; kk < 64; kk += 2) {
            u32 pv[4];
            #pragma unroll
            for (int i = 0; i < 4; ++i) pv[i] = Psh[(ty * 4 + i) * 33 + (kk >> 1)];
            #pragma unroll
            for (int half = 0; half < 2; ++half) {
                const float* ts = &Ts[(kk + half) * 65 + tx * 4];
                float b0 = ts[0], b1 = ts[1], b2 = ts[2], b3 = ts[3];
                #pragma unroll
                for (int i = 0; i < 4; ++i) {
                    float a = half ? bf_hi(pv[i]) : bf_lo(pv[i]);
                    acc[i][0] = fmaf(a, b0, acc[i][0]);
                    acc[i][1] = fmaf(a, b1, acc[i][1]);
                    acc[i][2] = fmaf(a, b2, acc[i][2]);
                    acc[i][3] = fmaf(a, b3, acc[i][3]);
                }
            }
        }
        __syncthreads();
    }
    #pragma unroll
    for (int i = 0; i < 4; ++i) {
        size_t idx = (size_t)bh * 512 * 64 + (size_t)(r0 + ty * 4 + i) * 64 + tx * 4;
        #pragma unroll
        for (int j = 0; j < 4; ++j) {
            float v = acc[i][j];
            Tout[idx + j] = v;
            Wacc[idx + j] += coef * v;
        }
    }
}

// ---------------------------------------------------------------------------
// attn[b,l,h*64+d] = softmax(Q Kᵀ / 8) @ W   (per head; 32 q-rows per block)
// ---------------------------------------------------------------------------
__global__ __launch_bounds__(256) void attn_kernel(
    const float* __restrict__ Q, const float* __restrict__ Kg,
    const float* __restrict__ Wv, float* __restrict__ attn)
{
    __shared__ float S[32 * 513];
    __shared__ float Qs[32 * 65];
    __shared__ float KW[64 * 65];
    const int bh = blockIdx.x;
    const int b = bh >> 4, h = bh & 15;
    const int q0 = blockIdx.y * 32;
    const int t = threadIdx.x;
    const int tx = t & 15, ty = t >> 4;

    {
        int r = t >> 4;
        int c4 = (t & 15) << 2;
        #pragma unroll
        for (int rr = 0; rr < 2; ++rr) {
            float4 v = *(const float4*)&Q[((size_t)(b * 512 + q0 + r + rr * 16)) * 1024 + h * 64 + c4];
            *(float4*)&Qs[(r + rr * 16) * 65 + c4] = v;
        }
    }
    // Phase A: scores
    for (int kt = 0; kt < 512; kt += 64) {
        #pragma unroll
        for (int it = 0; it < 4; ++it) {
            int jr = it * 16 + (t >> 4);
            int c4 = (t & 15) << 2;
            float4 v = *(const float4*)&Kg[((size_t)(b * 512 + kt + jr)) * 1024 + h * 64 + c4];
            *(float4*)&KW[jr * 65 + c4] = v;
        }
        __syncthreads();
        float a2[2][4];
        #pragma unroll
        for (int i = 0; i < 2; ++i)
            #pragma unroll
            for (int jj = 0; jj < 4; ++jj) a2[i][jj] = 0.f;
        #pragma unroll 8
        for (int d = 0; d < 64; ++d) {
            float qa = Qs[(ty * 2 + 0) * 65 + d];
            float qb = Qs[(ty * 2 + 1) * 65 + d];
            #pragma unroll
            for (int jj = 0; jj < 4; ++jj) {
                float kv = KW[(tx * 4 + jj) * 65 + d];
                a2[0][jj] = fmaf(qa, kv, a2[0][jj]);
                a2[1][jj] = fmaf(qb, kv, a2[1][jj]);
            }
        }
        #pragma unroll
        for (int i = 0; i < 2; ++i)
            #pragma unroll
            for (int jj = 0; jj < 4; ++jj)
                S[(ty * 2 + i) * 513 + kt + tx * 4 + jj] = a2[i][jj] * 0.125f;
        __syncthreads();
    }
    // Softmax rows (wave-parallel, 8 elems/lane)
    {
        const int wave = t >> 6, lane = t & 63;
        for (int rr = 0; rr < 8; ++rr) {
            const int r = wave * 8 + rr;
            float s[8];
            #pragma unroll
            for (int jj = 0; jj < 8; ++jj) s[jj] = S[r * 513 + jj * 64 + lane];
            float m = s[0];
            #pragma unroll
            for (int jj = 1; jj < 8; ++jj) m = fmaxf(m, s[jj]);
            #pragma unroll
            for (int off = 1; off < 64; off <<= 1) m = fmaxf(m, __shfl_xor(m, off));
            float sum = 0.f;
            #pragma unroll
            for (int jj = 0; jj < 8; ++jj) { s[jj] = __expf(s[jj] - m); sum += s[jj]; }
            #pragma unroll
            for (int off = 1; off < 64; off <<= 1) sum += __shfl_xor(sum, off);
            const float inv = 1.f / sum;
            #pragma unroll
            for (int jj = 0; jj < 8; ++jj) S[r * 513 + jj * 64 + lane] = s[jj] * inv;
        }
    }
    __syncthreads();
    // Phase B: attn = P0 @ W
    float acc[2][4];
    #pragma unroll
    for (int i = 0; i < 2; ++i)
        #pragma unroll
        for (int jj = 0; jj < 4; ++jj) acc[i][jj] = 0.f;
    const float* Wb = Wv + (size_t)bh * 512 * 64;
    for (int kt = 0; kt < 512; kt += 64) {
        #pragma unroll
        for (int it = 0; it < 4; ++it) {
            int jr = it * 16 + (t >> 4);
            int c4 = (t & 15) << 2;
            *(float4*)&KW[jr * 65 + c4] = *(const float4*)&Wb[(size_t)(kt + jr) * 64 + c4];
        }
        __syncthreads();
        #pragma unroll 8
        for (int k = 0; k < 64; ++k) {
            const float* wp = &KW[k * 65 + tx * 4];
            float w0 = wp[0], w1 = wp[1], w2 = wp[2], w3 = wp[3];
            float pa = S[(ty * 2 + 0) * 513 + kt + k];
            float pb = S[(ty * 2 + 1) * 513 + kt + k];
            acc[0][0] = fmaf(pa, w0, acc[0][0]); acc[0][1] = fmaf(pa, w1, acc[0][1]);
            acc[0][2] = fmaf(pa, w2, acc[0][2]); acc[0][3] = fmaf(pa, w3, acc[0][3]);
            acc[1][0] = fmaf(pb, w0, acc[1][0]); acc[1][1] = fmaf(pb, w1, acc[1][1]);
            acc[1][2] = fmaf(pb, w2, acc[1][2]); acc[1][3] = fmaf(pb, w3, acc[1][3]);
        }
        __syncthreads();
    }
    #pragma unroll
    for (int i = 0; i < 2; ++i) {
        size_t row = (size_t)(b * 512 + q0 + ty * 2 + i);
        float* ap = attn + row * 1024 + h * 64 + tx * 4;
        ap[0] = acc[i][0]; ap[1] = acc[i][1]; ap[2] = acc[i][2]; ap[3] = acc[i][3];
    }
}

// ---------------------------------------------------------------------------
extern "C" void kernel_launch(void* const* d_in, const int* in_sizes, int n_in,
                              void* d_out, int out_size, void* d_ws, size_t ws_size,
                              hipStream_t stream) {
    const float* X  = (const float*)d_in[0];
    const float* Wq = (const float*)d_in[1];
    const float* bq = (const float*)d_in[2];
    const float* Wk = (const float*)d_in[3];
    const float* bk = (const float*)d_in[4];
    const float* Wv = (const float*)d_in[5];
    const float* bv = (const float*)d_in[6];
    const float* Wo = (const float*)d_in[7];
    const float* bo = (const float*)d_in[8];
    float* out = (float*)d_out;

    // workspace layout (~164 MB total)
    char* ws = (char*)d_ws;
    size_t off = 0;
    auto alloc = [&](size_t bytes) -> void* {
        void* p = ws + off;
        off += (bytes + 255) & ~(size_t)255;
        return p;
    };
    const size_t NE = (size_t)NR_ * D_;               // 4,194,304 elems
    float* Q     = (float*)alloc(NE * 4);
    float* K     = (float*)alloc(NE * 4);
    float* V     = (float*)alloc(NE * 4);
    float* rnorm = (float*)alloc((size_t)BH_ * 512 * 4);
    float* Vd    = (float*)alloc(NE * 4);
    float* Wacc  = (float*)alloc(NE * 4);
    float* T1    = (float*)alloc(NE * 4);
    float* T2    = (float*)alloc(NE * 4);
    u16*   P     = (u16*)alloc((size_t)BH_ * 512 * 512 * 2);
    float* attn  = Vd;  // reuse: Vd only needed for chain pass 1

    const float a = ALPHA_;
    const float c1 = a * (1.f - a);
    const float c2 = a * a * (1.f - a);
    const float c3 = a * a * a * (1.f - a);
    const float c4 = a * a * a * a;

    dim3 blk(256);
    // QKV projections (fused launch: blockIdx.y selects weight set)
    gemm_bias_multi<<<dim3(32, 24), blk, 0, stream>>>(X, Wq, bq, Wk, bk, Wv, bv,
                                                      Q, K, V, NR_, D_, D_);
    knorm_kernel<<<dim3(256), blk, 0, stream>>>(K, rnorm);
    gather_v_winit<<<dim3(16384), blk, 0, stream>>>(V, Vd, Wacc);
    build_p_kernel<<<dim3(BH_, 8), blk, 0, stream>>>(K, rnorm, P);
    chain_kernel<<<dim3(BH_, 8), blk, 0, stream>>>(P, Vd, T1, Wacc, c1);
    chain_kernel<<<dim3(BH_, 8), blk, 0, stream>>>(P, T1, T2, Wacc, c2);
    chain_kernel<<<dim3(BH_, 8), blk, 0, stream>>>(P, T2, T1, Wacc, c3);
    chain_kernel<<<dim3(BH_, 8), blk, 0, stream>>>(P, T1, T2, Wacc, c4);
    attn_kernel<<<dim3(BH_, 16), blk, 0, stream>>>(Q, K, Wacc, attn);
    // output projection
    gemm_bias_multi<<<dim3(32, 8), blk, 0, stream>>>(attn, Wo, bo, Wo, bo, Wo, bo,
                                                     out, out, out, NR_, D_, D_);
}

// Round 2
// 667.933 us; speedup vs baseline: 1.9841x; 1.9841x over previous
//
#include <hip/hip_runtime.h>
#include <stdint.h>

#define B_ 8
#define L_ 512
#define D_ 1024
#define H_ 16
#define HD_ 64
#define BH_ (B_*H_)      // 128
#define NR_ (B_*L_)      // 4096 rows
#define ALPHA_ 0.02f
#define PSTR 72          // LDS row stride in u16 (144B = 128+16 -> conflict-free b128)

typedef unsigned int u32;
typedef unsigned short u16;
typedef __attribute__((ext_vector_type(8))) short bf16x8;
typedef __attribute__((ext_vector_type(4))) float f32x4;

#define MFMA16(a, b, c) __builtin_amdgcn_mfma_f32_16x16x32_bf16((a), (b), (c), 0, 0, 0)

__device__ __forceinline__ u32 f2bf_rne(float f) {
    u32 x = __float_as_uint(f);
    return (x + 0x7fffu + ((x >> 16) & 1u)) >> 16;
}
__device__ __forceinline__ float bf_lo(u32 u) { return __uint_as_float(u << 16); }

// split fp32 float4 -> hi/lo bf16 quads, stored as uint2 (4 bf16 = 8B) each
__device__ __forceinline__ void split4_store(float4 v, u16* hp, u16* lp) {
    u32 h0 = f2bf_rne(v.x), h1 = f2bf_rne(v.y), h2 = f2bf_rne(v.z), h3 = f2bf_rne(v.w);
    u32 l0 = f2bf_rne(v.x - bf_lo(h0));
    u32 l1 = f2bf_rne(v.y - bf_lo(h1));
    u32 l2 = f2bf_rne(v.z - bf_lo(h2));
    u32 l3 = f2bf_rne(v.w - bf_lo(h3));
    uint2 hw; hw.x = h0 | (h1 << 16); hw.y = h2 | (h3 << 16);
    uint2 lw; lw.x = l0 | (l1 << 16); lw.y = l2 | (l3 << 16);
    *(uint2*)hp = hw; *(uint2*)lp = lw;
}
__device__ __forceinline__ void pack4_store(float4 v, u16* p) {
    uint2 u;
    u.x = f2bf_rne(v.x) | (f2bf_rne(v.y) << 16);
    u.y = f2bf_rne(v.z) | (f2bf_rne(v.w) << 16);
    *(uint2*)p = u;
}

// ---------------------------------------------------------------------------
// fp32 SIMT GEMM with bias (QKV fused / Wo) -- unchanged from round 1
// ---------------------------------------------------------------------------
__global__ __launch_bounds__(256) void gemm_bias_multi(
    const float* __restrict__ A,
    const float* __restrict__ W0, const float* __restrict__ bias0,
    const float* __restrict__ W1, const float* __restrict__ bias1,
    const float* __restrict__ W2, const float* __restrict__ bias2,
    float* __restrict__ C0, float* __restrict__ C1, float* __restrict__ C2,
    int M, int N, int K)
{
    __shared__ float As[16][128];
    __shared__ float Bs[16][128];

    const int nb = N >> 7;
    const int which = blockIdx.y / nb;
    const int bn = blockIdx.y % nb;
    const int bm = blockIdx.x;
    const float* Wm   = (which == 0) ? W0 : (which == 1 ? W1 : W2);
    const float* bias = (which == 0) ? bias0 : (which == 1 ? bias1 : bias2);
    float* C          = (which == 0) ? C0 : (which == 1 ? C1 : C2);

    const int t  = threadIdx.x;
    const int tx = t & 15, ty = t >> 4;
    const int ar = t >> 2;
    const int ac = (t & 3) << 2;
    const int br = t >> 4;
    const int bc = (t & 15) << 2;

    float acc[8][8];
    #pragma unroll
    for (int i = 0; i < 8; ++i)
        #pragma unroll
        for (int j = 0; j < 8; ++j) acc[i][j] = 0.f;

    const int row0 = bm * 128, col0 = bn * 128;
    for (int kt = 0; kt < K; kt += 16) {
        #pragma unroll
        for (int rr = 0; rr < 2; ++rr) {
            int r = ar + rr * 64;
            float4 v = *(const float4*)&A[(size_t)(row0 + r) * K + kt + ac];
            As[ac + 0][r] = v.x; As[ac + 1][r] = v.y;
            As[ac + 2][r] = v.z; As[ac + 3][r] = v.w;
        }
        #pragma unroll
        for (int cc = 0; cc < 2; ++cc) {
            int c = bc + cc * 64;
            float4 v = *(const float4*)&Wm[(size_t)(kt + br) * N + col0 + c];
            *(float4*)&Bs[br][c] = v;
        }
        __syncthreads();
        #pragma unroll
        for (int kk = 0; kk < 16; ++kk) {
            float4 a0 = *(const float4*)&As[kk][ty * 8];
            float4 a1 = *(const float4*)&As[kk][ty * 8 + 4];
            float4 b0 = *(const float4*)&Bs[kk][tx * 8];
            float4 b1 = *(const float4*)&Bs[kk][tx * 8 + 4];
            float a[8] = {a0.x,a0.y,a0.z,a0.w,a1.x,a1.y,a1.z,a1.w};
            float b[8] = {b0.x,b0.y,b0.z,b0.w,b1.x,b1.y,b1.z,b1.w};
            #pragma unroll
            for (int i = 0; i < 8; ++i)
                #pragma unroll
                for (int j = 0; j < 8; ++j)
                    acc[i][j] = fmaf(a[i], b[j], acc[i][j]);
        }
        __syncthreads();
    }
    #pragma unroll
    for (int i = 0; i < 8; ++i) {
        size_t row = (size_t)(row0 + ty * 8 + i);
        float* crow = C + row * (size_t)N + col0 + tx * 8;
        #pragma unroll
        for (int j = 0; j < 8; ++j) crow[j] = acc[i][j] + bias[col0 + tx * 8 + j];
    }
}

// ---------------------------------------------------------------------------
__global__ __launch_bounds__(256) void knorm_kernel(
    const float* __restrict__ K, float* __restrict__ rnorm)
{
    int tid = blockIdx.x * 256 + threadIdx.x;
    int l = tid & 511;
    int h = (tid >> 9) & 15;
    int b = tid >> 13;
    const float4* row = (const float4*)(K + ((size_t)(b * 512 + l)) * 1024 + h * 64);
    float s = 0.f;
    #pragma unroll
    for (int i = 0; i < 16; ++i) {
        float4 v = row[i];
        s += v.x * v.x + v.y * v.y + v.z * v.z + v.w * v.w;
    }
    rnorm[tid] = 1.f / fmaxf(sqrtf(s), 1e-6f);
}

// ---------------------------------------------------------------------------
// V -> transposed-per-head VdT (bf16) and WaccT (fp32) = (1-alpha)*V
// grid (8 ltiles, 128 bh)
// ---------------------------------------------------------------------------
__global__ __launch_bounds__(256) void gather_vT(
    const float* __restrict__ V, u16* __restrict__ VdT, float* __restrict__ WaccT)
{
    __shared__ float Vs[64 * 69];
    const int bh = blockIdx.y, b = bh >> 4, h = bh & 15;
    const int l0b = blockIdx.x * 64;
    const int t = threadIdx.x;
    {
        const int l = t >> 2, d0 = (t & 3) << 4;
        const float4* src = (const float4*)&V[((size_t)(b * 512 + l0b + l)) * 1024 + h * 64 + d0];
        #pragma unroll
        for (int i = 0; i < 4; ++i) *(float4*)&Vs[l * 69 + d0 + i * 4] = src[i];
    }
    __syncthreads();
    {
        const int d = t >> 2, l0 = (t & 3) << 4;
        float v[16];
        #pragma unroll
        for (int i = 0; i < 16; ++i) v[i] = Vs[(l0 + i) * 69 + d];
        size_t idx = ((size_t)bh * 64 + d) * 512 + l0b + l0;
        #pragma unroll
        for (int i = 0; i < 16; i += 4) {
            uint2 u;
            u.x = f2bf_rne(v[i])   | (f2bf_rne(v[i+1]) << 16);
            u.y = f2bf_rne(v[i+2]) | (f2bf_rne(v[i+3]) << 16);
            *(uint2*)&VdT[idx + i] = u;
            float4 wv;
            wv.x = (1.0f - ALPHA_) * v[i];   wv.y = (1.0f - ALPHA_) * v[i+1];
            wv.z = (1.0f - ALPHA_) * v[i+2]; wv.w = (1.0f - ALPHA_) * v[i+3];
            *(float4*)&WaccT[idx + i] = wv;
        }
    }
}

// ---------------------------------------------------------------------------
// P[bh] = softmax(cos-sim/8)*(1-eps)+eps/512, bf16, via MFMA (two-pass).
// grid (8 qtiles, 128 bh). Swapped layout: S^T[j][i] = mfma(Kn_j, Kn_i).
// ---------------------------------------------------------------------------
__global__ __launch_bounds__(256) void build_p_mfma(
    const float* __restrict__ Kg, const float* __restrict__ rnorm,
    u16* __restrict__ P)
{
    __shared__ u16 Ksh[64 * PSTR];   // j-rows (A operand), restaged per jt
    __shared__ u16 Qsh[64 * PSTR];   // i-rows (B operand), staged once
    const int bh = blockIdx.y, b = bh >> 4, h = bh & 15;
    const int q0 = blockIdx.x * 64;
    const int t = threadIdx.x;
    const int w = t >> 6, lane = t & 63, l15 = lane & 15, g = lane >> 4;

    {
        const int r = t >> 2, d0 = (t & 3) << 4;
        const float rn = rnorm[bh * 512 + q0 + r];
        const float4* src = (const float4*)&Kg[((size_t)(b * 512 + q0 + r)) * 1024 + h * 64 + d0];
        #pragma unroll
        for (int i = 0; i < 4; ++i) {
            float4 v = src[i];
            v.x *= rn; v.y *= rn; v.z *= rn; v.w *= rn;
            pack4_store(v, &Qsh[r * PSTR + d0 + i * 4]);
        }
    }
    __syncthreads();
    bf16x8 qb[2];
    qb[0] = *(const bf16x8*)&Qsh[(w * 16 + l15) * PSTR + 8 * g];
    qb[1] = *(const bf16x8*)&Qsh[(w * 16 + l15) * PSTR + 32 + 8 * g];

    float m_run = -1e30f, l_run = 0.f, inv = 0.f;
    for (int pass = 0; pass < 2; ++pass) {
        if (pass == 1) inv = (1.0f - 1e-6f) / l_run;
        for (int jt = 0; jt < 512; jt += 64) {
            __syncthreads();
            {
                const int r = t >> 2, d0 = (t & 3) << 4;
                const float rn = rnorm[bh * 512 + jt + r];
                const float4* src = (const float4*)&Kg[((size_t)(b * 512 + jt + r)) * 1024 + h * 64 + d0];
                #pragma unroll
                for (int i = 0; i < 4; ++i) {
                    float4 v = src[i];
                    v.x *= rn; v.y *= rn; v.z *= rn; v.w *= rn;
                    pack4_store(v, &Ksh[r * PSTR + d0 + i * 4]);
                }
            }
            __syncthreads();
            f32x4 st[4];
            #pragma unroll
            for (int tk = 0; tk < 4; ++tk) {
                f32x4 acc = {0.f, 0.f, 0.f, 0.f};
                const int krow = tk * 16 + l15;
                #pragma unroll
                for (int c = 0; c < 2; ++c) {
                    bf16x8 ka = *(const bf16x8*)&Ksh[krow * PSTR + c * 32 + 8 * g];
                    acc = MFMA16(ka, qb[c], acc);
                }
                st[tk] = acc;
            }
            if (pass == 0) {
                float mt = st[0][0];
                #pragma unroll
                for (int tk = 0; tk < 4; ++tk)
                    #pragma unroll
                    for (int r = 0; r < 4; ++r) mt = fmaxf(mt, st[tk][r]);
                mt = fmaxf(mt, __shfl_xor(mt, 16));
                mt = fmaxf(mt, __shfl_xor(mt, 32));
                float m_new = fmaxf(m_run, mt);
                float scale = __expf((m_run - m_new) * 0.125f);
                float rsum = 0.f;
                #pragma unroll
                for (int tk = 0; tk < 4; ++tk)
                    #pragma unroll
                    for (int r = 0; r < 4; ++r)
                        rsum += __expf((st[tk][r] - m_new) * 0.125f);
                rsum += __shfl_xor(rsum, 16);
                rsum += __shfl_xor(rsum, 32);
                l_run = l_run * scale + rsum;
                m_run = m_new;
            } else {
                const int i_row = q0 + w * 16 + l15;
                u16* prow = P + ((size_t)bh * 512 + i_row) * 512;
                #pragma unroll
                for (int tk = 0; tk < 4; ++tk) {
                    float p0_ = __expf((st[tk][0] - m_run) * 0.125f) * inv + (1e-6f / 512.0f);
                    float p1_ = __expf((st[tk][1] - m_run) * 0.125f) * inv + (1e-6f / 512.0f);
                    float p2_ = __expf((st[tk][2] - m_run) * 0.125f) * inv + (1e-6f / 512.0f);
                    float p3_ = __expf((st[tk][3] - m_run) * 0.125f) * inv + (1e-6f / 512.0f);
                    uint2 u;
                    u.x = f2bf_rne(p0_) | (f2bf_rne(p1_) << 16);
                    u.y = f2bf_rne(p2_) | (f2bf_rne(p3_) << 16);
                    *(uint2*)&prow[jt + tk * 16 + g * 4] = u;
                }
            }
        }
    }
}

// ---------------------------------------------------------------------------
// ToutT[d][r] = sum_k P[r][k]*TinT[d_k... (Tout = P @ Tin); WaccT += coef*Tout
// grid (8 rtiles, 128 bh). Plain bf16 MFMA.
// ---------------------------------------------------------------------------
__global__ __launch_bounds__(256) void chain_mfma(
    const u16* __restrict__ P, const u16* __restrict__ TinT,
    u16* __restrict__ ToutT, float* __restrict__ WaccT, float coef)
{
    __shared__ u16 Psh[64 * PSTR];
    __shared__ u16 Tsh[64 * PSTR];
    const int bh = blockIdx.y;
    const int r0 = blockIdx.x * 64;
    const int t = threadIdx.x;
    const int w = t >> 6, lane = t & 63, l15 = lane & 15, g = lane >> 4;

    f32x4 O[4] = {{0,0,0,0},{0,0,0,0},{0,0,0,0},{0,0,0,0}};
    const u16* Pbase = P + ((size_t)bh * 512 + r0) * 512;
    const u16* Tbase = TinT + (size_t)bh * 64 * 512;

    for (int kt = 0; kt < 512; kt += 64) {
        __syncthreads();
        {
            const int rr = t >> 2, c = (t & 3) << 4;
            const uint4* ps = (const uint4*)&Pbase[(size_t)rr * 512 + kt + c];
            *(uint4*)&Psh[rr * PSTR + c]     = ps[0];
            *(uint4*)&Psh[rr * PSTR + c + 8] = ps[1];
            const uint4* ts = (const uint4*)&Tbase[(size_t)rr * 512 + kt + c];
            *(uint4*)&Tsh[rr * PSTR + c]     = ts[0];
            *(uint4*)&Tsh[rr * PSTR + c + 8] = ts[1];
        }
        __syncthreads();
        bf16x8 pa[2];
        pa[0] = *(const bf16x8*)&Psh[(w * 16 + l15) * PSTR + 8 * g];
        pa[1] = *(const bf16x8*)&Psh[(w * 16 + l15) * PSTR + 32 + 8 * g];
        #pragma unroll
        for (int td = 0; td < 4; ++td) {
            #pragma unroll
            for (int c = 0; c < 2; ++c) {
                bf16x8 tb = *(const bf16x8*)&Tsh[(td * 16 + l15) * PSTR + c * 32 + 8 * g];
                O[td] = MFMA16(pa[c], tb, O[td]);
            }
        }
    }
    #pragma unroll
    for (int td = 0; td < 4; ++td) {
        const int d = td * 16 + l15;
        const int r = r0 + w * 16 + g * 4;
        size_t idx = ((size_t)bh * 64 + d) * 512 + r;
        float4 wv = *(float4*)&WaccT[idx];
        wv.x += coef * O[td][0]; wv.y += coef * O[td][1];
        wv.z += coef * O[td][2]; wv.w += coef * O[td][3];
        *(float4*)&WaccT[idx] = wv;
        uint2 u;
        u.x = f2bf_rne(O[td][0]) | (f2bf_rne(O[td][1]) << 16);
        u.y = f2bf_rne(O[td][2]) | (f2bf_rne(O[td][3]) << 16);
        *(uint2*)&ToutT[idx] = u;
    }
}

// ---------------------------------------------------------------------------
// attn = softmax(QK^T/8) @ W, flash-style, bf16x3 MFMA (hi/lo split).
// grid (8 qtiles, 128 bh), 4 waves, 16 q-rows per wave, KBLK=64.
// ---------------------------------------------------------------------------
__global__ __launch_bounds__(256) void attn_mfma(
    const float* __restrict__ Q, const float* __restrict__ Kg,
    const float* __restrict__ WT, float* __restrict__ attn)
{
    __shared__ u16 Qh[64 * PSTR], Ql[64 * PSTR];
    __shared__ u16 Kh[64 * PSTR], Kl[64 * PSTR];
    __shared__ u16 Wh[64 * PSTR], Wl[64 * PSTR];
    __shared__ u16 Ph[4][16 * PSTR], Pl[4][16 * PSTR];
    const int bh = blockIdx.y, b = bh >> 4, h = bh & 15;
    const int q0 = blockIdx.x * 64;
    const int t = threadIdx.x;
    const int w = t >> 6, lane = t & 63, l15 = lane & 15, g = lane >> 4;

    {   // stage Q hi/lo (once)
        const int r = t >> 2, d0 = (t & 3) << 4;
        const float4* src = (const float4*)&Q[((size_t)(b * 512 + q0 + r)) * 1024 + h * 64 + d0];
        #pragma unroll
        for (int i = 0; i < 4; ++i)
            split4_store(src[i], &Qh[r * PSTR + d0 + i * 4], &Ql[r * PSTR + d0 + i * 4]);
    }
    __syncthreads();
    bf16x8 qbh[2], qbl[2];
    {
        const int row = (w * 16 + l15) * PSTR;
        qbh[0] = *(const bf16x8*)&Qh[row + 8 * g];
        qbh[1] = *(const bf16x8*)&Qh[row + 32 + 8 * g];
        qbl[0] = *(const bf16x8*)&Ql[row + 8 * g];
        qbl[1] = *(const bf16x8*)&Ql[row + 32 + 8 * g];
    }
    float m_run = -1e30f, l_run = 0.f;
    f32x4 O[4] = {{0,0,0,0},{0,0,0,0},{0,0,0,0},{0,0,0,0}};

    for (int kt = 0; kt < 512; kt += 64) {
        __syncthreads();
        {   // stage K tile + W tile (hi/lo)
            const int r = t >> 2, d0 = (t & 3) << 4;
            const float4* ks = (const float4*)&Kg[((size_t)(b * 512 + kt + r)) * 1024 + h * 64 + d0];
            const float4* wsrc = (const float4*)&WT[((size_t)(bh * 64 + r)) * 512 + kt + d0];
            #pragma unroll
            for (int i = 0; i < 4; ++i) {
                split4_store(ks[i],   &Kh[r * PSTR + d0 + i * 4], &Kl[r * PSTR + d0 + i * 4]);
                split4_store(wsrc[i], &Wh[r * PSTR + d0 + i * 4], &Wl[r * PSTR + d0 + i * 4]);
            }
        }
        __syncthreads();
        // S^T tiles: bf16x3 (Kh*Qh + Kh*Ql + Kl*Qh)
        f32x4 st[4];
        #pragma unroll
        for (int tk = 0; tk < 4; ++tk) {
            f32x4 acc = {0.f, 0.f, 0.f, 0.f};
            const int krow = (tk * 16 + l15) * PSTR;
            #pragma unroll
            for (int c = 0; c < 2; ++c) {
                bf16x8 kah = *(const bf16x8*)&Kh[krow + c * 32 + 8 * g];
                bf16x8 kal = *(const bf16x8*)&Kl[krow + c * 32 + 8 * g];
                acc = MFMA16(kah, qbh[c], acc);
                acc = MFMA16(kah, qbl[c], acc);
                acc = MFMA16(kal, qbh[c], acc);
            }
            st[tk] = acc;
        }
        // online softmax (lane's q = l15)
        float mt = st[0][0];
        #pragma unroll
        for (int tk = 0; tk < 4; ++tk)
            #pragma unroll
            for (int r = 0; r < 4; ++r) mt = fmaxf(mt, st[tk][r]);
        mt = fmaxf(mt, __shfl_xor(mt, 16));
        mt = fmaxf(mt, __shfl_xor(mt, 32));
        const float m_new = fmaxf(m_run, mt);
        const float scale = __expf((m_run - m_new) * 0.125f);
        float rsum = 0.f;
        #pragma unroll
        for (int tk = 0; tk < 4; ++tk) {
            float p0_ = __expf((st[tk][0] - m_new) * 0.125f);
            float p1_ = __expf((st[tk][1] - m_new) * 0.125f);
            float p2_ = __expf((st[tk][2] - m_new) * 0.125f);
            float p3_ = __expf((st[tk][3] - m_new) * 0.125f);
            rsum += p0_ + p1_ + p2_ + p3_;
            u32 h0 = f2bf_rne(p0_), h1 = f2bf_rne(p1_), h2 = f2bf_rne(p2_), h3 = f2bf_rne(p3_);
            uint2 hw; hw.x = h0 | (h1 << 16); hw.y = h2 | (h3 << 16);
            uint2 lw;
            lw.x = f2bf_rne(p0_ - bf_lo(h0)) | (f2bf_rne(p1_ - bf_lo(h1)) << 16);
            lw.y = f2bf_rne(p2_ - bf_lo(h2)) | (f2bf_rne(p3_ - bf_lo(h3)) << 16);
            const int poff = l15 * PSTR + tk * 16 + g * 4;
            *(uint2*)&Ph[w][poff] = hw;
            *(uint2*)&Pl[w][poff] = lw;
        }
        rsum += __shfl_xor(rsum, 16);
        rsum += __shfl_xor(rsum, 32);
        l_run = l_run * scale + rsum;
        m_run = m_new;
        // rescale O (scale lives at lane q=l15; O rows are q=g*4+r)
        float sc[4];
        #pragma unroll
        for (int r = 0; r < 4; ++r) sc[r] = __shfl(scale, g * 4 + r);
        #pragma unroll
        for (int td = 0; td < 4; ++td)
            #pragma unroll
            for (int r = 0; r < 4; ++r) O[td][r] *= sc[r];
        // PV: bf16x3 (Ph*Wh + Ph*Wl + Pl*Wh)
        bf16x8 pah[2], pal[2];
        #pragma unroll
        for (int c = 0; c < 2; ++c) {
            pah[c] = *(const bf16x8*)&Ph[w][l15 * PSTR + c * 32 + 8 * g];
            pal[c] = *(const bf16x8*)&Pl[w][l15 * PSTR + c * 32 + 8 * g];
        }
        #pragma unroll
        for (int td = 0; td < 4; ++td) {
            #pragma unroll
            for (int c = 0; c < 2; ++c) {
                const int wrow = (td * 16 + l15) * PSTR;
                bf16x8 wbh = *(const bf16x8*)&Wh[wrow + c * 32 + 8 * g];
                bf16x8 wbl = *(const bf16x8*)&Wl[wrow + c * 32 + 8 * g];
                O[td] = MFMA16(pah[c], wbh, O[td]);
                O[td] = MFMA16(pah[c], wbl, O[td]);
                O[td] = MFMA16(pal[c], wbh, O[td]);
            }
        }
    }
    // epilogue: O /= l, store
    const float linv = 1.f / l_run;
    float li[4];
    #pragma unroll
    for (int r = 0; r < 4; ++r) li[r] = __shfl(linv, g * 4 + r);
    #pragma unroll
    for (int td = 0; td < 4; ++td)
        #pragma unroll
        for (int r = 0; r < 4; ++r)
            attn[((size_t)(b * 512 + q0 + w * 16 + g * 4 + r)) * 1024 + h * 64 + td * 16 + l15]
                = O[td][r] * li[r];
}

// ---------------------------------------------------------------------------
extern "C" void kernel_launch(void* const* d_in, const int* in_sizes, int n_in,
                              void* d_out, int out_size, void* d_ws, size_t ws_size,
                              hipStream_t stream) {
    const float* X  = (const float*)d_in[0];
    const float* Wq = (const float*)d_in[1];
    const float* bq = (const float*)d_in[2];
    const float* Wk = (const float*)d_in[3];
    const float* bk = (const float*)d_in[4];
    const float* Wv = (const float*)d_in[5];
    const float* bv = (const float*)d_in[6];
    const float* Wo = (const float*)d_in[7];
    const float* bo = (const float*)d_in[8];
    float* out = (float*)d_out;

    char* ws = (char*)d_ws;
    size_t off = 0;
    auto alloc = [&](size_t bytes) -> void* {
        void* p = ws + off;
        off += (bytes + 255) & ~(size_t)255;
        return p;
    };
    const size_t NE = (size_t)NR_ * D_;               // 4,194,304
    const size_t HE = (size_t)BH_ * 64 * 512;         // 4,194,304 (per-head dense)
    float* Q     = (float*)alloc(NE * 4);
    float* K     = (float*)alloc(NE * 4);
    float* V     = (float*)alloc(NE * 4);             // reused as attn buffer
    float* rnorm = (float*)alloc((size_t)BH_ * 512 * 4);
    u16*   VdT   = (u16*)alloc(HE * 2);
    float* WaccT = (float*)alloc(HE * 4);
    u16*   T1T   = (u16*)alloc(HE * 2);
    u16*   T2T   = (u16*)alloc(HE * 2);
    u16*   P     = (u16*)alloc((size_t)BH_ * 512 * 512 * 2);
    float* attnb = V;

    const float a = ALPHA_;
    const float c1 = a * (1.f - a);
    const float c2 = a * a * (1.f - a);
    const float c3 = a * a * a * (1.f - a);
    const float c4 = a * a * a * a;

    dim3 blk(256);
    gemm_bias_multi<<<dim3(32, 24), blk, 0, stream>>>(X, Wq, bq, Wk, bk, Wv, bv,
                                                      Q, K, V, NR_, D_, D_);
    knorm_kernel<<<dim3(256), blk, 0, stream>>>(K, rnorm);
    gather_vT<<<dim3(8, BH_), blk, 0, stream>>>(V, VdT, WaccT);
    build_p_mfma<<<dim3(8, BH_), blk, 0, stream>>>(K, rnorm, P);
    chain_mfma<<<dim3(8, BH_), blk, 0, stream>>>(P, VdT, T1T, WaccT, c1);
    chain_mfma<<<dim3(8, BH_), blk, 0, stream>>>(P, T1T, T2T, WaccT, c2);
    chain_mfma<<<dim3(8, BH_), blk, 0, stream>>>(P, T2T, T1T, WaccT, c3);
    chain_mfma<<<dim3(8, BH_), blk, 0, stream>>>(P, T1T, T2T, WaccT, c4);
    attn_mfma<<<dim3(8, BH_), blk, 0, stream>>>(Q, K, WaccT, attnb);
    gemm_bias_multi<<<dim3(32, 8), blk, 0, stream>>>(attnb, Wo, bo, Wo, bo, Wo, bo,
                                                     out, out, out, NR_, D_, D_);
}

// Round 3
// 374.017 us; speedup vs baseline: 3.5432x; 1.7858x over previous
//
#include <hip/hip_runtime.h>
#include <stdint.h>

#define B_ 8
#define L_ 512
#define D_ 1024
#define H_ 16
#define HD_ 64
#define BH_ (B_*H_)      // 128
#define NR_ (B_*L_)      // 4096 rows
#define ALPHA_ 0.02f
#define PSTR 72          // LDS row stride in u16 (144B -> 2-way-max bank aliasing, free)
#define GSTR 72

typedef unsigned int u32;
typedef unsigned short u16;
typedef __attribute__((ext_vector_type(8))) short bf16x8;
typedef __attribute__((ext_vector_type(4))) float f32x4;

#define MFMA16(a, b, c) __builtin_amdgcn_mfma_f32_16x16x32_bf16((a), (b), (c), 0, 0, 0)

__device__ __forceinline__ u32 f2bf_rne(float f) {
    u32 x = __float_as_uint(f);
    return (x + 0x7fffu + ((x >> 16) & 1u)) >> 16;
}
__device__ __forceinline__ float bf_lo(u32 u) { return __uint_as_float(u << 16); }
__device__ __forceinline__ float bf_hi(u32 u) { return __uint_as_float(u & 0xffff0000u); }

__device__ __forceinline__ void split4_store(float4 v, u16* hp, u16* lp) {
    u32 h0 = f2bf_rne(v.x), h1 = f2bf_rne(v.y), h2 = f2bf_rne(v.z), h3 = f2bf_rne(v.w);
    uint2 hw; hw.x = h0 | (h1 << 16); hw.y = h2 | (h3 << 16);
    uint2 lw;
    lw.x = f2bf_rne(v.x - bf_lo(h0)) | (f2bf_rne(v.y - bf_lo(h1)) << 16);
    lw.y = f2bf_rne(v.z - bf_lo(h2)) | (f2bf_rne(v.w - bf_lo(h3)) << 16);
    *(uint2*)hp = hw; *(uint2*)lp = lw;
}
__device__ __forceinline__ void pack4_store(float4 v, u16* p) {
    uint2 u;
    u.x = f2bf_rne(v.x) | (f2bf_rne(v.y) << 16);
    u.y = f2bf_rne(v.z) | (f2bf_rne(v.w) << 16);
    *(uint2*)p = u;
}
// unpack 8 bf16 pairs (hi array + lo array words) -> 8 reconstructed floats
__device__ __forceinline__ void unpack_add8(uint4 h, uint4 l, float* v) {
    v[0] = bf_lo(h.x) + bf_lo(l.x); v[1] = bf_hi(h.x) + bf_hi(l.x);
    v[2] = bf_lo(h.y) + bf_lo(l.y); v[3] = bf_hi(h.y) + bf_hi(l.y);
    v[4] = bf_lo(h.z) + bf_lo(l.z); v[5] = bf_hi(h.z) + bf_hi(l.z);
    v[6] = bf_lo(h.w) + bf_lo(l.w); v[7] = bf_hi(h.w) + bf_hi(l.w);
}

// ---------------------------------------------------------------------------
// X (fp32) -> Xh/Xl bf16 split, flat
// ---------------------------------------------------------------------------
__global__ __launch_bounds__(256) void split_f32(
    const float* __restrict__ src, u16* __restrict__ dh, u16* __restrict__ dl, int n4)
{
    int i = blockIdx.x * 256 + threadIdx.x;
    if (i < n4) {
        float4 v = ((const float4*)src)[i];
        split4_store(v, &dh[(size_t)i * 4], &dl[(size_t)i * 4]);
    }
}

// ---------------------------------------------------------------------------
// W[k][n] fp32 -> WTh/WTl[w][n][k] bf16 split (transposed). grid (16,16,4)
// ---------------------------------------------------------------------------
__global__ __launch_bounds__(256) void wsplitT(
    const float* __restrict__ W0, const float* __restrict__ W1,
    const float* __restrict__ W2, const float* __restrict__ W3,
    u16* __restrict__ WTh, u16* __restrict__ WTl)
{
    __shared__ float Ws[64][65];
    const int wsel = blockIdx.z;
    const float* W = (wsel == 0) ? W0 : (wsel == 1) ? W1 : (wsel == 2) ? W2 : W3;
    const int k0 = blockIdx.x * 64, n0 = blockIdx.y * 64;
    const int t = threadIdx.x;
    {
        const int r = t >> 2, c0 = (t & 3) << 4;
        #pragma unroll
        for (int i = 0; i < 4; ++i)
            *(float4*)&Ws[r][c0 + i * 4] = *(const float4*)&W[(size_t)(k0 + r) * 1024 + n0 + c0 + i * 4];
    }
    __syncthreads();
    {
        const int n = t >> 2, kc0 = (t & 3) << 4;
        size_t base = ((size_t)wsel << 20) + (size_t)(n0 + n) * 1024 + k0 + kc0;
        #pragma unroll
        for (int j = 0; j < 4; ++j) {
            float4 v;
            v.x = Ws[kc0 + j * 4 + 0][n]; v.y = Ws[kc0 + j * 4 + 1][n];
            v.z = Ws[kc0 + j * 4 + 2][n]; v.w = Ws[kc0 + j * 4 + 3][n];
            split4_store(v, &WTh[base + j * 4], &WTl[base + j * 4]);
        }
    }
}

// ---------------------------------------------------------------------------
// bf16x3 split-precision MFMA GEMM: C = (Ah+Al) @ (Bh+Bl)^T' + bias
// A: [4096][1024] (hi/lo bf16). WT: [nw][1024(n)][1024(k)] (hi/lo bf16).
// 128x128 tile, BK=64, 4 waves (2x2), each wave 64x64.
// write_hl=1: write Ch/Cl bf16 split at weight offset; else Cf fp32.
// ---------------------------------------------------------------------------
__global__ __launch_bounds__(256) void gemm_mfma_x3(
    const u16* __restrict__ Ah, const u16* __restrict__ Al,
    const u16* __restrict__ WTh, const u16* __restrict__ WTl,
    const float* __restrict__ b0, const float* __restrict__ b1, const float* __restrict__ b2,
    float* __restrict__ Cf, u16* __restrict__ Ch, u16* __restrict__ Cl_,
    int write_hl)
{
    __shared__ u16 Ash[128 * GSTR], Als[128 * GSTR];
    __shared__ u16 Bsh[128 * GSTR], Bls[128 * GSTR];
    const int bm = blockIdx.x;
    const int which = blockIdx.y >> 3;
    const int bn = blockIdx.y & 7;
    const float* bias = (which == 0) ? b0 : (which == 1) ? b1 : b2;
    const int t = threadIdx.x;
    const int w = t >> 6, lane = t & 63, l15 = lane & 15, g = lane >> 4;
    const int wr = w >> 1, wc = w & 1;
    const int row0 = bm * 128, col0 = bn * 128;
    const u16* Bh_g = WTh + ((size_t)which << 20);
    const u16* Bl_g = WTl + ((size_t)which << 20);

    f32x4 acc[4][4];
    #pragma unroll
    for (int i = 0; i < 4; ++i)
        #pragma unroll
        for (int j = 0; j < 4; ++j) acc[i][j] = (f32x4){0.f, 0.f, 0.f, 0.f};

    for (int kt = 0; kt < 1024; kt += 64) {
        __syncthreads();
        #pragma unroll
        for (int i = 0; i < 4; ++i) {
            const int ci = t + i * 256;             // 0..1023
            const int r = ci >> 3, c8 = (ci & 7) * 8;
            const size_t ga = (size_t)(row0 + r) * 1024 + kt + c8;
            const size_t gb = (size_t)(col0 + r) * 1024 + kt + c8;
            *(uint4*)&Ash[r * GSTR + c8] = *(const uint4*)&Ah[ga];
            *(uint4*)&Als[r * GSTR + c8] = *(const uint4*)&Al[ga];
            *(uint4*)&Bsh[r * GSTR + c8] = *(const uint4*)&Bh_g[gb];
            *(uint4*)&Bls[r * GSTR + c8] = *(const uint4*)&Bl_g[gb];
        }
        __syncthreads();
        #pragma unroll
        for (int c = 0; c < 2; ++c) {
            bf16x8 ah[4], al[4], bh[4], bl[4];
            #pragma unroll
            for (int mf = 0; mf < 4; ++mf) {
                const int ro = (wr * 64 + mf * 16 + l15) * GSTR + c * 32 + g * 8;
                ah[mf] = *(const bf16x8*)&Ash[ro];
                al[mf] = *(const bf16x8*)&Als[ro];
            }
            #pragma unroll
            for (int nf = 0; nf < 4; ++nf) {
                const int ro = (wc * 64 + nf * 16 + l15) * GSTR + c * 32 + g * 8;
                bh[nf] = *(const bf16x8*)&Bsh[ro];
                bl[nf] = *(const bf16x8*)&Bls[ro];
            }
            #pragma unroll
            for (int mf = 0; mf < 4; ++mf)
                #pragma unroll
                for (int nf = 0; nf < 4; ++nf) {
                    acc[mf][nf] = MFMA16(ah[mf], bh[nf], acc[mf][nf]);
                    acc[mf][nf] = MFMA16(al[mf], bh[nf], acc[mf][nf]);
                    acc[mf][nf] = MFMA16(ah[mf], bl[nf], acc[mf][nf]);
                }
        }
    }
    #pragma unroll
    for (int mf = 0; mf < 4; ++mf)
        #pragma unroll
        for (int nf = 0; nf < 4; ++nf) {
            const int n = col0 + wc * 64 + nf * 16 + l15;
            const float bv = bias[n];
            #pragma unroll
            for (int r = 0; r < 4; ++r) {
                const int m = row0 + wr * 64 + mf * 16 + g * 4 + r;
                const float v = acc[mf][nf][r] + bv;
                if (write_hl) {
                    const size_t idx = ((size_t)which << 22) + (size_t)m * 1024 + n;
                    const u32 hh = f2bf_rne(v);
                    Ch[idx]  = (u16)hh;
                    Cl_[idx] = (u16)f2bf_rne(v - bf_lo(hh));
                } else {
                    Cf[(size_t)m * 1024 + n] = v;
                }
            }
        }
}

// ---------------------------------------------------------------------------
// 1/max(||K_row||,eps) from split K
// ---------------------------------------------------------------------------
__global__ __launch_bounds__(256) void knorm_kernel(
    const u16* __restrict__ Kh, const u16* __restrict__ Kl, float* __restrict__ rnorm)
{
    int tid = blockIdx.x * 256 + threadIdx.x;
    int l = tid & 511;
    int h = (tid >> 9) & 15;
    int b = tid >> 13;
    const size_t base = ((size_t)(b * 512 + l)) * 1024 + h * 64;
    float s = 0.f;
    #pragma unroll
    for (int i = 0; i < 8; ++i) {
        uint4 hv = *(const uint4*)&Kh[base + i * 8];
        uint4 lv = *(const uint4*)&Kl[base + i * 8];
        float v[8];
        unpack_add8(hv, lv, v);
        #pragma unroll
        for (int j = 0; j < 8; ++j) s += v[j] * v[j];
    }
    rnorm[tid] = 1.f / fmaxf(sqrtf(s), 1e-6f);
}

// ---------------------------------------------------------------------------
// V(split) -> transposed-per-head VdT (bf16) and WaccT (fp32) = (1-alpha)*V
// ---------------------------------------------------------------------------
__global__ __launch_bounds__(256) void gather_vT(
    const u16* __restrict__ Vh, const u16* __restrict__ Vl,
    u16* __restrict__ VdT, float* __restrict__ WaccT)
{
    __shared__ float Vs[64 * 69];
    const int bh = blockIdx.y, b = bh >> 4, h = bh & 15;
    const int l0b = blockIdx.x * 64;
    const int t = threadIdx.x;
    {
        const int l = t >> 2, d0 = (t & 3) << 4;
        const size_t gv = ((size_t)(b * 512 + l0b + l)) * 1024 + h * 64 + d0;
        #pragma unroll
        for (int i = 0; i < 2; ++i) {
            uint4 hv = *(const uint4*)&Vh[gv + i * 8];
            uint4 lv = *(const uint4*)&Vl[gv + i * 8];
            float v[8];
            unpack_add8(hv, lv, v);
            #pragma unroll
            for (int j = 0; j < 8; ++j) Vs[l * 69 + d0 + i * 8 + j] = v[j];
        }
    }
    __syncthreads();
    {
        const int d = t >> 2, l0 = (t & 3) << 4;
        float v[16];
        #pragma unroll
        for (int i = 0; i < 16; ++i) v[i] = Vs[(l0 + i) * 69 + d];
        size_t idx = ((size_t)bh * 64 + d) * 512 + l0b + l0;
        #pragma unroll
        for (int i = 0; i < 16; i += 4) {
            uint2 u;
            u.x = f2bf_rne(v[i])   | (f2bf_rne(v[i+1]) << 16);
            u.y = f2bf_rne(v[i+2]) | (f2bf_rne(v[i+3]) << 16);
            *(uint2*)&VdT[idx + i] = u;
            float4 wv;
            wv.x = (1.0f - ALPHA_) * v[i];   wv.y = (1.0f - ALPHA_) * v[i+1];
            wv.z = (1.0f - ALPHA_) * v[i+2]; wv.w = (1.0f - ALPHA_) * v[i+3];
            *(float4*)&WaccT[idx + i] = wv;
        }
    }
}

// ---------------------------------------------------------------------------
// P = softmax(cos-sim/8)*(1-eps)+eps/512, bf16, MFMA two-pass (K from split).
// ---------------------------------------------------------------------------
__global__ __launch_bounds__(256) void build_p_mfma(
    const u16* __restrict__ Kh_g, const u16* __restrict__ Kl_g,
    const float* __restrict__ rnorm, u16* __restrict__ P)
{
    __shared__ u16 Ksh[64 * PSTR];
    __shared__ u16 Qsh[64 * PSTR];
    const int bh = blockIdx.y, b = bh >> 4, h = bh & 15;
    const int q0 = blockIdx.x * 64;
    const int t = threadIdx.x;
    const int w = t >> 6, lane = t & 63, l15 = lane & 15, g = lane >> 4;

    {
        const int r = t >> 2, d0 = (t & 3) << 4;
        const float rn = rnorm[bh * 512 + q0 + r];
        const size_t gk = ((size_t)(b * 512 + q0 + r)) * 1024 + h * 64 + d0;
        #pragma unroll
        for (int i = 0; i < 2; ++i) {
            uint4 hv = *(const uint4*)&Kh_g[gk + i * 8];
            uint4 lv = *(const uint4*)&Kl_g[gk + i * 8];
            float v[8];
            unpack_add8(hv, lv, v);
            float4 v0 = {v[0]*rn, v[1]*rn, v[2]*rn, v[3]*rn};
            float4 v1 = {v[4]*rn, v[5]*rn, v[6]*rn, v[7]*rn};
            pack4_store(v0, &Qsh[r * PSTR + d0 + i * 8]);
            pack4_store(v1, &Qsh[r * PSTR + d0 + i * 8 + 4]);
        }
    }
    __syncthreads();
    bf16x8 qb[2];
    qb[0] = *(const bf16x8*)&Qsh[(w * 16 + l15) * PSTR + 8 * g];
    qb[1] = *(const bf16x8*)&Qsh[(w * 16 + l15) * PSTR + 32 + 8 * g];

    float m_run = -1e30f, l_run = 0.f, inv = 0.f;
    for (int pass = 0; pass < 2; ++pass) {
        if (pass == 1) inv = (1.0f - 1e-6f) / l_run;
        for (int jt = 0; jt < 512; jt += 64) {
            __syncthreads();
            {
                const int r = t >> 2, d0 = (t & 3) << 4;
                const float rn = rnorm[bh * 512 + jt + r];
                const size_t gk = ((size_t)(b * 512 + jt + r)) * 1024 + h * 64 + d0;
                #pragma unroll
                for (int i = 0; i < 2; ++i) {
                    uint4 hv = *(const uint4*)&Kh_g[gk + i * 8];
                    uint4 lv = *(const uint4*)&Kl_g[gk + i * 8];
                    float v[8];
                    unpack_add8(hv, lv, v);
                    float4 v0 = {v[0]*rn, v[1]*rn, v[2]*rn, v[3]*rn};
                    float4 v1 = {v[4]*rn, v[5]*rn, v[6]*rn, v[7]*rn};
                    pack4_store(v0, &Ksh[r * PSTR + d0 + i * 8]);
                    pack4_store(v1, &Ksh[r * PSTR + d0 + i * 8 + 4]);
                }
            }
            __syncthreads();
            f32x4 st[4];
            #pragma unroll
            for (int tk = 0; tk < 4; ++tk) {
                f32x4 a = {0.f, 0.f, 0.f, 0.f};
                const int krow = tk * 16 + l15;
                #pragma unroll
                for (int c = 0; c < 2; ++c) {
                    bf16x8 ka = *(const bf16x8*)&Ksh[krow * PSTR + c * 32 + 8 * g];
                    a = MFMA16(ka, qb[c], a);
                }
                st[tk] = a;
            }
            if (pass == 0) {
                float mt = st[0][0];
                #pragma unroll
                for (int tk = 0; tk < 4; ++tk)
                    #pragma unroll
                    for (int r = 0; r < 4; ++r) mt = fmaxf(mt, st[tk][r]);
                mt = fmaxf(mt, __shfl_xor(mt, 16));
                mt = fmaxf(mt, __shfl_xor(mt, 32));
                float m_new = fmaxf(m_run, mt);
                float scale = __expf((m_run - m_new) * 0.125f);
                float rsum = 0.f;
                #pragma unroll
                for (int tk = 0; tk < 4; ++tk)
                    #pragma unroll
                    for (int r = 0; r < 4; ++r)
                        rsum += __expf((st[tk][r] - m_new) * 0.125f);
                rsum += __shfl_xor(rsum, 16);
                rsum += __shfl_xor(rsum, 32);
                l_run = l_run * scale + rsum;
                m_run = m_new;
            } else {
                const int i_row = q0 + w * 16 + l15;
                u16* prow = P + ((size_t)bh * 512 + i_row) * 512;
                #pragma unroll
                for (int tk = 0; tk < 4; ++tk) {
                    float p0_ = __expf((st[tk][0] - m_run) * 0.125f) * inv + (1e-6f / 512.0f);
                    float p1_ = __expf((st[tk][1] - m_run) * 0.125f) * inv + (1e-6f / 512.0f);
                    float p2_ = __expf((st[tk][2] - m_run) * 0.125f) * inv + (1e-6f / 512.0f);
                    float p3_ = __expf((st[tk][3] - m_run) * 0.125f) * inv + (1e-6f / 512.0f);
                    uint2 u;
                    u.x = f2bf_rne(p0_) | (f2bf_rne(p1_) << 16);
                    u.y = f2bf_rne(p2_) | (f2bf_rne(p3_) << 16);
                    *(uint2*)&prow[jt + tk * 16 + g * 4] = u;
                }
            }
        }
    }
}

// ---------------------------------------------------------------------------
// ToutT = (P @ Tin)^T per head; WaccT += coef*Tout. Plain bf16 MFMA.
// ---------------------------------------------------------------------------
__global__ __launch_bounds__(256) void chain_mfma(
    const u16* __restrict__ P, const u16* __restrict__ TinT,
    u16* __restrict__ ToutT, float* __restrict__ WaccT, float coef)
{
    __shared__ u16 Psh[64 * PSTR];
    __shared__ u16 Tsh[64 * PSTR];
    const int bh = blockIdx.y;
    const int r0 = blockIdx.x * 64;
    const int t = threadIdx.x;
    const int w = t >> 6, lane = t & 63, l15 = lane & 15, g = lane >> 4;

    f32x4 O[4] = {{0,0,0,0},{0,0,0,0},{0,0,0,0},{0,0,0,0}};
    const u16* Pbase = P + ((size_t)bh * 512 + r0) * 512;
    const u16* Tbase = TinT + (size_t)bh * 64 * 512;

    for (int kt = 0; kt < 512; kt += 64) {
        __syncthreads();
        {
            const int rr = t >> 2, c = (t & 3) << 4;
            const uint4* ps = (const uint4*)&Pbase[(size_t)rr * 512 + kt + c];
            *(uint4*)&Psh[rr * PSTR + c]     = ps[0];
            *(uint4*)&Psh[rr * PSTR + c + 8] = ps[1];
            const uint4* ts = (const uint4*)&Tbase[(size_t)rr * 512 + kt + c];
            *(uint4*)&Tsh[rr * PSTR + c]     = ts[0];
            *(uint4*)&Tsh[rr * PSTR + c + 8] = ts[1];
        }
        __syncthreads();
        bf16x8 pa[2];
        pa[0] = *(const bf16x8*)&Psh[(w * 16 + l15) * PSTR + 8 * g];
        pa[1] = *(const bf16x8*)&Psh[(w * 16 + l15) * PSTR + 32 + 8 * g];
        #pragma unroll
        for (int td = 0; td < 4; ++td) {
            #pragma unroll
            for (int c = 0; c < 2; ++c) {
                bf16x8 tb = *(const bf16x8*)&Tsh[(td * 16 + l15) * PSTR + c * 32 + 8 * g];
                O[td] = MFMA16(pa[c], tb, O[td]);
            }
        }
    }
    #pragma unroll
    for (int td = 0; td < 4; ++td) {
        const int d = td * 16 + l15;
        const int r = r0 + w * 16 + g * 4;
        size_t idx = ((size_t)bh * 64 + d) * 512 + r;
        float4 wv = *(float4*)&WaccT[idx];
        wv.x += coef * O[td][0]; wv.y += coef * O[td][1];
        wv.z += coef * O[td][2]; wv.w += coef * O[td][3];
        *(float4*)&WaccT[idx] = wv;
        uint2 u;
        u.x = f2bf_rne(O[td][0]) | (f2bf_rne(O[td][1]) << 16);
        u.y = f2bf_rne(O[td][2]) | (f2bf_rne(O[td][3]) << 16);
        *(uint2*)&ToutT[idx] = u;
    }
}

// ---------------------------------------------------------------------------
// attn = softmax(QK^T/8) @ W, flash-style, bf16x3 MFMA, pre-split Q/K inputs.
// Emits attnh/attnl bf16 split for the out-projection GEMM.
// ---------------------------------------------------------------------------
__global__ __launch_bounds__(256) void attn_mfma(
    const u16* __restrict__ Qh_g, const u16* __restrict__ Ql_g,
    const u16* __restrict__ Kh_g, const u16* __restrict__ Kl_g,
    const float* __restrict__ WT,
    u16* __restrict__ attnh, u16* __restrict__ attnl)
{
    __shared__ u16 Qh[64 * PSTR], Ql[64 * PSTR];
    __shared__ u16 Kh[64 * PSTR], Kl[64 * PSTR];
    __shared__ u16 Wh[64 * PSTR], Wl[64 * PSTR];
    __shared__ u16 Ph[4][16 * PSTR], Pl[4][16 * PSTR];
    const int bh = blockIdx.y, b = bh >> 4, h = bh & 15;
    const int q0 = blockIdx.x * 64;
    const int t = threadIdx.x;
    const int w = t >> 6, lane = t & 63, l15 = lane & 15, g = lane >> 4;

    {   // stage Q hi/lo (once) -- plain copies of pre-split data
        const int r = t >> 2, d0 = (t & 3) << 4;
        const size_t gq = ((size_t)(b * 512 + q0 + r)) * 1024 + h * 64 + d0;
        *(uint4*)&Qh[r * PSTR + d0]     = *(const uint4*)&Qh_g[gq];
        *(uint4*)&Qh[r * PSTR + d0 + 8] = *(const uint4*)&Qh_g[gq + 8];
        *(uint4*)&Ql[r * PSTR + d0]     = *(const uint4*)&Ql_g[gq];
        *(uint4*)&Ql[r * PSTR + d0 + 8] = *(const uint4*)&Ql_g[gq + 8];
    }
    __syncthreads();
    bf16x8 qbh[2], qbl[2];
    {
        const int row = (w * 16 + l15) * PSTR;
        qbh[0] = *(const bf16x8*)&Qh[row + 8 * g];
        qbh[1] = *(const bf16x8*)&Qh[row + 32 + 8 * g];
        qbl[0] = *(const bf16x8*)&Ql[row + 8 * g];
        qbl[1] = *(const bf16x8*)&Ql[row + 32 + 8 * g];
    }
    float m_run = -1e30f, l_run = 0.f;
    f32x4 O[4] = {{0,0,0,0},{0,0,0,0},{0,0,0,0},{0,0,0,0}};

    for (int kt = 0; kt < 512; kt += 64) {
        __syncthreads();
        {
            const int r = t >> 2, d0 = (t & 3) << 4;
            const size_t gk = ((size_t)(b * 512 + kt + r)) * 1024 + h * 64 + d0;
            *(uint4*)&Kh[r * PSTR + d0]     = *(const uint4*)&Kh_g[gk];
            *(uint4*)&Kh[r * PSTR + d0 + 8] = *(const uint4*)&Kh_g[gk + 8];
            *(uint4*)&Kl[r * PSTR + d0]     = *(const uint4*)&Kl_g[gk];
            *(uint4*)&Kl[r * PSTR + d0 + 8] = *(const uint4*)&Kl_g[gk + 8];
            const float4* wsrc = (const float4*)&WT[((size_t)(bh * 64 + r)) * 512 + kt + d0];
            #pragma unroll
            for (int i = 0; i < 4; ++i)
                split4_store(wsrc[i], &Wh[r * PSTR + d0 + i * 4], &Wl[r * PSTR + d0 + i * 4]);
        }
        __syncthreads();
        f32x4 st[4];
        #pragma unroll
        for (int tk = 0; tk < 4; ++tk) {
            f32x4 a = {0.f, 0.f, 0.f, 0.f};
            const int krow = (tk * 16 + l15) * PSTR;
            #pragma unroll
            for (int c = 0; c < 2; ++c) {
                bf16x8 kah = *(const bf16x8*)&Kh[krow + c * 32 + 8 * g];
                bf16x8 kal = *(const bf16x8*)&Kl[krow + c * 32 + 8 * g];
                a = MFMA16(kah, qbh[c], a);
                a = MFMA16(kah, qbl[c], a);
                a = MFMA16(kal, qbh[c], a);
            }
            st[tk] = a;
        }
        float mt = st[0][0];
        #pragma unroll
        for (int tk = 0; tk < 4; ++tk)
            #pragma unroll
            for (int r = 0; r < 4; ++r) mt = fmaxf(mt, st[tk][r]);
        mt = fmaxf(mt, __shfl_xor(mt, 16));
        mt = fmaxf(mt, __shfl_xor(mt, 32));
        const float m_new = fmaxf(m_run, mt);
        const float scale = __expf((m_run - m_new) * 0.125f);
        float rsum = 0.f;
        #pragma unroll
        for (int tk = 0; tk < 4; ++tk) {
            float p0_ = __expf((st[tk][0] - m_new) * 0.125f);
            float p1_ = __expf((st[tk][1] - m_new) * 0.125f);
            float p2_ = __expf((st[tk][2] - m_new) * 0.125f);
            float p3_ = __expf((st[tk][3] - m_new) * 0.125f);
            rsum += p0_ + p1_ + p2_ + p3_;
            u32 h0 = f2bf_rne(p0_), h1 = f2bf_rne(p1_), h2 = f2bf_rne(p2_), h3 = f2bf_rne(p3_);
            uint2 hw; hw.x = h0 | (h1 << 16); hw.y = h2 | (h3 << 16);
            uint2 lw;
            lw.x = f2bf_rne(p0_ - bf_lo(h0)) | (f2bf_rne(p1_ - bf_lo(h1)) << 16);
            lw.y = f2bf_rne(p2_ - bf_lo(h2)) | (f2bf_rne(p3_ - bf_lo(h3)) << 16);
            const int poff = l15 * PSTR + tk * 16 + g * 4;
            *(uint2*)&Ph[w][poff] = hw;
            *(uint2*)&Pl[w][poff] = lw;
        }
        rsum += __shfl_xor(rsum, 16);
        rsum += __shfl_xor(rsum, 32);
        l_run = l_run * scale + rsum;
        m_run = m_new;
        float sc[4];
        #pragma unroll
        for (int r = 0; r < 4; ++r) sc[r] = __shfl(scale, g * 4 + r);
        #pragma unroll
        for (int td = 0; td < 4; ++td)
            #pragma unroll
            for (int r = 0; r < 4; ++r) O[td][r] *= sc[r];
        bf16x8 pah[2], pal[2];
        #pragma unroll
        for (int c = 0; c < 2; ++c) {
            pah[c] = *(const bf16x8*)&Ph[w][l15 * PSTR + c * 32 + 8 * g];
            pal[c] = *(const bf16x8*)&Pl[w][l15 * PSTR + c * 32 + 8 * g];
        }
        #pragma unroll
        for (int td = 0; td < 4; ++td) {
            #pragma unroll
            for (int c = 0; c < 2; ++c) {
                const int wrow = (td * 16 + l15) * PSTR;
                bf16x8 wbh = *(const bf16x8*)&Wh[wrow + c * 32 + 8 * g];
                bf16x8 wbl = *(const bf16x8*)&Wl[wrow + c * 32 + 8 * g];
                O[td] = MFMA16(pah[c], wbh, O[td]);
                O[td] = MFMA16(pah[c], wbl, O[td]);
                O[td] = MFMA16(pal[c], wbh, O[td]);
            }
        }
    }
    const float linv = 1.f / l_run;
    float li[4];
    #pragma unroll
    for (int r = 0; r < 4; ++r) li[r] = __shfl(linv, g * 4 + r);
    #pragma unroll
    for (int td = 0; td < 4; ++td)
        #pragma unroll
        for (int r = 0; r < 4; ++r) {
            const float v = O[td][r] * li[r];
            const size_t idx = ((size_t)(b * 512 + q0 + w * 16 + g * 4 + r)) * 1024
                             + h * 64 + td * 16 + l15;
            const u32 hh = f2bf_rne(v);
            attnh[idx] = (u16)hh;
            attnl[idx] = (u16)f2bf_rne(v - bf_lo(hh));
        }
}

// ---------------------------------------------------------------------------
extern "C" void kernel_launch(void* const* d_in, const int* in_sizes, int n_in,
                              void* d_out, int out_size, void* d_ws, size_t ws_size,
                              hipStream_t stream) {
    const float* X  = (const float*)d_in[0];
    const float* Wq = (const float*)d_in[1];
    const float* bq = (const float*)d_in[2];
    const float* Wk = (const float*)d_in[3];
    const float* bk = (const float*)d_in[4];
    const float* Wv = (const float*)d_in[5];
    const float* bv = (const float*)d_in[6];
    const float* Wo = (const float*)d_in[7];
    const float* bo = (const float*)d_in[8];
    float* out = (float*)d_out;

    char* ws = (char*)d_ws;
    size_t off = 0;
    auto alloc = [&](size_t bytes) -> void* {
        void* p = ws + off;
        off += (bytes + 255) & ~(size_t)255;
        return p;
    };
    const size_t NE = (size_t)NR_ * D_;               // 4,194,304
    const size_t HE = (size_t)BH_ * 64 * 512;         // 4,194,304
    u16* Xh    = (u16*)alloc(NE * 2);
    u16* Xl    = (u16*)alloc(NE * 2);
    u16* WTh   = (u16*)alloc((size_t)4 * 1024 * 1024 * 2);
    u16* WTl   = (u16*)alloc((size_t)4 * 1024 * 1024 * 2);
    u16* QKVh  = (u16*)alloc(3 * NE * 2);             // Q|K|V hi, [which][4096][1024]
    u16* QKVl  = (u16*)alloc(3 * NE * 2);
    float* rnorm = (float*)alloc((size_t)BH_ * 512 * 4);
    u16*   VdT   = (u16*)alloc(HE * 2);
    float* WaccT = (float*)alloc(HE * 4);
    u16*   T1T   = (u16*)alloc(HE * 2);
    u16*   T2T   = (u16*)alloc(HE * 2);
    u16*   P     = (u16*)alloc((size_t)BH_ * 512 * 512 * 2);
    u16*   attnh = (u16*)alloc(NE * 2);
    u16*   attnl = (u16*)alloc(NE * 2);

    const u16* Qh_g = QKVh;            const u16* Ql_g = QKVl;
    const u16* Kh_g = QKVh + NE;       const u16* Kl_g = QKVl + NE;
    const u16* Vh_g = QKVh + 2 * NE;   const u16* Vl_g = QKVl + 2 * NE;

    const float a = ALPHA_;
    const float c1 = a * (1.f - a);
    const float c2 = a * a * (1.f - a);
    const float c3 = a * a * a * (1.f - a);
    const float c4 = a * a * a * a;

    dim3 blk(256);
    split_f32<<<dim3(4096), blk, 0, stream>>>(X, Xh, Xl, (int)(NE / 4));
    wsplitT<<<dim3(16, 16, 4), blk, 0, stream>>>(Wq, Wk, Wv, Wo, WTh, WTl);
    // QKV projections (bf16x3 MFMA), hi/lo split outputs
    gemm_mfma_x3<<<dim3(32, 24), blk, 0, stream>>>(Xh, Xl, WTh, WTl, bq, bk, bv,
                                                   nullptr, QKVh, QKVl, 1);
    knorm_kernel<<<dim3(256), blk, 0, stream>>>(Kh_g, Kl_g, rnorm);
    gather_vT<<<dim3(8, BH_), blk, 0, stream>>>(Vh_g, Vl_g, VdT, WaccT);
    build_p_mfma<<<dim3(8, BH_), blk, 0, stream>>>(Kh_g, Kl_g, rnorm, P);
    chain_mfma<<<dim3(8, BH_), blk, 0, stream>>>(P, VdT, T1T, WaccT, c1);
    chain_mfma<<<dim3(8, BH_), blk, 0, stream>>>(P, T1T, T2T, WaccT, c2);
    chain_mfma<<<dim3(8, BH_), blk, 0, stream>>>(P, T2T, T1T, WaccT, c3);
    chain_mfma<<<dim3(8, BH_), blk, 0, stream>>>(P, T1T, T2T, WaccT, c4);
    attn_mfma<<<dim3(8, BH_), blk, 0, stream>>>(Qh_g, Ql_g, Kh_g, Kl_g, WaccT,
                                                attnh, attnl);
    // output projection (fp32 result + bias), weight slot 3 of WT
    gemm_mfma_x3<<<dim3(32, 8), blk, 0, stream>>>(attnh, attnl,
                                                  WTh + ((size_t)3 << 20), WTl + ((size_t)3 << 20),
                                                  bo, bo, bo, out, nullptr, nullptr, 0);
}

// Round 4
// 281.520 us; speedup vs baseline: 4.7074x; 1.3286x over previous
//
#include <hip/hip_runtime.h>
#include <stdint.h>

#define B_ 8
#define L_ 512
#define D_ 1024
#define H_ 16
#define HD_ 64
#define BH_ (B_*H_)      // 128
#define NR_ (B_*L_)      // 4096 rows
#define ALPHA_ 0.02f
#define C1_ (ALPHA_*(1.f-ALPHA_))     // coef of P V
#define C2_ (ALPHA_*ALPHA_)           // coef of P^2 V  (== c2+c3+c4 exactly)
#define PSTR 72          // LDS row stride in u16 (144B -> 2-way-max bank aliasing, free)
#define GSTR 72

typedef unsigned int u32;
typedef unsigned short u16;
typedef __attribute__((ext_vector_type(8))) short bf16x8;
typedef __attribute__((ext_vector_type(4))) float f32x4;

#define MFMA16(a, b, c) __builtin_amdgcn_mfma_f32_16x16x32_bf16((a), (b), (c), 0, 0, 0)

__device__ __forceinline__ u32 f2bf_rne(float f) {
    u32 x = __float_as_uint(f);
    return (x + 0x7fffu + ((x >> 16) & 1u)) >> 16;
}
__device__ __forceinline__ float bf_lo(u32 u) { return __uint_as_float(u << 16); }
__device__ __forceinline__ float bf_hi(u32 u) { return __uint_as_float(u & 0xffff0000u); }

__device__ __forceinline__ void split4_store(float4 v, u16* hp, u16* lp) {
    u32 h0 = f2bf_rne(v.x), h1 = f2bf_rne(v.y), h2 = f2bf_rne(v.z), h3 = f2bf_rne(v.w);
    uint2 hw; hw.x = h0 | (h1 << 16); hw.y = h2 | (h3 << 16);
    uint2 lw;
    lw.x = f2bf_rne(v.x - bf_lo(h0)) | (f2bf_rne(v.y - bf_lo(h1)) << 16);
    lw.y = f2bf_rne(v.z - bf_lo(h2)) | (f2bf_rne(v.w - bf_lo(h3)) << 16);
    *(uint2*)hp = hw; *(uint2*)lp = lw;
}
__device__ __forceinline__ void pack4_store(float4 v, u16* p) {
    uint2 u;
    u.x = f2bf_rne(v.x) | (f2bf_rne(v.y) << 16);
    u.y = f2bf_rne(v.z) | (f2bf_rne(v.w) << 16);
    *(uint2*)p = u;
}
__device__ __forceinline__ void unpack_add8(uint4 h, uint4 l, float* v) {
    v[0] = bf_lo(h.x) + bf_lo(l.x); v[1] = bf_hi(h.x) + bf_hi(l.x);
    v[2] = bf_lo(h.y) + bf_lo(l.y); v[3] = bf_hi(h.y) + bf_hi(l.y);
    v[4] = bf_lo(h.z) + bf_lo(l.z); v[5] = bf_hi(h.z) + bf_hi(l.z);
    v[6] = bf_lo(h.w) + bf_lo(l.w); v[7] = bf_hi(h.w) + bf_hi(l.w);
}

// ---------------------------------------------------------------------------
// X (fp32) -> Xh/Xl bf16 split, flat
// ---------------------------------------------------------------------------
__global__ __launch_bounds__(256) void split_f32(
    const float* __restrict__ src, u16* __restrict__ dh, u16* __restrict__ dl, int n4)
{
    int i = blockIdx.x * 256 + threadIdx.x;
    if (i < n4) {
        float4 v = ((const float4*)src)[i];
        split4_store(v, &dh[(size_t)i * 4], &dl[(size_t)i * 4]);
    }
}

// ---------------------------------------------------------------------------
// W[k][n] fp32 -> WTh/WTl[w][n][k] bf16 split (transposed). grid (16,16,4)
// ---------------------------------------------------------------------------
__global__ __launch_bounds__(256) void wsplitT(
    const float* __restrict__ W0, const float* __restrict__ W1,
    const float* __restrict__ W2, const float* __restrict__ W3,
    u16* __restrict__ WTh, u16* __restrict__ WTl)
{
    __shared__ float Ws[64][65];
    const int wsel = blockIdx.z;
    const float* W = (wsel == 0) ? W0 : (wsel == 1) ? W1 : (wsel == 2) ? W2 : W3;
    const int k0 = blockIdx.x * 64, n0 = blockIdx.y * 64;
    const int t = threadIdx.x;
    {
        const int r = t >> 2, c0 = (t & 3) << 4;
        #pragma unroll
        for (int i = 0; i < 4; ++i)
            *(float4*)&Ws[r][c0 + i * 4] = *(const float4*)&W[(size_t)(k0 + r) * 1024 + n0 + c0 + i * 4];
    }
    __syncthreads();
    {
        const int n = t >> 2, kc0 = (t & 3) << 4;
        size_t base = ((size_t)wsel << 20) + (size_t)(n0 + n) * 1024 + k0 + kc0;
        #pragma unroll
        for (int j = 0; j < 4; ++j) {
            float4 v;
            v.x = Ws[kc0 + j * 4 + 0][n]; v.y = Ws[kc0 + j * 4 + 1][n];
            v.z = Ws[kc0 + j * 4 + 2][n]; v.w = Ws[kc0 + j * 4 + 3][n];
            split4_store(v, &WTh[base + j * 4], &WTl[base + j * 4]);
        }
    }
}

// ---------------------------------------------------------------------------
// MFMA GEMM. USE_BL=false: x2 split (Ah*Bh + Al*Bh). true: x3 (+ Ah*Bl).
// ---------------------------------------------------------------------------
template<bool USE_BL>
__global__ __launch_bounds__(256) void gemm_mfma(
    const u16* __restrict__ Ah, const u16* __restrict__ Al,
    const u16* __restrict__ WTh, const u16* __restrict__ WTl,
    const float* __restrict__ b0, const float* __restrict__ b1, const float* __restrict__ b2,
    float* __restrict__ Cf, u16* __restrict__ Ch, u16* __restrict__ Cl_,
    int write_hl)
{
    __shared__ u16 Ash[128 * GSTR], Als[128 * GSTR];
    __shared__ u16 Bsh[128 * GSTR];
    __shared__ u16 Bls[USE_BL ? 128 * GSTR : 8];
    const int bm = blockIdx.x;
    const int which = blockIdx.y >> 3;
    const int bn = blockIdx.y & 7;
    const float* bias = (which == 0) ? b0 : (which == 1) ? b1 : b2;
    const int t = threadIdx.x;
    const int w = t >> 6, lane = t & 63, l15 = lane & 15, g = lane >> 4;
    const int wr = w >> 1, wc = w & 1;
    const int row0 = bm * 128, col0 = bn * 128;
    const u16* Bh_g = WTh + ((size_t)which << 20);
    const u16* Bl_g = WTl + ((size_t)which << 20);

    f32x4 acc[4][4];
    #pragma unroll
    for (int i = 0; i < 4; ++i)
        #pragma unroll
        for (int j = 0; j < 4; ++j) acc[i][j] = (f32x4){0.f, 0.f, 0.f, 0.f};

    for (int kt = 0; kt < 1024; kt += 64) {
        __syncthreads();
        #pragma unroll
        for (int i = 0; i < 4; ++i) {
            const int ci = t + i * 256;
            const int r = ci >> 3, c8 = (ci & 7) * 8;
            const size_t ga = (size_t)(row0 + r) * 1024 + kt + c8;
            const size_t gb = (size_t)(col0 + r) * 1024 + kt + c8;
            *(uint4*)&Ash[r * GSTR + c8] = *(const uint4*)&Ah[ga];
            *(uint4*)&Als[r * GSTR + c8] = *(const uint4*)&Al[ga];
            *(uint4*)&Bsh[r * GSTR + c8] = *(const uint4*)&Bh_g[gb];
            if constexpr (USE_BL)
                *(uint4*)&Bls[r * GSTR + c8] = *(const uint4*)&Bl_g[gb];
        }
        __syncthreads();
        #pragma unroll
        for (int c = 0; c < 2; ++c) {
            bf16x8 ah[4], al[4], bh[4], bl[4];
            #pragma unroll
            for (int mf = 0; mf < 4; ++mf) {
                const int ro = (wr * 64 + mf * 16 + l15) * GSTR + c * 32 + g * 8;
                ah[mf] = *(const bf16x8*)&Ash[ro];
                al[mf] = *(const bf16x8*)&Als[ro];
            }
            #pragma unroll
            for (int nf = 0; nf < 4; ++nf) {
                const int ro = (wc * 64 + nf * 16 + l15) * GSTR + c * 32 + g * 8;
                bh[nf] = *(const bf16x8*)&Bsh[ro];
                if constexpr (USE_BL) bl[nf] = *(const bf16x8*)&Bls[ro];
            }
            #pragma unroll
            for (int mf = 0; mf < 4; ++mf)
                #pragma unroll
                for (int nf = 0; nf < 4; ++nf) {
                    acc[mf][nf] = MFMA16(ah[mf], bh[nf], acc[mf][nf]);
                    acc[mf][nf] = MFMA16(al[mf], bh[nf], acc[mf][nf]);
                    if constexpr (USE_BL)
                        acc[mf][nf] = MFMA16(ah[mf], bl[nf], acc[mf][nf]);
                }
        }
    }
    #pragma unroll
    for (int mf = 0; mf < 4; ++mf)
        #pragma unroll
        for (int nf = 0; nf < 4; ++nf) {
            const int n = col0 + wc * 64 + nf * 16 + l15;
            const float bv = bias[n];
            #pragma unroll
            for (int r = 0; r < 4; ++r) {
                const int m = row0 + wr * 64 + mf * 16 + g * 4 + r;
                const float v = acc[mf][nf][r] + bv;
                if (write_hl) {
                    const size_t idx = ((size_t)which << 22) + (size_t)m * 1024 + n;
                    const u32 hh = f2bf_rne(v);
                    Ch[idx]  = (u16)hh;
                    Cl_[idx] = (u16)f2bf_rne(v - bf_lo(hh));
                } else {
                    Cf[(size_t)m * 1024 + n] = v;
                }
            }
        }
}

// ---------------------------------------------------------------------------
// 1/max(||K_row||,eps) from split K
// ---------------------------------------------------------------------------
__global__ __launch_bounds__(256) void knorm_kernel(
    const u16* __restrict__ Kh, const u16* __restrict__ Kl, float* __restrict__ rnorm)
{
    int tid = blockIdx.x * 256 + threadIdx.x;
    int l = tid & 511;
    int h = (tid >> 9) & 15;
    int b = tid >> 13;
    const size_t base = ((size_t)(b * 512 + l)) * 1024 + h * 64;
    float s = 0.f;
    #pragma unroll
    for (int i = 0; i < 8; ++i) {
        uint4 hv = *(const uint4*)&Kh[base + i * 8];
        uint4 lv = *(const uint4*)&Kl[base + i * 8];
        float v[8];
        unpack_add8(hv, lv, v);
        #pragma unroll
        for (int j = 0; j < 8; ++j) s += v[j] * v[j];
    }
    rnorm[tid] = 1.f / fmaxf(sqrtf(s), 1e-6f);
}

// ---------------------------------------------------------------------------
// Vh (bf16, [b][l][h*64+d]) -> VdT (bf16, [bh][64 d][512 l]) transposed per head
// ---------------------------------------------------------------------------
__global__ __launch_bounds__(256) void gather_vT(
    const u16* __restrict__ Vh, u16* __restrict__ VdT)
{
    __shared__ u16 Vs[64 * 72];
    const int bh = blockIdx.y, b = bh >> 4, h = bh & 15;
    const int l0b = blockIdx.x * 64;
    const int t = threadIdx.x;
    {
        const int l = t >> 2, d0 = (t & 3) << 4;
        const size_t gv = ((size_t)(b * 512 + l0b + l)) * 1024 + h * 64 + d0;
        *(uint4*)&Vs[l * 72 + d0]     = *(const uint4*)&Vh[gv];
        *(uint4*)&Vs[l * 72 + d0 + 8] = *(const uint4*)&Vh[gv + 8];
    }
    __syncthreads();
    {
        const int d = t >> 2, l0 = (t & 3) << 4;
        size_t idx = ((size_t)bh * 64 + d) * 512 + l0b + l0;
        #pragma unroll
        for (int i = 0; i < 16; i += 4) {
            uint2 u;
            u.x = Vs[(l0 + i + 0) * 72 + d] | ((u32)Vs[(l0 + i + 1) * 72 + d] << 16);
            u.y = Vs[(l0 + i + 2) * 72 + d] | ((u32)Vs[(l0 + i + 3) * 72 + d] << 16);
            *(uint2*)&VdT[idx + i] = u;
        }
    }
}

// ---------------------------------------------------------------------------
// P = softmax(cos-sim/8)*(1-eps)+eps/512, bf16, MFMA two-pass (K from split).
// ---------------------------------------------------------------------------
__global__ __launch_bounds__(256) void build_p_mfma(
    const u16* __restrict__ Kh_g, const u16* __restrict__ Kl_g,
    const float* __restrict__ rnorm, u16* __restrict__ P)
{
    __shared__ u16 Ksh[64 * PSTR];
    __shared__ u16 Qsh[64 * PSTR];
    const int bh = blockIdx.y, b = bh >> 4, h = bh & 15;
    const int q0 = blockIdx.x * 64;
    const int t = threadIdx.x;
    const int w = t >> 6, lane = t & 63, l15 = lane & 15, g = lane >> 4;

    {
        const int r = t >> 2, d0 = (t & 3) << 4;
        const float rn = rnorm[bh * 512 + q0 + r];
        const size_t gk = ((size_t)(b * 512 + q0 + r)) * 1024 + h * 64 + d0;
        #pragma unroll
        for (int i = 0; i < 2; ++i) {
            uint4 hv = *(const uint4*)&Kh_g[gk + i * 8];
            uint4 lv = *(const uint4*)&Kl_g[gk + i * 8];
            float v[8];
            unpack_add8(hv, lv, v);
            float4 v0 = {v[0]*rn, v[1]*rn, v[2]*rn, v[3]*rn};
            float4 v1 = {v[4]*rn, v[5]*rn, v[6]*rn, v[7]*rn};
            pack4_store(v0, &Qsh[r * PSTR + d0 + i * 8]);
            pack4_store(v1, &Qsh[r * PSTR + d0 + i * 8 + 4]);
        }
    }
    __syncthreads();
    bf16x8 qb[2];
    qb[0] = *(const bf16x8*)&Qsh[(w * 16 + l15) * PSTR + 8 * g];
    qb[1] = *(const bf16x8*)&Qsh[(w * 16 + l15) * PSTR + 32 + 8 * g];

    float m_run = -1e30f, l_run = 0.f, inv = 0.f;
    for (int pass = 0; pass < 2; ++pass) {
        if (pass == 1) inv = (1.0f - 1e-6f) / l_run;
        for (int jt = 0; jt < 512; jt += 64) {
            __syncthreads();
            {
                const int r = t >> 2, d0 = (t & 3) << 4;
                const float rn = rnorm[bh * 512 + jt + r];
                const size_t gk = ((size_t)(b * 512 + jt + r)) * 1024 + h * 64 + d0;
                #pragma unroll
                for (int i = 0; i < 2; ++i) {
                    uint4 hv = *(const uint4*)&Kh_g[gk + i * 8];
                    uint4 lv = *(const uint4*)&Kl_g[gk + i * 8];
                    float v[8];
                    unpack_add8(hv, lv, v);
                    float4 v0 = {v[0]*rn, v[1]*rn, v[2]*rn, v[3]*rn};
                    float4 v1 = {v[4]*rn, v[5]*rn, v[6]*rn, v[7]*rn};
                    pack4_store(v0, &Ksh[r * PSTR + d0 + i * 8]);
                    pack4_store(v1, &Ksh[r * PSTR + d0 + i * 8 + 4]);
                }
            }
            __syncthreads();
            f32x4 st[4];
            #pragma unroll
            for (int tk = 0; tk < 4; ++tk) {
                f32x4 a = {0.f, 0.f, 0.f, 0.f};
                const int krow = tk * 16 + l15;
                #pragma unroll
                for (int c = 0; c < 2; ++c) {
                    bf16x8 ka = *(const bf16x8*)&Ksh[krow * PSTR + c * 32 + 8 * g];
                    a = MFMA16(ka, qb[c], a);
                }
                st[tk] = a;
            }
            if (pass == 0) {
                float mt = st[0][0];
                #pragma unroll
                for (int tk = 0; tk < 4; ++tk)
                    #pragma unroll
                    for (int r = 0; r < 4; ++r) mt = fmaxf(mt, st[tk][r]);
                mt = fmaxf(mt, __shfl_xor(mt, 16));
                mt = fmaxf(mt, __shfl_xor(mt, 32));
                float m_new = fmaxf(m_run, mt);
                float scale = __expf((m_run - m_new) * 0.125f);
                float rsum = 0.f;
                #pragma unroll
                for (int tk = 0; tk < 4; ++tk)
                    #pragma unroll
                    for (int r = 0; r < 4; ++r)
                        rsum += __expf((st[tk][r] - m_new) * 0.125f);
                rsum += __shfl_xor(rsum, 16);
                rsum += __shfl_xor(rsum, 32);
                l_run = l_run * scale + rsum;
                m_run = m_new;
            } else {
                const int i_row = q0 + w * 16 + l15;
                u16* prow = P + ((size_t)bh * 512 + i_row) * 512;
                #pragma unroll
                for (int tk = 0; tk < 4; ++tk) {
                    float p0_ = __expf((st[tk][0] - m_run) * 0.125f) * inv + (1e-6f / 512.0f);
                    float p1_ = __expf((st[tk][1] - m_run) * 0.125f) * inv + (1e-6f / 512.0f);
                    float p2_ = __expf((st[tk][2] - m_run) * 0.125f) * inv + (1e-6f / 512.0f);
                    float p3_ = __expf((st[tk][3] - m_run) * 0.125f) * inv + (1e-6f / 512.0f);
                    uint2 u;
                    u.x = f2bf_rne(p0_) | (f2bf_rne(p1_) << 16);
                    u.y = f2bf_rne(p2_) | (f2bf_rne(p3_) << 16);
                    *(uint2*)&prow[jt + tk * 16 + g * 4] = u;
                }
            }
        }
    }
}

// ---------------------------------------------------------------------------
// Shared chain K-loop body: O = P_tile @ Tin (per head), tiles 64r x 64d.
// ---------------------------------------------------------------------------
__device__ __forceinline__ void chain_loop(
    const u16* __restrict__ Pbase, const u16* __restrict__ Tbase,
    u16* Psh, u16* Tsh, int t, int w, int l15, int g, f32x4 O[4])
{
    for (int kt = 0; kt < 512; kt += 64) {
        __syncthreads();
        {
            const int rr = t >> 2, c = (t & 3) << 4;
            const uint4* ps = (const uint4*)&Pbase[(size_t)rr * 512 + kt + c];
            *(uint4*)&Psh[rr * PSTR + c]     = ps[0];
            *(uint4*)&Psh[rr * PSTR + c + 8] = ps[1];
            const uint4* ts = (const uint4*)&Tbase[(size_t)rr * 512 + kt + c];
            *(uint4*)&Tsh[rr * PSTR + c]     = ts[0];
            *(uint4*)&Tsh[rr * PSTR + c + 8] = ts[1];
        }
        __syncthreads();
        bf16x8 pa[2];
        pa[0] = *(const bf16x8*)&Psh[(w * 16 + l15) * PSTR + 8 * g];
        pa[1] = *(const bf16x8*)&Psh[(w * 16 + l15) * PSTR + 32 + 8 * g];
        #pragma unroll
        for (int td = 0; td < 4; ++td) {
            #pragma unroll
            for (int c = 0; c < 2; ++c) {
                bf16x8 tb = *(const bf16x8*)&Tsh[(td * 16 + l15) * PSTR + c * 32 + 8 * g];
                O[td] = MFMA16(pa[c], tb, O[td]);
            }
        }
    }
}

// chain step 1: T1 = P @ V; T1T bf16 out; Wpart = bf16(0.98 V + c1 T1)
__global__ __launch_bounds__(256) void chain1_mfma(
    const u16* __restrict__ P, const u16* __restrict__ VdT,
    u16* __restrict__ T1T, u16* __restrict__ Wpart)
{
    __shared__ u16 Psh[64 * PSTR];
    __shared__ u16 Tsh[64 * PSTR];
    const int bh = blockIdx.y;
    const int r0 = blockIdx.x * 64;
    const int t = threadIdx.x;
    const int w = t >> 6, lane = t & 63, l15 = lane & 15, g = lane >> 4;
    f32x4 O[4] = {{0,0,0,0},{0,0,0,0},{0,0,0,0},{0,0,0,0}};
    chain_loop(P + ((size_t)bh * 512 + r0) * 512, VdT + (size_t)bh * 64 * 512,
               Psh, Tsh, t, w, l15, g, O);
    #pragma unroll
    for (int td = 0; td < 4; ++td) {
        const int d = td * 16 + l15;
        const int r = r0 + w * 16 + g * 4;
        size_t idx = ((size_t)bh * 64 + d) * 512 + r;
        uint2 vv = *(const uint2*)&VdT[idx];
        float v0 = bf_lo(vv.x), v1 = bf_hi(vv.x), v2 = bf_lo(vv.y), v3 = bf_hi(vv.y);
        uint2 tu;
        tu.x = f2bf_rne(O[td][0]) | (f2bf_rne(O[td][1]) << 16);
        tu.y = f2bf_rne(O[td][2]) | (f2bf_rne(O[td][3]) << 16);
        *(uint2*)&T1T[idx] = tu;
        uint2 wu;
        wu.x = f2bf_rne(0.98f * v0 + C1_ * O[td][0])
             | (f2bf_rne(0.98f * v1 + C1_ * O[td][1]) << 16);
        wu.y = f2bf_rne(0.98f * v2 + C1_ * O[td][2])
             | (f2bf_rne(0.98f * v3 + C1_ * O[td][3]) << 16);
        *(uint2*)&Wpart[idx] = wu;
    }
}

// chain step 2: T2 = P @ T1; Wh = bf16(Wpart + a^2 T2)
__global__ __launch_bounds__(256) void chain2_mfma(
    const u16* __restrict__ P, const u16* __restrict__ T1T,
    const u16* __restrict__ Wpart, u16* __restrict__ Wh)
{
    __shared__ u16 Psh[64 * PSTR];
    __shared__ u16 Tsh[64 * PSTR];
    const int bh = blockIdx.y;
    const int r0 = blockIdx.x * 64;
    const int t = threadIdx.x;
    const int w = t >> 6, lane = t & 63, l15 = lane & 15, g = lane >> 4;
    f32x4 O[4] = {{0,0,0,0},{0,0,0,0},{0,0,0,0},{0,0,0,0}};
    chain_loop(P + ((size_t)bh * 512 + r0) * 512, T1T + (size_t)bh * 64 * 512,
               Psh, Tsh, t, w, l15, g, O);
    #pragma unroll
    for (int td = 0; td < 4; ++td) {
        const int d = td * 16 + l15;
        const int r = r0 + w * 16 + g * 4;
        size_t idx = ((size_t)bh * 64 + d) * 512 + r;
        uint2 wv = *(const uint2*)&Wpart[idx];
        uint2 wu;
        wu.x = f2bf_rne(bf_lo(wv.x) + C2_ * O[td][0])
             | (f2bf_rne(bf_hi(wv.x) + C2_ * O[td][1]) << 16);
        wu.y = f2bf_rne(bf_lo(wv.y) + C2_ * O[td][2])
             | (f2bf_rne(bf_hi(wv.y) + C2_ * O[td][3]) << 16);
        *(uint2*)&Wh[idx] = wu;
    }
}

// ---------------------------------------------------------------------------
// attn = softmax(QK^T/8) @ W, flash-style. QK^T x2 (K-split x Q-hi),
// PV x2 (P-split x W-hi). W pre-split bf16 -> plain staging copies.
// ---------------------------------------------------------------------------
__global__ __launch_bounds__(256) void attn_mfma(
    const u16* __restrict__ Qh_g,
    const u16* __restrict__ Kh_g, const u16* __restrict__ Kl_g,
    const u16* __restrict__ Wh_g,
    u16* __restrict__ attnh, u16* __restrict__ attnl)
{
    __shared__ u16 Qh[64 * PSTR];
    __shared__ u16 Kh[64 * PSTR], Kl[64 * PSTR];
    __shared__ u16 Wh[64 * PSTR];
    __shared__ u16 Ph[4][16 * PSTR], Pl[4][16 * PSTR];
    const int bh = blockIdx.y, b = bh >> 4, h = bh & 15;
    const int q0 = blockIdx.x * 64;
    const int t = threadIdx.x;
    const int w = t >> 6, lane = t & 63, l15 = lane & 15, g = lane >> 4;

    {
        const int r = t >> 2, d0 = (t & 3) << 4;
        const size_t gq = ((size_t)(b * 512 + q0 + r)) * 1024 + h * 64 + d0;
        *(uint4*)&Qh[r * PSTR + d0]     = *(const uint4*)&Qh_g[gq];
        *(uint4*)&Qh[r * PSTR + d0 + 8] = *(const uint4*)&Qh_g[gq + 8];
    }
    __syncthreads();
    bf16x8 qbh[2];
    {
        const int row = (w * 16 + l15) * PSTR;
        qbh[0] = *(const bf16x8*)&Qh[row + 8 * g];
        qbh[1] = *(const bf16x8*)&Qh[row + 32 + 8 * g];
    }
    float m_run = -1e30f, l_run = 0.f;
    f32x4 O[4] = {{0,0,0,0},{0,0,0,0},{0,0,0,0},{0,0,0,0}};

    for (int kt = 0; kt < 512; kt += 64) {
        __syncthreads();
        {
            const int r = t >> 2, d0 = (t & 3) << 4;
            const size_t gk = ((size_t)(b * 512 + kt + r)) * 1024 + h * 64 + d0;
            *(uint4*)&Kh[r * PSTR + d0]     = *(const uint4*)&Kh_g[gk];
            *(uint4*)&Kh[r * PSTR + d0 + 8] = *(const uint4*)&Kh_g[gk + 8];
            *(uint4*)&Kl[r * PSTR + d0]     = *(const uint4*)&Kl_g[gk];
            *(uint4*)&Kl[r * PSTR + d0 + 8] = *(const uint4*)&Kl_g[gk + 8];
            const size_t gw = ((size_t)(bh * 64 + r)) * 512 + kt + d0;
            *(uint4*)&Wh[r * PSTR + d0]     = *(const uint4*)&Wh_g[gw];
            *(uint4*)&Wh[r * PSTR + d0 + 8] = *(const uint4*)&Wh_g[gw + 8];
        }
        __syncthreads();
        f32x4 st[4];
        #pragma unroll
        for (int tk = 0; tk < 4; ++tk) {
            f32x4 a = {0.f, 0.f, 0.f, 0.f};
            const int krow = (tk * 16 + l15) * PSTR;
            #pragma unroll
            for (int c = 0; c < 2; ++c) {
                bf16x8 kah = *(const bf16x8*)&Kh[krow + c * 32 + 8 * g];
                bf16x8 kal = *(const bf16x8*)&Kl[krow + c * 32 + 8 * g];
                a = MFMA16(kah, qbh[c], a);
                a = MFMA16(kal, qbh[c], a);
            }
            st[tk] = a;
        }
        float mt = st[0][0];
        #pragma unroll
        for (int tk = 0; tk < 4; ++tk)
            #pragma unroll
            for (int r = 0; r < 4; ++r) mt = fmaxf(mt, st[tk][r]);
        mt = fmaxf(mt, __shfl_xor(mt, 16));
        mt = fmaxf(mt, __shfl_xor(mt, 32));
        const float m_new = fmaxf(m_run, mt);
        const float scale = __expf((m_run - m_new) * 0.125f);
        float rsum = 0.f;
        #pragma unroll
        for (int tk = 0; tk < 4; ++tk) {
            float p0_ = __expf((st[tk][0] - m_new) * 0.125f);
            float p1_ = __expf((st[tk][1] - m_new) * 0.125f);
            float p2_ = __expf((st[tk][2] - m_new) * 0.125f);
            float p3_ = __expf((st[tk][3] - m_new) * 0.125f);
            rsum += p0_ + p1_ + p2_ + p3_;
            u32 h0 = f2bf_rne(p0_), h1 = f2bf_rne(p1_), h2 = f2bf_rne(p2_), h3 = f2bf_rne(p3_);
            uint2 hw; hw.x = h0 | (h1 << 16); hw.y = h2 | (h3 << 16);
            uint2 lw;
            lw.x = f2bf_rne(p0_ - bf_lo(h0)) | (f2bf_rne(p1_ - bf_lo(h1)) << 16);
            lw.y = f2bf_rne(p2_ - bf_lo(h2)) | (f2bf_rne(p3_ - bf_lo(h3)) << 16);
            const int poff = l15 * PSTR + tk * 16 + g * 4;
            *(uint2*)&Ph[w][poff] = hw;
            *(uint2*)&Pl[w][poff] = lw;
        }
        rsum += __shfl_xor(rsum, 16);
        rsum += __shfl_xor(rsum, 32);
        l_run = l_run * scale + rsum;
        m_run = m_new;
        float sc[4];
        #pragma unroll
        for (int r = 0; r < 4; ++r) sc[r] = __shfl(scale, g * 4 + r);
        #pragma unroll
        for (int td = 0; td < 4; ++td)
            #pragma unroll
            for (int r = 0; r < 4; ++r) O[td][r] *= sc[r];
        bf16x8 pah[2], pal[2];
        #pragma unroll
        for (int c = 0; c < 2; ++c) {
            pah[c] = *(const bf16x8*)&Ph[w][l15 * PSTR + c * 32 + 8 * g];
            pal[c] = *(const bf16x8*)&Pl[w][l15 * PSTR + c * 32 + 8 * g];
        }
        #pragma unroll
        for (int td = 0; td < 4; ++td) {
            #pragma unroll
            for (int c = 0; c < 2; ++c) {
                const int wrow = (td * 16 + l15) * PSTR;
                bf16x8 wbh = *(const bf16x8*)&Wh[wrow + c * 32 + 8 * g];
                O[td] = MFMA16(pah[c], wbh, O[td]);
                O[td] = MFMA16(pal[c], wbh, O[td]);
            }
        }
    }
    const float linv = 1.f / l_run;
    float li[4];
    #pragma unroll
    for (int r = 0; r < 4; ++r) li[r] = __shfl(linv, g * 4 + r);
    #pragma unroll
    for (int td = 0; td < 4; ++td)
        #pragma unroll
        for (int r = 0; r < 4; ++r) {
            const float v = O[td][r] * li[r];
            const size_t idx = ((size_t)(b * 512 + q0 + w * 16 + g * 4 + r)) * 1024
                             + h * 64 + td * 16 + l15;
            const u32 hh = f2bf_rne(v);
            attnh[idx] = (u16)hh;
            attnl[idx] = (u16)f2bf_rne(v - bf_lo(hh));
        }
}

// ---------------------------------------------------------------------------
extern "C" void kernel_launch(void* const* d_in, const int* in_sizes, int n_in,
                              void* d_out, int out_size, void* d_ws, size_t ws_size,
                              hipStream_t stream) {
    const float* X  = (const float*)d_in[0];
    const float* Wq = (const float*)d_in[1];
    const float* bq = (const float*)d_in[2];
    const float* Wk = (const float*)d_in[3];
    const float* bk = (const float*)d_in[4];
    const float* Wv = (const float*)d_in[5];
    const float* bv = (const float*)d_in[6];
    const float* Wo = (const float*)d_in[7];
    const float* bo = (const float*)d_in[8];
    float* out = (float*)d_out;

    char* ws = (char*)d_ws;
    size_t off = 0;
    auto alloc = [&](size_t bytes) -> void* {
        void* p = ws + off;
        off += (bytes + 255) & ~(size_t)255;
        return p;
    };
    const size_t NE = (size_t)NR_ * D_;               // 4,194,304
    const size_t HE = (size_t)BH_ * 64 * 512;         // 4,194,304
    u16* Xh    = (u16*)alloc(NE * 2);
    u16* Xl    = (u16*)alloc(NE * 2);
    u16* WTh   = (u16*)alloc((size_t)4 * 1024 * 1024 * 2);
    u16* WTl   = (u16*)alloc((size_t)4 * 1024 * 1024 * 2);
    u16* QKVh  = (u16*)alloc(3 * NE * 2);
    u16* QKVl  = (u16*)alloc(3 * NE * 2);
    float* rnorm = (float*)alloc((size_t)BH_ * 512 * 4);
    u16*   VdT   = (u16*)alloc(HE * 2);
    u16*   T1T   = (u16*)alloc(HE * 2);
    u16*   Wpart = (u16*)alloc(HE * 2);
    u16*   Whb   = (u16*)alloc(HE * 2);
    u16*   P     = (u16*)alloc((size_t)BH_ * 512 * 512 * 2);
    u16*   attnh = (u16*)alloc(NE * 2);
    u16*   attnl = (u16*)alloc(NE * 2);

    const u16* Qh_g = QKVh;
    const u16* Kh_g = QKVh + NE;       const u16* Kl_g = QKVl + NE;
    const u16* Vh_g = QKVh + 2 * NE;

    dim3 blk(256);
    split_f32<<<dim3(4096), blk, 0, stream>>>(X, Xh, Xl, (int)(NE / 4));
    wsplitT<<<dim3(16, 16, 4), blk, 0, stream>>>(Wq, Wk, Wv, Wo, WTh, WTl);
    gemm_mfma<false><<<dim3(32, 24), blk, 0, stream>>>(Xh, Xl, WTh, WTl, bq, bk, bv,
                                                       nullptr, QKVh, QKVl, 1);
    knorm_kernel<<<dim3(256), blk, 0, stream>>>(Kh_g, Kl_g, rnorm);
    gather_vT<<<dim3(8, BH_), blk, 0, stream>>>(Vh_g, VdT);
    build_p_mfma<<<dim3(8, BH_), blk, 0, stream>>>(Kh_g, Kl_g, rnorm, P);
    chain1_mfma<<<dim3(8, BH_), blk, 0, stream>>>(P, VdT, T1T, Wpart);
    chain2_mfma<<<dim3(8, BH_), blk, 0, stream>>>(P, T1T, Wpart, Whb);
    attn_mfma<<<dim3(8, BH_), blk, 0, stream>>>(Qh_g, Kh_g, Kl_g, Whb, attnh, attnl);
    gemm_mfma<true><<<dim3(32, 8), blk, 0, stream>>>(attnh, attnl,
                                                  WTh + ((size_t)3 << 20), WTl + ((size_t)3 << 20),
                                                  bo, bo, bo, out, nullptr, nullptr, 0);
}

// Round 5
// 227.954 us; speedup vs baseline: 5.8136x; 1.2350x over previous
//
#include <hip/hip_runtime.h>
#include <stdint.h>

#define B_ 8
#define L_ 512
#define D_ 1024
#define H_ 16
#define HD_ 64
#define BH_ (B_*H_)      // 128
#define NR_ (B_*L_)      // 4096 rows
#define ALPHA_ 0.02f
#define C1_ (ALPHA_*(1.f-ALPHA_))     // coef of P V
#define C2_ (ALPHA_*ALPHA_)           // coef of P^2 V  (== c2+c3+c4 exactly)
#define PSTR 72          // padded LDS row stride (u16) for copy-staged tiles

typedef unsigned int u32;
typedef unsigned short u16;
typedef __attribute__((ext_vector_type(8))) short bf16x8;
typedef __attribute__((ext_vector_type(4))) float f32x4;

#define MFMA16(a, b, c) __builtin_amdgcn_mfma_f32_16x16x32_bf16((a), (b), (c), 0, 0, 0)

__device__ __forceinline__ u32 f2bf_rne(float f) {
    u32 x = __float_as_uint(f);
    return (x + 0x7fffu + ((x >> 16) & 1u)) >> 16;
}
__device__ __forceinline__ float bf_lo(u32 u) { return __uint_as_float(u << 16); }
__device__ __forceinline__ float bf_hi(u32 u) { return __uint_as_float(u & 0xffff0000u); }

__device__ __forceinline__ void pack4_store(float4 v, u16* p) {
    uint2 u;
    u.x = f2bf_rne(v.x) | (f2bf_rne(v.y) << 16);
    u.y = f2bf_rne(v.z) | (f2bf_rne(v.w) << 16);
    *(uint2*)p = u;
}

// global->LDS DMA, 16B per lane. lds base must be wave-uniform; HW writes
// base + lane*16 (guide §5 / m97). CK-style address-space casts.
__device__ __forceinline__ void gl_lds16(const u16* g, u16* l) {
    auto gp = reinterpret_cast<const __attribute__((address_space(1))) void*>(
        reinterpret_cast<uintptr_t>(g));
    auto lp = reinterpret_cast<__attribute__((address_space(3))) void*>(
        reinterpret_cast<uintptr_t>(l));
    __builtin_amdgcn_global_load_lds(gp, lp, 16, 0, 0);
}

// ---------------------------------------------------------------------------
// X (fp32) -> bf16 (hi only)
// ---------------------------------------------------------------------------
__global__ __launch_bounds__(256) void cast_bf16(
    const float* __restrict__ src, u16* __restrict__ dst, int n8)
{
    int i = blockIdx.x * 256 + threadIdx.x;
    if (i < n8) {
        float4 a = ((const float4*)src)[(size_t)i * 2];
        float4 b = ((const float4*)src)[(size_t)i * 2 + 1];
        uint4 o;
        o.x = f2bf_rne(a.x) | (f2bf_rne(a.y) << 16);
        o.y = f2bf_rne(a.z) | (f2bf_rne(a.w) << 16);
        o.z = f2bf_rne(b.x) | (f2bf_rne(b.y) << 16);
        o.w = f2bf_rne(b.z) | (f2bf_rne(b.w) << 16);
        ((uint4*)dst)[i] = o;
    }
}

// ---------------------------------------------------------------------------
// W[k][n] fp32 -> WTh[w][n][k] bf16 (transposed, hi only). grid (16,16,4)
// ---------------------------------------------------------------------------
__global__ __launch_bounds__(256) void wT_bf16(
    const float* __restrict__ W0, const float* __restrict__ W1,
    const float* __restrict__ W2, const float* __restrict__ W3,
    u16* __restrict__ WTh)
{
    __shared__ float Ws[64][65];
    const int wsel = blockIdx.z;
    const float* W = (wsel == 0) ? W0 : (wsel == 1) ? W1 : (wsel == 2) ? W2 : W3;
    const int k0 = blockIdx.x * 64, n0 = blockIdx.y * 64;
    const int t = threadIdx.x;
    {
        const int r = t >> 2, c0 = (t & 3) << 4;
        #pragma unroll
        for (int i = 0; i < 4; ++i)
            *(float4*)&Ws[r][c0 + i * 4] = *(const float4*)&W[(size_t)(k0 + r) * 1024 + n0 + c0 + i * 4];
    }
    __syncthreads();
    {
        const int n = t >> 2, kc0 = (t & 3) << 4;
        size_t base = ((size_t)wsel << 20) + (size_t)(n0 + n) * 1024 + k0 + kc0;
        #pragma unroll
        for (int j = 0; j < 4; ++j) {
            float4 v;
            v.x = Ws[kc0 + j * 4 + 0][n]; v.y = Ws[kc0 + j * 4 + 1][n];
            v.z = Ws[kc0 + j * 4 + 2][n]; v.w = Ws[kc0 + j * 4 + 3][n];
            pack4_store(v, &WTh[base + j * 4]);
        }
    }
}

// ---------------------------------------------------------------------------
// MFMA GEMM, global_load_lds staging, linear LDS [128][64] (m97 pattern).
// TERMS=1: C = Ah@B^T'. TERMS=2: C = (Ah+Al)@B^T'.
// write_hl=1: bf16 out at (which<<22); else fp32 Cf.
// ---------------------------------------------------------------------------
template<int TERMS>
__global__ __launch_bounds__(256) void gemm_mfma(
    const u16* __restrict__ Ah, const u16* __restrict__ Al,
    const u16* __restrict__ WTh,
    const float* __restrict__ b0, const float* __restrict__ b1, const float* __restrict__ b2,
    float* __restrict__ Cf, u16* __restrict__ Ch, int write_hl)
{
    __shared__ u16 Ash[128 * 64];
    __shared__ u16 Als[TERMS == 2 ? 128 * 64 : 8];
    __shared__ u16 Bsh[128 * 64];
    const int bm = blockIdx.x;
    const int which = blockIdx.y >> 3;
    const int bn = blockIdx.y & 7;
    const float* bias = (which == 0) ? b0 : (which == 1) ? b1 : b2;
    const int t = threadIdx.x;
    const int w = t >> 6, lane = t & 63, l15 = lane & 15, g = lane >> 4;
    const int wr = w >> 1, wc = w & 1;
    const int row0 = bm * 128, col0 = bn * 128;
    const u16* Bg = WTh + ((size_t)which << 20);
    const int lrow = lane >> 3, lcol = (lane & 7) << 3;

    f32x4 acc[4][4];
    #pragma unroll
    for (int i = 0; i < 4; ++i)
        #pragma unroll
        for (int j = 0; j < 4; ++j) acc[i][j] = (f32x4){0.f, 0.f, 0.f, 0.f};

    for (int kt = 0; kt < 1024; kt += 64) {
        __syncthreads();
        #pragma unroll
        for (int q = 0; q < 4; ++q) {
            const int rb = w * 32 + q * 8;
            const size_t ga = (size_t)(row0 + rb + lrow) * 1024 + kt + lcol;
            const size_t gb = (size_t)(col0 + rb + lrow) * 1024 + kt + lcol;
            gl_lds16(&Ah[ga], &Ash[rb * 64]);
            if constexpr (TERMS == 2) gl_lds16(&Al[ga], &Als[rb * 64]);
            gl_lds16(&Bg[gb], &Bsh[rb * 64]);
        }
        __syncthreads();
        #pragma unroll
        for (int c = 0; c < 2; ++c) {
            bf16x8 ah[4], al[4], bh[4];
            #pragma unroll
            for (int mf = 0; mf < 4; ++mf) {
                const int ro = (wr * 64 + mf * 16 + l15) * 64 + c * 32 + g * 8;
                ah[mf] = *(const bf16x8*)&Ash[ro];
                if constexpr (TERMS == 2) al[mf] = *(const bf16x8*)&Als[ro];
            }
            #pragma unroll
            for (int nf = 0; nf < 4; ++nf)
                bh[nf] = *(const bf16x8*)&Bsh[(wc * 64 + nf * 16 + l15) * 64 + c * 32 + g * 8];
            #pragma unroll
            for (int mf = 0; mf < 4; ++mf)
                #pragma unroll
                for (int nf = 0; nf < 4; ++nf) {
                    acc[mf][nf] = MFMA16(ah[mf], bh[nf], acc[mf][nf]);
                    if constexpr (TERMS == 2)
                        acc[mf][nf] = MFMA16(al[mf], bh[nf], acc[mf][nf]);
                }
        }
    }
    #pragma unroll
    for (int mf = 0; mf < 4; ++mf)
        #pragma unroll
        for (int nf = 0; nf < 4; ++nf) {
            const int n = col0 + wc * 64 + nf * 16 + l15;
            const float bv = bias[n];
            #pragma unroll
            for (int r = 0; r < 4; ++r) {
                const int m = row0 + wr * 64 + mf * 16 + g * 4 + r;
                const float v = acc[mf][nf][r] + bv;
                if (write_hl) {
                    Ch[((size_t)which << 22) + (size_t)m * 1024 + n] = (u16)f2bf_rne(v);
                } else {
                    Cf[(size_t)m * 1024 + n] = v;
                }
            }
        }
}

// ---------------------------------------------------------------------------
// Kn = bf16(K / max(||K_head_row||, eps))  (norm from bf16 K; error alpha-damped)
// ---------------------------------------------------------------------------
__global__ __launch_bounds__(256) void knorm_kn(
    const u16* __restrict__ Kh, u16* __restrict__ Kn)
{
    int tid = blockIdx.x * 256 + threadIdx.x;
    int l = tid & 511;
    int h = (tid >> 9) & 15;
    int b = tid >> 13;
    const size_t base = ((size_t)(b * 512 + l)) * 1024 + h * 64;
    uint4 kv[8];
    float s = 0.f;
    #pragma unroll
    for (int i = 0; i < 8; ++i) {
        kv[i] = *(const uint4*)&Kh[base + i * 8];
        float v0 = bf_lo(kv[i].x), v1 = bf_hi(kv[i].x);
        float v2 = bf_lo(kv[i].y), v3 = bf_hi(kv[i].y);
        float v4 = bf_lo(kv[i].z), v5 = bf_hi(kv[i].z);
        float v6 = bf_lo(kv[i].w), v7 = bf_hi(kv[i].w);
        s += v0*v0 + v1*v1 + v2*v2 + v3*v3 + v4*v4 + v5*v5 + v6*v6 + v7*v7;
    }
    const float rn = 1.f / fmaxf(sqrtf(s), 1e-6f);
    #pragma unroll
    for (int i = 0; i < 8; ++i) {
        uint4 o;
        o.x = f2bf_rne(bf_lo(kv[i].x) * rn) | (f2bf_rne(bf_hi(kv[i].x) * rn) << 16);
        o.y = f2bf_rne(bf_lo(kv[i].y) * rn) | (f2bf_rne(bf_hi(kv[i].y) * rn) << 16);
        o.z = f2bf_rne(bf_lo(kv[i].z) * rn) | (f2bf_rne(bf_hi(kv[i].z) * rn) << 16);
        o.w = f2bf_rne(bf_lo(kv[i].w) * rn) | (f2bf_rne(bf_hi(kv[i].w) * rn) << 16);
        *(uint4*)&Kn[base + i * 8] = o;
    }
}

// ---------------------------------------------------------------------------
// Vh (bf16, [b][l][h*64+d]) -> VdT (bf16, [bh][64 d][512 l])
// ---------------------------------------------------------------------------
__global__ __launch_bounds__(256) void gather_vT(
    const u16* __restrict__ Vh, u16* __restrict__ VdT)
{
    __shared__ u16 Vs[64 * 72];
    const int bh = blockIdx.y, b = bh >> 4, h = bh & 15;
    const int l0b = blockIdx.x * 64;
    const int t = threadIdx.x;
    {
        const int l = t >> 2, d0 = (t & 3) << 4;
        const size_t gv = ((size_t)(b * 512 + l0b + l)) * 1024 + h * 64 + d0;
        *(uint4*)&Vs[l * 72 + d0]     = *(const uint4*)&Vh[gv];
        *(uint4*)&Vs[l * 72 + d0 + 8] = *(const uint4*)&Vh[gv + 8];
    }
    __syncthreads();
    {
        const int d = t >> 2, l0 = (t & 3) << 4;
        size_t idx = ((size_t)bh * 64 + d) * 512 + l0b + l0;
        #pragma unroll
        for (int i = 0; i < 16; i += 4) {
            uint2 u;
            u.x = Vs[(l0 + i + 0) * 72 + d] | ((u32)Vs[(l0 + i + 1) * 72 + d] << 16);
            u.y = Vs[(l0 + i + 2) * 72 + d] | ((u32)Vs[(l0 + i + 3) * 72 + d] << 16);
            *(uint2*)&VdT[idx + i] = u;
        }
    }
}

// ---------------------------------------------------------------------------
// E = exp(cos-sim/8) (bf16, unnormalized), Dinv = (1-eps)/rowsum.
// Single pass: scores bounded in [-0.125,0.125] -> exp in [0.88,1.13], no max.
// P == Dinv . E algebraically (jitter term ~5e-10, dropped).
// ---------------------------------------------------------------------------
__global__ __launch_bounds__(256) void build_p_mfma(
    const u16* __restrict__ Kn_g, float* __restrict__ Dinv, u16* __restrict__ P)
{
    __shared__ u16 Ksh[64 * PSTR];
    __shared__ u16 Qsh[64 * PSTR];
    const int bh = blockIdx.y, b = bh >> 4, h = bh & 15;
    const int q0 = blockIdx.x * 64;
    const int t = threadIdx.x;
    const int w = t >> 6, lane = t & 63, l15 = lane & 15, g = lane >> 4;

    {
        const int r = t >> 2, d0 = (t & 3) << 4;
        const size_t gk = ((size_t)(b * 512 + q0 + r)) * 1024 + h * 64 + d0;
        *(uint4*)&Qsh[r * PSTR + d0]     = *(const uint4*)&Kn_g[gk];
        *(uint4*)&Qsh[r * PSTR + d0 + 8] = *(const uint4*)&Kn_g[gk + 8];
    }
    __syncthreads();
    bf16x8 qb[2];
    qb[0] = *(const bf16x8*)&Qsh[(w * 16 + l15) * PSTR + 8 * g];
    qb[1] = *(const bf16x8*)&Qsh[(w * 16 + l15) * PSTR + 32 + 8 * g];

    float rsum = 0.f;
    u16* prow = P + ((size_t)bh * 512 + q0 + w * 16 + l15) * 512;
    for (int jt = 0; jt < 512; jt += 64) {
        __syncthreads();
        {
            const int r = t >> 2, d0 = (t & 3) << 4;
            const size_t gk = ((size_t)(b * 512 + jt + r)) * 1024 + h * 64 + d0;
            *(uint4*)&Ksh[r * PSTR + d0]     = *(const uint4*)&Kn_g[gk];
            *(uint4*)&Ksh[r * PSTR + d0 + 8] = *(const uint4*)&Kn_g[gk + 8];
        }
        __syncthreads();
        #pragma unroll
        for (int tk = 0; tk < 4; ++tk) {
            f32x4 a = {0.f, 0.f, 0.f, 0.f};
            #pragma unroll
            for (int c = 0; c < 2; ++c) {
                bf16x8 ka = *(const bf16x8*)&Ksh[(tk * 16 + l15) * PSTR + c * 32 + 8 * g];
                a = MFMA16(ka, qb[c], a);
            }
            const float e0 = __expf(a[0] * 0.125f);
            const float e1 = __expf(a[1] * 0.125f);
            const float e2 = __expf(a[2] * 0.125f);
            const float e3 = __expf(a[3] * 0.125f);
            rsum += e0 + e1 + e2 + e3;
            uint2 u;
            u.x = f2bf_rne(e0) | (f2bf_rne(e1) << 16);
            u.y = f2bf_rne(e2) | (f2bf_rne(e3) << 16);
            *(uint2*)&prow[jt + tk * 16 + g * 4] = u;
        }
    }
    rsum += __shfl_xor(rsum, 16);
    rsum += __shfl_xor(rsum, 32);
    if (g == 0)
        Dinv[bh * 512 + q0 + w * 16 + l15] = (1.0f - 1e-6f) / rsum;
}

// ---------------------------------------------------------------------------
// Shared chain K-loop body: O = E_tile @ Tin (per head), 64r x 64d.
// ---------------------------------------------------------------------------
__device__ __forceinline__ void chain_loop(
    const u16* __restrict__ Pbase, const u16* __restrict__ Tbase,
    u16* Psh, u16* Tsh, int t, int w, int l15, int g, f32x4 O[4])
{
    for (int kt = 0; kt < 512; kt += 64) {
        __syncthreads();
        {
            const int rr = t >> 2, c = (t & 3) << 4;
            const uint4* ps = (const uint4*)&Pbase[(size_t)rr * 512 + kt + c];
            *(uint4*)&Psh[rr * PSTR + c]     = ps[0];
            *(uint4*)&Psh[rr * PSTR + c + 8] = ps[1];
            const uint4* ts = (const uint4*)&Tbase[(size_t)rr * 512 + kt + c];
            *(uint4*)&Tsh[rr * PSTR + c]     = ts[0];
            *(uint4*)&Tsh[rr * PSTR + c + 8] = ts[1];
        }
        __syncthreads();
        bf16x8 pa[2];
        pa[0] = *(const bf16x8*)&Psh[(w * 16 + l15) * PSTR + 8 * g];
        pa[1] = *(const bf16x8*)&Psh[(w * 16 + l15) * PSTR + 32 + 8 * g];
        #pragma unroll
        for (int td = 0; td < 4; ++td) {
            #pragma unroll
            for (int c = 0; c < 2; ++c) {
                bf16x8 tb = *(const bf16x8*)&Tsh[(td * 16 + l15) * PSTR + c * 32 + 8 * g];
                O[td] = MFMA16(pa[c], tb, O[td]);
            }
        }
    }
}

// chain 1: T1 = Dinv.(E@V); Wpart = bf16(0.98 V + c1 T1)
__global__ __launch_bounds__(256) void chain1_mfma(
    const u16* __restrict__ P, const u16* __restrict__ VdT,
    const float* __restrict__ Dinv,
    u16* __restrict__ T1T, u16* __restrict__ Wpart)
{
    __shared__ u16 Psh[64 * PSTR];
    __shared__ u16 Tsh[64 * PSTR];
    const int bh = blockIdx.y;
    const int r0 = blockIdx.x * 64;
    const int t = threadIdx.x;
    const int w = t >> 6, lane = t & 63, l15 = lane & 15, g = lane >> 4;
    f32x4 O[4] = {{0,0,0,0},{0,0,0,0},{0,0,0,0},{0,0,0,0}};
    chain_loop(P + ((size_t)bh * 512 + r0) * 512, VdT + (size_t)bh * 64 * 512,
               Psh, Tsh, t, w, l15, g, O);
    const float4 dv = *(const float4*)&Dinv[bh * 512 + r0 + w * 16 + g * 4];
    #pragma unroll
    for (int td = 0; td < 4; ++td) {
        const int d = td * 16 + l15;
        const int r = r0 + w * 16 + g * 4;
        size_t idx = ((size_t)bh * 64 + d) * 512 + r;
        const float t0 = dv.x * O[td][0], t1 = dv.y * O[td][1];
        const float t2 = dv.z * O[td][2], t3 = dv.w * O[td][3];
        uint2 vv = *(const uint2*)&VdT[idx];
        uint2 tu;
        tu.x = f2bf_rne(t0) | (f2bf_rne(t1) << 16);
        tu.y = f2bf_rne(t2) | (f2bf_rne(t3) << 16);
        *(uint2*)&T1T[idx] = tu;
        uint2 wu;
        wu.x = f2bf_rne(0.98f * bf_lo(vv.x) + C1_ * t0)
             | (f2bf_rne(0.98f * bf_hi(vv.x) + C1_ * t1) << 16);
        wu.y = f2bf_rne(0.98f * bf_lo(vv.y) + C1_ * t2)
             | (f2bf_rne(0.98f * bf_hi(vv.y) + C1_ * t3) << 16);
        *(uint2*)&Wpart[idx] = wu;
    }
}

// chain 2: T2 = Dinv.(E@T1); Wh = bf16(Wpart + a^2 T2)
__global__ __launch_bounds__(256) void chain2_mfma(
    const u16* __restrict__ P, const u16* __restrict__ T1T,
    const float* __restrict__ Dinv,
    const u16* __restrict__ Wpart, u16* __restrict__ Wh)
{
    __shared__ u16 Psh[64 * PSTR];
    __shared__ u16 Tsh[64 * PSTR];
    const int bh = blockIdx.y;
    const int r0 = blockIdx.x * 64;
    const int t = threadIdx.x;
    const int w = t >> 6, lane = t & 63, l15 = lane & 15, g = lane >> 4;
    f32x4 O[4] = {{0,0,0,0},{0,0,0,0},{0,0,0,0},{0,0,0,0}};
    chain_loop(P + ((size_t)bh * 512 + r0) * 512, T1T + (size_t)bh * 64 * 512,
               Psh, Tsh, t, w, l15, g, O);
    const float4 dv = *(const float4*)&Dinv[bh * 512 + r0 + w * 16 + g * 4];
    #pragma unroll
    for (int td = 0; td < 4; ++td) {
        const int d = td * 16 + l15;
        const int r = r0 + w * 16 + g * 4;
        size_t idx = ((size_t)bh * 64 + d) * 512 + r;
        uint2 wv = *(const uint2*)&Wpart[idx];
        uint2 wu;
        wu.x = f2bf_rne(bf_lo(wv.x) + C2_ * dv.x * O[td][0])
             | (f2bf_rne(bf_hi(wv.x) + C2_ * dv.y * O[td][1]) << 16);
        wu.y = f2bf_rne(bf_lo(wv.y) + C2_ * dv.z * O[td][2])
             | (f2bf_rne(bf_hi(wv.y) + C2_ * dv.w * O[td][3]) << 16);
        *(uint2*)&Wh[idx] = wu;
    }
}

// ---------------------------------------------------------------------------
// attn = softmax(QK^T/8) @ W, flash-style. QK x1 (Kh.Qh), PV x2 (Ph+Pl).Wh.
// K/W/Q tiles staged via global_load_lds into linear [64][64] LDS.
// ---------------------------------------------------------------------------
__global__ __launch_bounds__(256) void attn_mfma(
    const u16* __restrict__ Qh_g, const u16* __restrict__ Kh_g,
    const u16* __restrict__ Wh_g,
    u16* __restrict__ attnh, u16* __restrict__ attnl)
{
    __shared__ u16 Qs[64 * 64];
    __shared__ u16 Ks[64 * 64];
    __shared__ u16 Wsh[64 * 64];
    __shared__ u16 Ph[4][16 * PSTR], Pl[4][16 * PSTR];
    const int bh = blockIdx.y, b = bh >> 4, h = bh & 15;
    const int q0 = blockIdx.x * 64;
    const int t = threadIdx.x;
    const int w = t >> 6, lane = t & 63, l15 = lane & 15, g = lane >> 4;
    const int lrow = lane >> 3, lcol = (lane & 7) << 3;

    #pragma unroll
    for (int q = 0; q < 2; ++q) {
        const int rb = w * 16 + q * 8;
        gl_lds16(&Qh_g[((size_t)(b * 512 + q0 + rb + lrow)) * 1024 + h * 64 + lcol],
                 &Qs[rb * 64]);
    }
    __syncthreads();
    bf16x8 qbh[2];
    qbh[0] = *(const bf16x8*)&Qs[(w * 16 + l15) * 64 + 8 * g];
    qbh[1] = *(const bf16x8*)&Qs[(w * 16 + l15) * 64 + 32 + 8 * g];

    float m_run = -1e30f, l_run = 0.f;
    f32x4 O[4] = {{0,0,0,0},{0,0,0,0},{0,0,0,0},{0,0,0,0}};

    for (int kt = 0; kt < 512; kt += 64) {
        __syncthreads();
        #pragma unroll
        for (int q = 0; q < 2; ++q) {
            const int rb = w * 16 + q * 8;
            gl_lds16(&Kh_g[((size_t)(b * 512 + kt + rb + lrow)) * 1024 + h * 64 + lcol],
                     &Ks[rb * 64]);
            gl_lds16(&Wh_g[((size_t)(bh * 64 + rb + lrow)) * 512 + kt + lcol],
                     &Wsh[rb * 64]);
        }
        __syncthreads();
        f32x4 st[4];
        #pragma unroll
        for (int tk = 0; tk < 4; ++tk) {
            f32x4 a = {0.f, 0.f, 0.f, 0.f};
            #pragma unroll
            for (int c = 0; c < 2; ++c) {
                bf16x8 kah = *(const bf16x8*)&Ks[(tk * 16 + l15) * 64 + c * 32 + 8 * g];
                a = MFMA16(kah, qbh[c], a);
            }
            st[tk] = a;
        }
        float mt = st[0][0];
        #pragma unroll
        for (int tk = 0; tk < 4; ++tk)
            #pragma unroll
            for (int r = 0; r < 4; ++r) mt = fmaxf(mt, st[tk][r]);
        mt = fmaxf(mt, __shfl_xor(mt, 16));
        mt = fmaxf(mt, __shfl_xor(mt, 32));
        const float m_new = fmaxf(m_run, mt);
        const float scale = __expf((m_run - m_new) * 0.125f);
        float rsum = 0.f;
        #pragma unroll
        for (int tk = 0; tk < 4; ++tk) {
            float p0_ = __expf((st[tk][0] - m_new) * 0.125f);
            float p1_ = __expf((st[tk][1] - m_new) * 0.125f);
            float p2_ = __expf((st[tk][2] - m_new) * 0.125f);
            float p3_ = __expf((st[tk][3] - m_new) * 0.125f);
            rsum += p0_ + p1_ + p2_ + p3_;
            u32 h0 = f2bf_rne(p0_), h1 = f2bf_rne(p1_), h2 = f2bf_rne(p2_), h3 = f2bf_rne(p3_);
            uint2 hw; hw.x = h0 | (h1 << 16); hw.y = h2 | (h3 << 16);
            uint2 lw;
            lw.x = f2bf_rne(p0_ - bf_lo(h0)) | (f2bf_rne(p1_ - bf_lo(h1)) << 16);
            lw.y = f2bf_rne(p2_ - bf_lo(h2)) | (f2bf_rne(p3_ - bf_lo(h3)) << 16);
            const int poff = l15 * PSTR + tk * 16 + g * 4;
            *(uint2*)&Ph[w][poff] = hw;
            *(uint2*)&Pl[w][poff] = lw;
        }
        rsum += __shfl_xor(rsum, 16);
        rsum += __shfl_xor(rsum, 32);
        l_run = l_run * scale + rsum;
        m_run = m_new;
        float sc[4];
        #pragma unroll
        for (int r = 0; r < 4; ++r) sc[r] = __shfl(scale, g * 4 + r);
        #pragma unroll
        for (int td = 0; td < 4; ++td)
            #pragma unroll
            for (int r = 0; r < 4; ++r) O[td][r] *= sc[r];
        bf16x8 pah[2], pal[2];
        #pragma unroll
        for (int c = 0; c < 2; ++c) {
            pah[c] = *(const bf16x8*)&Ph[w][l15 * PSTR + c * 32 + 8 * g];
            pal[c] = *(const bf16x8*)&Pl[w][l15 * PSTR + c * 32 + 8 * g];
        }
        #pragma unroll
        for (int td = 0; td < 4; ++td) {
            #pragma unroll
            for (int c = 0; c < 2; ++c) {
                bf16x8 wbh = *(const bf16x8*)&Wsh[(td * 16 + l15) * 64 + c * 32 + 8 * g];
                O[td] = MFMA16(pah[c], wbh, O[td]);
                O[td] = MFMA16(pal[c], wbh, O[td]);
            }
        }
    }
    const float linv = 1.f / l_run;
    float li[4];
    #pragma unroll
    for (int r = 0; r < 4; ++r) li[r] = __shfl(linv, g * 4 + r);
    #pragma unroll
    for (int td = 0; td < 4; ++td)
        #pragma unroll
        for (int r = 0; r < 4; ++r) {
            const float v = O[td][r] * li[r];
            const size_t idx = ((size_t)(b * 512 + q0 + w * 16 + g * 4 + r)) * 1024
                             + h * 64 + td * 16 + l15;
            const u32 hh = f2bf_rne(v);
            attnh[idx] = (u16)hh;
            attnl[idx] = (u16)f2bf_rne(v - bf_lo(hh));
        }
}

// ---------------------------------------------------------------------------
extern "C" void kernel_launch(void* const* d_in, const int* in_sizes, int n_in,
                              void* d_out, int out_size, void* d_ws, size_t ws_size,
                              hipStream_t stream) {
    const float* X  = (const float*)d_in[0];
    const float* Wq = (const float*)d_in[1];
    const float* bq = (const float*)d_in[2];
    const float* Wk = (const float*)d_in[3];
    const float* bk = (const float*)d_in[4];
    const float* Wv = (const float*)d_in[5];
    const float* bv = (const float*)d_in[6];
    const float* Wo = (const float*)d_in[7];
    const float* bo = (const float*)d_in[8];
    float* out = (float*)d_out;

    char* ws = (char*)d_ws;
    size_t off = 0;
    auto alloc = [&](size_t bytes) -> void* {
        void* p = ws + off;
        off += (bytes + 255) & ~(size_t)255;
        return p;
    };
    const size_t NE = (size_t)NR_ * D_;               // 4,194,304
    const size_t HE = (size_t)BH_ * 64 * 512;         // 4,194,304
    u16*   Xh    = (u16*)alloc(NE * 2);
    u16*   WTh   = (u16*)alloc((size_t)4 * 1024 * 1024 * 2);
    u16*   QKVh  = (u16*)alloc(3 * NE * 2);           // [which][4096][1024]
    u16*   Kn    = (u16*)alloc(NE * 2);
    float* Dinv  = (float*)alloc((size_t)BH_ * 512 * 4);
    u16*   VdT   = (u16*)alloc(HE * 2);
    u16*   T1T   = (u16*)alloc(HE * 2);
    u16*   Wpart = (u16*)alloc(HE * 2);
    u16*   Whb   = (u16*)alloc(HE * 2);
    u16*   P     = (u16*)alloc((size_t)BH_ * 512 * 512 * 2);
    u16*   attnh = (u16*)alloc(NE * 2);
    u16*   attnl = (u16*)alloc(NE * 2);

    const u16* Qh_g = QKVh;
    const u16* Kh_g = QKVh + NE;
    const u16* Vh_g = QKVh + 2 * NE;

    dim3 blk(256);
    cast_bf16<<<dim3(2048), blk, 0, stream>>>(X, Xh, (int)(NE / 8));
    wT_bf16<<<dim3(16, 16, 4), blk, 0, stream>>>(Wq, Wk, Wv, Wo, WTh);
    gemm_mfma<1><<<dim3(32, 24), blk, 0, stream>>>(Xh, nullptr, WTh, bq, bk, bv,
                                                   nullptr, QKVh, 1);
    knorm_kn<<<dim3(256), blk, 0, stream>>>(Kh_g, Kn);
    gather_vT<<<dim3(8, BH_), blk, 0, stream>>>(Vh_g, VdT);
    build_p_mfma<<<dim3(8, BH_), blk, 0, stream>>>(Kn, Dinv, P);
    chain1_mfma<<<dim3(8, BH_), blk, 0, stream>>>(P, VdT, Dinv, T1T, Wpart);
    chain2_mfma<<<dim3(8, BH_), blk, 0, stream>>>(P, T1T, Dinv, Wpart, Whb);
    attn_mfma<<<dim3(8, BH_), blk, 0, stream>>>(Qh_g, Kh_g, Whb, attnh, attnl);
    gemm_mfma<2><<<dim3(32, 8), blk, 0, stream>>>(attnh, attnl,
                                                  WTh + ((size_t)3 << 20),
                                                  bo, bo, bo, out, nullptr, 0);
}

// Round 6
// 195.223 us; speedup vs baseline: 6.7883x; 1.1677x over previous
//
#include <hip/hip_runtime.h>
#include <stdint.h>

#define B_ 8
#define L_ 512
#define D_ 1024
#define H_ 16
#define HD_ 64
#define BH_ (B_*H_)      // 128
#define NR_ (B_*L_)      // 4096 rows
#define ALPHA_ 0.02f
#define C1_ (ALPHA_*(1.f-ALPHA_))     // coef of P V
#define C2_ (ALPHA_*ALPHA_)           // coef of P^2 V  (== c2+c3+c4 exactly)
#define PSTR 72          // padded LDS stride for per-lane-written P tiles (attn)

typedef unsigned int u32;
typedef unsigned short u16;
typedef __attribute__((ext_vector_type(8))) short bf16x8;
typedef __attribute__((ext_vector_type(4))) float f32x4;

#define MFMA16(a, b, c) __builtin_amdgcn_mfma_f32_16x16x32_bf16((a), (b), (c), 0, 0, 0)

__device__ __forceinline__ u32 f2bf_rne(float f) {
    u32 x = __float_as_uint(f);
    return (x + 0x7fffu + ((x >> 16) & 1u)) >> 16;
}
__device__ __forceinline__ float bf_lo(u32 u) { return __uint_as_float(u << 16); }
__device__ __forceinline__ float bf_hi(u32 u) { return __uint_as_float(u & 0xffff0000u); }

__device__ __forceinline__ void pack4_store(float4 v, u16* p) {
    uint2 u;
    u.x = f2bf_rne(v.x) | (f2bf_rne(v.y) << 16);
    u.y = f2bf_rne(v.z) | (f2bf_rne(v.w) << 16);
    *(uint2*)p = u;
}

// global->LDS DMA, 16B/lane; LDS dest = wave-uniform base + lane*16 (linear).
__device__ __forceinline__ void gl_lds16(const u16* g, u16* l) {
    auto gp = reinterpret_cast<const __attribute__((address_space(1))) void*>(
        reinterpret_cast<uintptr_t>(g));
    auto lp = reinterpret_cast<__attribute__((address_space(3))) void*>(
        reinterpret_cast<uintptr_t>(l));
    __builtin_amdgcn_global_load_lds(gp, lp, 16, 0, 0);
}

// XOR-swizzle (T2 / rule #21): LDS tile is linear [rows][64 u16]; the 16B-unit
// index within each row is permuted by unit ^= (row & 7). Staging pre-swizzles
// the per-lane GLOBAL source; reads apply the same XOR. Involution => exact.
// Stage 8 rows of a 64-u16-wide tile per call (64 lanes x 16B).
//   g      : global base of the 8-row chunk (row pitch = gpitch u16)
//   lds    : LDS base of the chunk (linear, 64 u16/row)
__device__ __forceinline__ void stage8_swz(const u16* g, size_t gpitch, u16* lds, int lane) {
    const int lrow = lane >> 3;              // 0..7 == row&7 (chunks 8-aligned)
    const int su = (lane & 7) ^ lrow;        // swizzled source 16B-unit
    gl_lds16(&g[(size_t)lrow * gpitch + su * 8], lds);
}

// ---------------------------------------------------------------------------
// X (fp32) -> bf16 (hi only)
// ---------------------------------------------------------------------------
__global__ __launch_bounds__(256) void cast_bf16(
    const float* __restrict__ src, u16* __restrict__ dst, int n8)
{
    int i = blockIdx.x * 256 + threadIdx.x;
    if (i < n8) {
        float4 a = ((const float4*)src)[(size_t)i * 2];
        float4 b = ((const float4*)src)[(size_t)i * 2 + 1];
        uint4 o;
        o.x = f2bf_rne(a.x) | (f2bf_rne(a.y) << 16);
        o.y = f2bf_rne(a.z) | (f2bf_rne(a.w) << 16);
        o.z = f2bf_rne(b.x) | (f2bf_rne(b.y) << 16);
        o.w = f2bf_rne(b.z) | (f2bf_rne(b.w) << 16);
        ((uint4*)dst)[i] = o;
    }
}

// ---------------------------------------------------------------------------
// W[k][n] fp32 -> WTh[w][n][k] bf16 (transposed, hi only). grid (16,16,4)
// ---------------------------------------------------------------------------
__global__ __launch_bounds__(256) void wT_bf16(
    const float* __restrict__ W0, const float* __restrict__ W1,
    const float* __restrict__ W2, const float* __restrict__ W3,
    u16* __restrict__ WTh)
{
    __shared__ float Ws[64][65];
    const int wsel = blockIdx.z;
    const float* W = (wsel == 0) ? W0 : (wsel == 1) ? W1 : (wsel == 2) ? W2 : W3;
    const int k0 = blockIdx.x * 64, n0 = blockIdx.y * 64;
    const int t = threadIdx.x;
    {
        const int r = t >> 2, c0 = (t & 3) << 4;
        #pragma unroll
        for (int i = 0; i < 4; ++i)
            *(float4*)&Ws[r][c0 + i * 4] = *(const float4*)&W[(size_t)(k0 + r) * 1024 + n0 + c0 + i * 4];
    }
    __syncthreads();
    {
        const int n = t >> 2, kc0 = (t & 3) << 4;
        size_t base = ((size_t)wsel << 20) + (size_t)(n0 + n) * 1024 + k0 + kc0;
        #pragma unroll
        for (int j = 0; j < 4; ++j) {
            float4 v;
            v.x = Ws[kc0 + j * 4 + 0][n]; v.y = Ws[kc0 + j * 4 + 1][n];
            v.z = Ws[kc0 + j * 4 + 2][n]; v.w = Ws[kc0 + j * 4 + 3][n];
            pack4_store(v, &WTh[base + j * 4]);
        }
    }
}

// ---------------------------------------------------------------------------
// MFMA GEMM, swizzled global_load_lds staging, linear LDS [128][64].
// TERMS=1: C = Ah@B^T'. TERMS=2: C = (Ah+Al)@B^T'.
// ---------------------------------------------------------------------------
template<int TERMS>
__global__ __launch_bounds__(256) void gemm_mfma(
    const u16* __restrict__ Ah, const u16* __restrict__ Al,
    const u16* __restrict__ WTh,
    const float* __restrict__ b0, const float* __restrict__ b1, const float* __restrict__ b2,
    float* __restrict__ Cf, u16* __restrict__ Ch, int write_hl)
{
    __shared__ u16 Ash[128 * 64];
    __shared__ u16 Als[TERMS == 2 ? 128 * 64 : 8];
    __shared__ u16 Bsh[128 * 64];
    const int bm = blockIdx.x;
    const int which = blockIdx.y >> 3;
    const int bn = blockIdx.y & 7;
    const float* bias = (which == 0) ? b0 : (which == 1) ? b1 : b2;
    const int t = threadIdx.x;
    const int w = t >> 6, lane = t & 63, l15 = lane & 15, g = lane >> 4;
    const int wr = w >> 1, wc = w & 1;
    const int row0 = bm * 128, col0 = bn * 128;
    const u16* Bg = WTh + ((size_t)which << 20);
    const int r7 = l15 & 7;

    f32x4 acc[4][4];
    #pragma unroll
    for (int i = 0; i < 4; ++i)
        #pragma unroll
        for (int j = 0; j < 4; ++j) acc[i][j] = (f32x4){0.f, 0.f, 0.f, 0.f};

    for (int kt = 0; kt < 1024; kt += 64) {
        __syncthreads();
        #pragma unroll
        for (int q = 0; q < 4; ++q) {
            const int rb = w * 32 + q * 8;
            stage8_swz(&Ah[(size_t)(row0 + rb) * 1024 + kt], 1024, &Ash[rb * 64], lane);
            if constexpr (TERMS == 2)
                stage8_swz(&Al[(size_t)(row0 + rb) * 1024 + kt], 1024, &Als[rb * 64], lane);
            stage8_swz(&Bg[(size_t)(col0 + rb) * 1024 + kt], 1024, &Bsh[rb * 64], lane);
        }
        __syncthreads();
        #pragma unroll
        for (int c = 0; c < 2; ++c) {
            const int uo = ((c * 4 + g) ^ r7) * 8;
            bf16x8 ah[4], al[4], bh[4];
            #pragma unroll
            for (int mf = 0; mf < 4; ++mf) {
                const int ro = (wr * 64 + mf * 16 + l15) * 64 + uo;
                ah[mf] = *(const bf16x8*)&Ash[ro];
                if constexpr (TERMS == 2) al[mf] = *(const bf16x8*)&Als[ro];
            }
            #pragma unroll
            for (int nf = 0; nf < 4; ++nf)
                bh[nf] = *(const bf16x8*)&Bsh[(wc * 64 + nf * 16 + l15) * 64 + uo];
            #pragma unroll
            for (int mf = 0; mf < 4; ++mf)
                #pragma unroll
                for (int nf = 0; nf < 4; ++nf) {
                    acc[mf][nf] = MFMA16(ah[mf], bh[nf], acc[mf][nf]);
                    if constexpr (TERMS == 2)
                        acc[mf][nf] = MFMA16(al[mf], bh[nf], acc[mf][nf]);
                }
        }
    }
    #pragma unroll
    for (int mf = 0; mf < 4; ++mf)
        #pragma unroll
        for (int nf = 0; nf < 4; ++nf) {
            const int n = col0 + wc * 64 + nf * 16 + l15;
            const float bv = bias[n];
            #pragma unroll
            for (int r = 0; r < 4; ++r) {
                const int m = row0 + wr * 64 + mf * 16 + g * 4 + r;
                const float v = acc[mf][nf][r] + bv;
                if (write_hl) {
                    Ch[((size_t)which << 22) + (size_t)m * 1024 + n] = (u16)f2bf_rne(v);
                } else {
                    Cf[(size_t)m * 1024 + n] = v;
                }
            }
        }
}

// ---------------------------------------------------------------------------
// Kn = bf16(K / max(||K_head_row||, eps))
// ---------------------------------------------------------------------------
__global__ __launch_bounds__(256) void knorm_kn(
    const u16* __restrict__ Kh, u16* __restrict__ Kn)
{
    int tid = blockIdx.x * 256 + threadIdx.x;
    int l = tid & 511;
    int h = (tid >> 9) & 15;
    int b = tid >> 13;
    const size_t base = ((size_t)(b * 512 + l)) * 1024 + h * 64;
    uint4 kv[8];
    float s = 0.f;
    #pragma unroll
    for (int i = 0; i < 8; ++i) {
        kv[i] = *(const uint4*)&Kh[base + i * 8];
        float v0 = bf_lo(kv[i].x), v1 = bf_hi(kv[i].x);
        float v2 = bf_lo(kv[i].y), v3 = bf_hi(kv[i].y);
        float v4 = bf_lo(kv[i].z), v5 = bf_hi(kv[i].z);
        float v6 = bf_lo(kv[i].w), v7 = bf_hi(kv[i].w);
        s += v0*v0 + v1*v1 + v2*v2 + v3*v3 + v4*v4 + v5*v5 + v6*v6 + v7*v7;
    }
    const float rn = 1.f / fmaxf(sqrtf(s), 1e-6f);
    #pragma unroll
    for (int i = 0; i < 8; ++i) {
        uint4 o;
        o.x = f2bf_rne(bf_lo(kv[i].x) * rn) | (f2bf_rne(bf_hi(kv[i].x) * rn) << 16);
        o.y = f2bf_rne(bf_lo(kv[i].y) * rn) | (f2bf_rne(bf_hi(kv[i].y) * rn) << 16);
        o.z = f2bf_rne(bf_lo(kv[i].z) * rn) | (f2bf_rne(bf_hi(kv[i].z) * rn) << 16);
        o.w = f2bf_rne(bf_lo(kv[i].w) * rn) | (f2bf_rne(bf_hi(kv[i].w) * rn) << 16);
        *(uint4*)&Kn[base + i * 8] = o;
    }
}

// ---------------------------------------------------------------------------
// Vh (bf16, [b][l][h*64+d]) -> VdT (bf16, [bh][64 d][512 l])
// ---------------------------------------------------------------------------
__global__ __launch_bounds__(256) void gather_vT(
    const u16* __restrict__ Vh, u16* __restrict__ VdT)
{
    __shared__ u16 Vs[64 * 72];
    const int bh = blockIdx.y, b = bh >> 4, h = bh & 15;
    const int l0b = blockIdx.x * 64;
    const int t = threadIdx.x;
    {
        const int l = t >> 2, d0 = (t & 3) << 4;
        const size_t gv = ((size_t)(b * 512 + l0b + l)) * 1024 + h * 64 + d0;
        *(uint4*)&Vs[l * 72 + d0]     = *(const uint4*)&Vh[gv];
        *(uint4*)&Vs[l * 72 + d0 + 8] = *(const uint4*)&Vh[gv + 8];
    }
    __syncthreads();
    {
        const int d = t >> 2, l0 = (t & 3) << 4;
        size_t idx = ((size_t)bh * 64 + d) * 512 + l0b + l0;
        #pragma unroll
        for (int i = 0; i < 16; i += 4) {
            uint2 u;
            u.x = Vs[(l0 + i + 0) * 72 + d] | ((u32)Vs[(l0 + i + 1) * 72 + d] << 16);
            u.y = Vs[(l0 + i + 2) * 72 + d] | ((u32)Vs[(l0 + i + 3) * 72 + d] << 16);
            *(uint2*)&VdT[idx + i] = u;
        }
    }
}

// ---------------------------------------------------------------------------
// E = exp(cos-sim/8) (bf16, unnormalized), Dinv = (1-eps)/rowsum.
// Scores in [-0.125,0.125] -> no max needed. Swizzled gl_lds staging.
// ---------------------------------------------------------------------------
__global__ __launch_bounds__(256) void build_p_mfma(
    const u16* __restrict__ Kn_g, float* __restrict__ Dinv, u16* __restrict__ P)
{
    __shared__ u16 Ksh[64 * 64];
    __shared__ u16 Qsh[64 * 64];
    const int bh = blockIdx.y, b = bh >> 4, h = bh & 15;
    const int q0 = blockIdx.x * 64;
    const int t = threadIdx.x;
    const int w = t >> 6, lane = t & 63, l15 = lane & 15, g = lane >> 4;
    const int r7 = l15 & 7;

    #pragma unroll
    for (int q = 0; q < 2; ++q) {
        const int rb = w * 16 + q * 8;
        stage8_swz(&Kn_g[((size_t)(b * 512 + q0 + rb)) * 1024 + h * 64], 1024,
                   &Qsh[rb * 64], lane);
    }
    __syncthreads();
    bf16x8 qb[2];
    qb[0] = *(const bf16x8*)&Qsh[(w * 16 + l15) * 64 + ((g ^ r7) * 8)];
    qb[1] = *(const bf16x8*)&Qsh[(w * 16 + l15) * 64 + (((4 + g) ^ r7) * 8)];

    float rsum = 0.f;
    u16* prow = P + ((size_t)bh * 512 + q0 + w * 16 + l15) * 512;
    for (int jt = 0; jt < 512; jt += 64) {
        __syncthreads();
        #pragma unroll
        for (int q = 0; q < 2; ++q) {
            const int rb = w * 16 + q * 8;
            stage8_swz(&Kn_g[((size_t)(b * 512 + jt + rb)) * 1024 + h * 64], 1024,
                       &Ksh[rb * 64], lane);
        }
        __syncthreads();
        #pragma unroll
        for (int tk = 0; tk < 4; ++tk) {
            f32x4 a = {0.f, 0.f, 0.f, 0.f};
            #pragma unroll
            for (int c = 0; c < 2; ++c) {
                bf16x8 ka = *(const bf16x8*)&Ksh[(tk * 16 + l15) * 64 + (((c * 4 + g) ^ r7) * 8)];
                a = MFMA16(ka, qb[c], a);
            }
            const float e0 = __expf(a[0] * 0.125f);
            const float e1 = __expf(a[1] * 0.125f);
            const float e2 = __expf(a[2] * 0.125f);
            const float e3 = __expf(a[3] * 0.125f);
            rsum += e0 + e1 + e2 + e3;
            uint2 u;
            u.x = f2bf_rne(e0) | (f2bf_rne(e1) << 16);
            u.y = f2bf_rne(e2) | (f2bf_rne(e3) << 16);
            *(uint2*)&prow[jt + tk * 16 + g * 4] = u;
        }
    }
    rsum += __shfl_xor(rsum, 16);
    rsum += __shfl_xor(rsum, 32);
    if (g == 0)
        Dinv[bh * 512 + q0 + w * 16 + l15] = (1.0f - 1e-6f) / rsum;
}

// ---------------------------------------------------------------------------
// Shared chain K-loop body: O = E_tile @ Tin, swizzled gl_lds staging.
// ---------------------------------------------------------------------------
__device__ __forceinline__ void chain_loop(
    const u16* __restrict__ Pbase, const u16* __restrict__ Tbase,
    u16* Psh, u16* Tsh, int w, int lane, int l15, int g, f32x4 O[4])
{
    const int r7 = l15 & 7;
    for (int kt = 0; kt < 512; kt += 64) {
        __syncthreads();
        #pragma unroll
        for (int q = 0; q < 2; ++q) {
            const int rb = w * 16 + q * 8;
            stage8_swz(&Pbase[(size_t)rb * 512 + kt], 512, &Psh[rb * 64], lane);
            stage8_swz(&Tbase[(size_t)rb * 512 + kt], 512, &Tsh[rb * 64], lane);
        }
        __syncthreads();
        bf16x8 pa[2];
        pa[0] = *(const bf16x8*)&Psh[(w * 16 + l15) * 64 + ((g ^ r7) * 8)];
        pa[1] = *(const bf16x8*)&Psh[(w * 16 + l15) * 64 + (((4 + g) ^ r7) * 8)];
        #pragma unroll
        for (int td = 0; td < 4; ++td) {
            #pragma unroll
            for (int c = 0; c < 2; ++c) {
                bf16x8 tb = *(const bf16x8*)&Tsh[(td * 16 + l15) * 64 + (((c * 4 + g) ^ r7) * 8)];
                O[td] = MFMA16(pa[c], tb, O[td]);
            }
        }
    }
}

// chain 1: T1 = Dinv.(E@V); Wpart = bf16(0.98 V + c1 T1)
__global__ __launch_bounds__(256) void chain1_mfma(
    const u16* __restrict__ P, const u16* __restrict__ VdT,
    const float* __restrict__ Dinv,
    u16* __restrict__ T1T, u16* __restrict__ Wpart)
{
    __shared__ u16 Psh[64 * 64];
    __shared__ u16 Tsh[64 * 64];
    const int bh = blockIdx.y;
    const int r0 = blockIdx.x * 64;
    const int t = threadIdx.x;
    const int w = t >> 6, lane = t & 63, l15 = lane & 15, g = lane >> 4;
    f32x4 O[4] = {{0,0,0,0},{0,0,0,0},{0,0,0,0},{0,0,0,0}};
    chain_loop(P + ((size_t)bh * 512 + r0) * 512, VdT + (size_t)bh * 64 * 512,
               Psh, Tsh, w, lane, l15, g, O);
    const float4 dv = *(const float4*)&Dinv[bh * 512 + r0 + w * 16 + g * 4];
    #pragma unroll
    for (int td = 0; td < 4; ++td) {
        const int d = td * 16 + l15;
        const int r = r0 + w * 16 + g * 4;
        size_t idx = ((size_t)bh * 64 + d) * 512 + r;
        const float t0 = dv.x * O[td][0], t1 = dv.y * O[td][1];
        const float t2 = dv.z * O[td][2], t3 = dv.w * O[td][3];
        uint2 vv = *(const uint2*)&VdT[idx];
        uint2 tu;
        tu.x = f2bf_rne(t0) | (f2bf_rne(t1) << 16);
        tu.y = f2bf_rne(t2) | (f2bf_rne(t3) << 16);
        *(uint2*)&T1T[idx] = tu;
        uint2 wu;
        wu.x = f2bf_rne(0.98f * bf_lo(vv.x) + C1_ * t0)
             | (f2bf_rne(0.98f * bf_hi(vv.x) + C1_ * t1) << 16);
        wu.y = f2bf_rne(0.98f * bf_lo(vv.y) + C1_ * t2)
             | (f2bf_rne(0.98f * bf_hi(vv.y) + C1_ * t3) << 16);
        *(uint2*)&Wpart[idx] = wu;
    }
}

// chain 2: T2 = Dinv.(E@T1); Wh = bf16(Wpart + a^2 T2)
__global__ __launch_bounds__(256) void chain2_mfma(
    const u16* __restrict__ P, const u16* __restrict__ T1T,
    const float* __restrict__ Dinv,
    const u16* __restrict__ Wpart, u16* __restrict__ Wh)
{
    __shared__ u16 Psh[64 * 64];
    __shared__ u16 Tsh[64 * 64];
    const int bh = blockIdx.y;
    const int r0 = blockIdx.x * 64;
    const int t = threadIdx.x;
    const int w = t >> 6, lane = t & 63, l15 = lane & 15, g = lane >> 4;
    f32x4 O[4] = {{0,0,0,0},{0,0,0,0},{0,0,0,0},{0,0,0,0}};
    chain_loop(P + ((size_t)bh * 512 + r0) * 512, T1T + (size_t)bh * 64 * 512,
               Psh, Tsh, w, lane, l15, g, O);
    const float4 dv = *(const float4*)&Dinv[bh * 512 + r0 + w * 16 + g * 4];
    #pragma unroll
    for (int td = 0; td < 4; ++td) {
        const int d = td * 16 + l15;
        const int r = r0 + w * 16 + g * 4;
        size_t idx = ((size_t)bh * 64 + d) * 512 + r;
        uint2 wv = *(const uint2*)&Wpart[idx];
        uint2 wu;
        wu.x = f2bf_rne(bf_lo(wv.x) + C2_ * dv.x * O[td][0])
             | (f2bf_rne(bf_hi(wv.x) + C2_ * dv.y * O[td][1]) << 16);
        wu.y = f2bf_rne(bf_lo(wv.y) + C2_ * dv.z * O[td][2])
             | (f2bf_rne(bf_hi(wv.y) + C2_ * dv.w * O[td][3]) << 16);
        *(uint2*)&Wh[idx] = wu;
    }
}

// ---------------------------------------------------------------------------
// attn = softmax(QK^T/8) @ W, flash-style. QK x1, PV x2 (Ph+Pl).Wh.
// Q/K/W tiles: swizzled gl_lds, linear [64][64] LDS.
// ---------------------------------------------------------------------------
__global__ __launch_bounds__(256) void attn_mfma(
    const u16* __restrict__ Qh_g, const u16* __restrict__ Kh_g,
    const u16* __restrict__ Wh_g,
    u16* __restrict__ attnh, u16* __restrict__ attnl)
{
    __shared__ u16 Qs[64 * 64];
    __shared__ u16 Ks[64 * 64];
    __shared__ u16 Wsh[64 * 64];
    __shared__ u16 Ph[4][16 * PSTR], Pl[4][16 * PSTR];
    const int bh = blockIdx.y, b = bh >> 4, h = bh & 15;
    const int q0 = blockIdx.x * 64;
    const int t = threadIdx.x;
    const int w = t >> 6, lane = t & 63, l15 = lane & 15, g = lane >> 4;
    const int r7 = l15 & 7;

    #pragma unroll
    for (int q = 0; q < 2; ++q) {
        const int rb = w * 16 + q * 8;
        stage8_swz(&Qh_g[((size_t)(b * 512 + q0 + rb)) * 1024 + h * 64], 1024,
                   &Qs[rb * 64], lane);
    }
    __syncthreads();
    bf16x8 qbh[2];
    qbh[0] = *(const bf16x8*)&Qs[(w * 16 + l15) * 64 + ((g ^ r7) * 8)];
    qbh[1] = *(const bf16x8*)&Qs[(w * 16 + l15) * 64 + (((4 + g) ^ r7) * 8)];

    float m_run = -1e30f, l_run = 0.f;
    f32x4 O[4] = {{0,0,0,0},{0,0,0,0},{0,0,0,0},{0,0,0,0}};

    for (int kt = 0; kt < 512; kt += 64) {
        __syncthreads();
        #pragma unroll
        for (int q = 0; q < 2; ++q) {
            const int rb = w * 16 + q * 8;
            stage8_swz(&Kh_g[((size_t)(b * 512 + kt + rb)) * 1024 + h * 64], 1024,
                       &Ks[rb * 64], lane);
            stage8_swz(&Wh_g[((size_t)(bh * 64 + rb)) * 512 + kt], 512,
                       &Wsh[rb * 64], lane);
        }
        __syncthreads();
        f32x4 st[4];
        #pragma unroll
        for (int tk = 0; tk < 4; ++tk) {
            f32x4 a = {0.f, 0.f, 0.f, 0.f};
            #pragma unroll
            for (int c = 0; c < 2; ++c) {
                bf16x8 kah = *(const bf16x8*)&Ks[(tk * 16 + l15) * 64 + (((c * 4 + g) ^ r7) * 8)];
                a = MFMA16(kah, qbh[c], a);
            }
            st[tk] = a;
        }
        float mt = st[0][0];
        #pragma unroll
        for (int tk = 0; tk < 4; ++tk)
            #pragma unroll
            for (int r = 0; r < 4; ++r) mt = fmaxf(mt, st[tk][r]);
        mt = fmaxf(mt, __shfl_xor(mt, 16));
        mt = fmaxf(mt, __shfl_xor(mt, 32));
        const float m_new = fmaxf(m_run, mt);
        const float scale = __expf((m_run - m_new) * 0.125f);
        float rsum = 0.f;
        #pragma unroll
        for (int tk = 0; tk < 4; ++tk) {
            float p0_ = __expf((st[tk][0] - m_new) * 0.125f);
            float p1_ = __expf((st[tk][1] - m_new) * 0.125f);
            float p2_ = __expf((st[tk][2] - m_new) * 0.125f);
            float p3_ = __expf((st[tk][3] - m_new) * 0.125f);
            rsum += p0_ + p1_ + p2_ + p3_;
            u32 h0 = f2bf_rne(p0_), h1 = f2bf_rne(p1_), h2 = f2bf_rne(p2_), h3 = f2bf_rne(p3_);
            uint2 hw; hw.x = h0 | (h1 << 16); hw.y = h2 | (h3 << 16);
            uint2 lw;
            lw.x = f2bf_rne(p0_ - bf_lo(h0)) | (f2bf_rne(p1_ - bf_lo(h1)) << 16);
            lw.y = f2bf_rne(p2_ - bf_lo(h2)) | (f2bf_rne(p3_ - bf_lo(h3)) << 16);
            const int poff = l15 * PSTR + tk * 16 + g * 4;
            *(uint2*)&Ph[w][poff] = hw;
            *(uint2*)&Pl[w][poff] = lw;
        }
        rsum += __shfl_xor(rsum, 16);
        rsum += __shfl_xor(rsum, 32);
        l_run = l_run * scale + rsum;
        m_run = m_new;
        float sc[4];
        #pragma unroll
        for (int r = 0; r < 4; ++r) sc[r] = __shfl(scale, g * 4 + r);
        #pragma unroll
        for (int td = 0; td < 4; ++td)
            #pragma unroll
            for (int r = 0; r < 4; ++r) O[td][r] *= sc[r];
        bf16x8 pah[2], pal[2];
        #pragma unroll
        for (int c = 0; c < 2; ++c) {
            pah[c] = *(const bf16x8*)&Ph[w][l15 * PSTR + c * 32 + 8 * g];
            pal[c] = *(const bf16x8*)&Pl[w][l15 * PSTR + c * 32 + 8 * g];
        }
        #pragma unroll
        for (int td = 0; td < 4; ++td) {
            #pragma unroll
            for (int c = 0; c < 2; ++c) {
                bf16x8 wbh = *(const bf16x8*)&Wsh[(td * 16 + l15) * 64 + (((c * 4 + g) ^ r7) * 8)];
                O[td] = MFMA16(pah[c], wbh, O[td]);
                O[td] = MFMA16(pal[c], wbh, O[td]);
            }
        }
    }
    const float linv = 1.f / l_run;
    float li[4];
    #pragma unroll
    for (int r = 0; r < 4; ++r) li[r] = __shfl(linv, g * 4 + r);
    #pragma unroll
    for (int td = 0; td < 4; ++td)
        #pragma unroll
        for (int r = 0; r < 4; ++r) {
            const float v = O[td][r] * li[r];
            const size_t idx = ((size_t)(b * 512 + q0 + w * 16 + g * 4 + r)) * 1024
                             + h * 64 + td * 16 + l15;
            const u32 hh = f2bf_rne(v);
            attnh[idx] = (u16)hh;
            attnl[idx] = (u16)f2bf_rne(v - bf_lo(hh));
        }
}

// ---------------------------------------------------------------------------
extern "C" void kernel_launch(void* const* d_in, const int* in_sizes, int n_in,
                              void* d_out, int out_size, void* d_ws, size_t ws_size,
                              hipStream_t stream) {
    const float* X  = (const float*)d_in[0];
    const float* Wq = (const float*)d_in[1];
    const float* bq = (const float*)d_in[2];
    const float* Wk = (const float*)d_in[3];
    const float* bk = (const float*)d_in[4];
    const float* Wv = (const float*)d_in[5];
    const float* bv = (const float*)d_in[6];
    const float* Wo = (const float*)d_in[7];
    const float* bo = (const float*)d_in[8];
    float* out = (float*)d_out;

    char* ws = (char*)d_ws;
    size_t off = 0;
    auto alloc = [&](size_t bytes) -> void* {
        void* p = ws + off;
        off += (bytes + 255) & ~(size_t)255;
        return p;
    };
    const size_t NE = (size_t)NR_ * D_;               // 4,194,304
    const size_t HE = (size_t)BH_ * 64 * 512;         // 4,194,304
    u16*   Xh    = (u16*)alloc(NE * 2);
    u16*   WTh   = (u16*)alloc((size_t)4 * 1024 * 1024 * 2);
    u16*   QKVh  = (u16*)alloc(3 * NE * 2);           // [which][4096][1024]
    u16*   Kn    = (u16*)alloc(NE * 2);
    float* Dinv  = (float*)alloc((size_t)BH_ * 512 * 4);
    u16*   VdT   = (u16*)alloc(HE * 2);
    u16*   T1T   = (u16*)alloc(HE * 2);
    u16*   Wpart = (u16*)alloc(HE * 2);
    u16*   Whb   = (u16*)alloc(HE * 2);
    u16*   P     = (u16*)alloc((size_t)BH_ * 512 * 512 * 2);
    u16*   attnh = (u16*)alloc(NE * 2);
    u16*   attnl = (u16*)alloc(NE * 2);

    const u16* Qh_g = QKVh;
    const u16* Kh_g = QKVh + NE;
    const u16* Vh_g = QKVh + 2 * NE;

    dim3 blk(256);
    cast_bf16<<<dim3(2048), blk, 0, stream>>>(X, Xh, (int)(NE / 8));
    wT_bf16<<<dim3(16, 16, 4), blk, 0, stream>>>(Wq, Wk, Wv, Wo, WTh);
    gemm_mfma<1><<<dim3(32, 24), blk, 0, stream>>>(Xh, nullptr, WTh, bq, bk, bv,
                                                   nullptr, QKVh, 1);
    knorm_kn<<<dim3(256), blk, 0, stream>>>(Kh_g, Kn);
    gather_vT<<<dim3(8, BH_), blk, 0, stream>>>(Vh_g, VdT);
    build_p_mfma<<<dim3(8, BH_), blk, 0, stream>>>(Kn, Dinv, P);
    chain1_mfma<<<dim3(8, BH_), blk, 0, stream>>>(P, VdT, Dinv, T1T, Wpart);
    chain2_mfma<<<dim3(8, BH_), blk, 0, stream>>>(P, T1T, Dinv, Wpart, Whb);
    attn_mfma<<<dim3(8, BH_), blk, 0, stream>>>(Qh_g, Kh_g, Whb, attnh, attnl);
    gemm_mfma<2><<<dim3(32, 8), blk, 0, stream>>>(attnh, attnl,
                                                  WTh + ((size_t)3 << 20),
                                                  bo, bo, bo, out, nullptr, 0);
}

// Round 7
// 148.913 us; speedup vs baseline: 8.8994x; 1.3110x over previous
//
#include <hip/hip_runtime.h>
#include <stdint.h>

#define B_ 8
#define L_ 512
#define D_ 1024
#define H_ 16
#define HD_ 64
#define BH_ (B_*H_)      // 128
#define NR_ (B_*L_)      // 4096 rows
#define ALPHA_ 0.02f
#define PSTR 72          // padded LDS stride for per-lane-written P/E tiles

typedef unsigned int u32;
typedef unsigned short u16;
typedef __attribute__((ext_vector_type(8))) short bf16x8;
typedef __attribute__((ext_vector_type(4))) float f32x4;

#define MFMA16(a, b, c) __builtin_amdgcn_mfma_f32_16x16x32_bf16((a), (b), (c), 0, 0, 0)

__device__ __forceinline__ u32 f2bf_rne(float f) {
    u32 x = __float_as_uint(f);
    return (x + 0x7fffu + ((x >> 16) & 1u)) >> 16;
}
__device__ __forceinline__ float bf_lo(u32 u) { return __uint_as_float(u << 16); }
__device__ __forceinline__ float bf_hi(u32 u) { return __uint_as_float(u & 0xffff0000u); }

__device__ __forceinline__ void pack4_store(float4 v, u16* p) {
    uint2 u;
    u.x = f2bf_rne(v.x) | (f2bf_rne(v.y) << 16);
    u.y = f2bf_rne(v.z) | (f2bf_rne(v.w) << 16);
    *(uint2*)p = u;
}

// global->LDS DMA, 16B/lane; LDS dest = wave-uniform base + lane*16 (linear).
__device__ __forceinline__ void gl_lds16(const u16* g, u16* l) {
    auto gp = reinterpret_cast<const __attribute__((address_space(1))) void*>(
        reinterpret_cast<uintptr_t>(g));
    auto lp = reinterpret_cast<__attribute__((address_space(3))) void*>(
        reinterpret_cast<uintptr_t>(l));
    __builtin_amdgcn_global_load_lds(gp, lp, 16, 0, 0);
}

// XOR-swizzle (T2 / rule #21): linear LDS [rows][64 u16]; 16B-unit index within
// each row permuted by unit ^= (row & 7); staging pre-swizzles the per-lane
// GLOBAL source, reads apply the same XOR (involution => exact).
__device__ __forceinline__ void stage8_swz(const u16* g, size_t gpitch, u16* lds, int lane) {
    const int lrow = lane >> 3;              // 0..7 == row&7 (chunks 8-aligned)
    const int su = (lane & 7) ^ lrow;        // swizzled source 16B-unit
    gl_lds16(&g[(size_t)lrow * gpitch + su * 8], lds);
}

// ---------------------------------------------------------------------------
// X (fp32) -> bf16 (hi only)
// ---------------------------------------------------------------------------
__global__ __launch_bounds__(256) void cast_bf16(
    const float* __restrict__ src, u16* __restrict__ dst, int n8)
{
    int i = blockIdx.x * 256 + threadIdx.x;
    if (i < n8) {
        float4 a = ((const float4*)src)[(size_t)i * 2];
        float4 b = ((const float4*)src)[(size_t)i * 2 + 1];
        uint4 o;
        o.x = f2bf_rne(a.x) | (f2bf_rne(a.y) << 16);
        o.y = f2bf_rne(a.z) | (f2bf_rne(a.w) << 16);
        o.z = f2bf_rne(b.x) | (f2bf_rne(b.y) << 16);
        o.w = f2bf_rne(b.z) | (f2bf_rne(b.w) << 16);
        ((uint4*)dst)[i] = o;
    }
}

// ---------------------------------------------------------------------------
// W[k][n] fp32 -> WTh[w][n][k] bf16 (transposed, hi only). grid (16,16,4)
// ---------------------------------------------------------------------------
__global__ __launch_bounds__(256) void wT_bf16(
    const float* __restrict__ W0, const float* __restrict__ W1,
    const float* __restrict__ W2, const float* __restrict__ W3,
    u16* __restrict__ WTh)
{
    __shared__ float Ws[64][65];
    const int wsel = blockIdx.z;
    const float* W = (wsel == 0) ? W0 : (wsel == 1) ? W1 : (wsel == 2) ? W2 : W3;
    const int k0 = blockIdx.x * 64, n0 = blockIdx.y * 64;
    const int t = threadIdx.x;
    {
        const int r = t >> 2, c0 = (t & 3) << 4;
        #pragma unroll
        for (int i = 0; i < 4; ++i)
            *(float4*)&Ws[r][c0 + i * 4] = *(const float4*)&W[(size_t)(k0 + r) * 1024 + n0 + c0 + i * 4];
    }
    __syncthreads();
    {
        const int n = t >> 2, kc0 = (t & 3) << 4;
        size_t base = ((size_t)wsel << 20) + (size_t)(n0 + n) * 1024 + k0 + kc0;
        #pragma unroll
        for (int j = 0; j < 4; ++j) {
            float4 v;
            v.x = Ws[kc0 + j * 4 + 0][n]; v.y = Ws[kc0 + j * 4 + 1][n];
            v.z = Ws[kc0 + j * 4 + 2][n]; v.w = Ws[kc0 + j * 4 + 3][n];
            pack4_store(v, &WTh[base + j * 4]);
        }
    }
}

// ---------------------------------------------------------------------------
// MFMA GEMM, swizzled global_load_lds staging, linear LDS [128][64].
// TERMS=1: C = Ah@B^T'. TERMS=2: C = (Ah+Al)@B^T'.
// ---------------------------------------------------------------------------
template<int TERMS>
__global__ __launch_bounds__(256) void gemm_mfma(
    const u16* __restrict__ Ah, const u16* __restrict__ Al,
    const u16* __restrict__ WTh,
    const float* __restrict__ b0, const float* __restrict__ b1, const float* __restrict__ b2,
    float* __restrict__ Cf, u16* __restrict__ Ch, int write_hl)
{
    __shared__ u16 Ash[128 * 64];
    __shared__ u16 Als[TERMS == 2 ? 128 * 64 : 8];
    __shared__ u16 Bsh[128 * 64];
    const int bm = blockIdx.x;
    const int which = blockIdx.y >> 3;
    const int bn = blockIdx.y & 7;
    const float* bias = (which == 0) ? b0 : (which == 1) ? b1 : b2;
    const int t = threadIdx.x;
    const int w = t >> 6, lane = t & 63, l15 = lane & 15, g = lane >> 4;
    const int wr = w >> 1, wc = w & 1;
    const int row0 = bm * 128, col0 = bn * 128;
    const u16* Bg = WTh + ((size_t)which << 20);
    const int r7 = l15 & 7;

    f32x4 acc[4][4];
    #pragma unroll
    for (int i = 0; i < 4; ++i)
        #pragma unroll
        for (int j = 0; j < 4; ++j) acc[i][j] = (f32x4){0.f, 0.f, 0.f, 0.f};

    for (int kt = 0; kt < 1024; kt += 64) {
        __syncthreads();
        #pragma unroll
        for (int q = 0; q < 4; ++q) {
            const int rb = w * 32 + q * 8;
            stage8_swz(&Ah[(size_t)(row0 + rb) * 1024 + kt], 1024, &Ash[rb * 64], lane);
            if constexpr (TERMS == 2)
                stage8_swz(&Al[(size_t)(row0 + rb) * 1024 + kt], 1024, &Als[rb * 64], lane);
            stage8_swz(&Bg[(size_t)(col0 + rb) * 1024 + kt], 1024, &Bsh[rb * 64], lane);
        }
        __syncthreads();
        #pragma unroll
        for (int c = 0; c < 2; ++c) {
            const int uo = ((c * 4 + g) ^ r7) * 8;
            bf16x8 ah[4], al[4], bh[4];
            #pragma unroll
            for (int mf = 0; mf < 4; ++mf) {
                const int ro = (wr * 64 + mf * 16 + l15) * 64 + uo;
                ah[mf] = *(const bf16x8*)&Ash[ro];
                if constexpr (TERMS == 2) al[mf] = *(const bf16x8*)&Als[ro];
            }
            #pragma unroll
            for (int nf = 0; nf < 4; ++nf)
                bh[nf] = *(const bf16x8*)&Bsh[(wc * 64 + nf * 16 + l15) * 64 + uo];
            #pragma unroll
            for (int mf = 0; mf < 4; ++mf)
                #pragma unroll
                for (int nf = 0; nf < 4; ++nf) {
                    acc[mf][nf] = MFMA16(ah[mf], bh[nf], acc[mf][nf]);
                    if constexpr (TERMS == 2)
                        acc[mf][nf] = MFMA16(al[mf], bh[nf], acc[mf][nf]);
                }
        }
    }
    #pragma unroll
    for (int mf = 0; mf < 4; ++mf)
        #pragma unroll
        for (int nf = 0; nf < 4; ++nf) {
            const int n = col0 + wc * 64 + nf * 16 + l15;
            const float bv = bias[n];
            #pragma unroll
            for (int r = 0; r < 4; ++r) {
                const int m = row0 + wr * 64 + mf * 16 + g * 4 + r;
                const float v = acc[mf][nf][r] + bv;
                if (write_hl) {
                    Ch[((size_t)which << 22) + (size_t)m * 1024 + n] = (u16)f2bf_rne(v);
                } else {
                    Cf[(size_t)m * 1024 + n] = v;
                }
            }
        }
}

// ---------------------------------------------------------------------------
// Kn = bf16(K / max(||K_head_row||, eps))
// ---------------------------------------------------------------------------
__global__ __launch_bounds__(256) void knorm_kn(
    const u16* __restrict__ Kh, u16* __restrict__ Kn)
{
    int tid = blockIdx.x * 256 + threadIdx.x;
    int l = tid & 511;
    int h = (tid >> 9) & 15;
    int b = tid >> 13;
    const size_t base = ((size_t)(b * 512 + l)) * 1024 + h * 64;
    uint4 kv[8];
    float s = 0.f;
    #pragma unroll
    for (int i = 0; i < 8; ++i) {
        kv[i] = *(const uint4*)&Kh[base + i * 8];
        float v0 = bf_lo(kv[i].x), v1 = bf_hi(kv[i].x);
        float v2 = bf_lo(kv[i].y), v3 = bf_hi(kv[i].y);
        float v4 = bf_lo(kv[i].z), v5 = bf_hi(kv[i].z);
        float v6 = bf_lo(kv[i].w), v7 = bf_hi(kv[i].w);
        s += v0*v0 + v1*v1 + v2*v2 + v3*v3 + v4*v4 + v5*v5 + v6*v6 + v7*v7;
    }
    const float rn = 1.f / fmaxf(sqrtf(s), 1e-6f);
    #pragma unroll
    for (int i = 0; i < 8; ++i) {
        uint4 o;
        o.x = f2bf_rne(bf_lo(kv[i].x) * rn) | (f2bf_rne(bf_hi(kv[i].x) * rn) << 16);
        o.y = f2bf_rne(bf_lo(kv[i].y) * rn) | (f2bf_rne(bf_hi(kv[i].y) * rn) << 16);
        o.z = f2bf_rne(bf_lo(kv[i].z) * rn) | (f2bf_rne(bf_hi(kv[i].z) * rn) << 16);
        o.w = f2bf_rne(bf_lo(kv[i].w) * rn) | (f2bf_rne(bf_hi(kv[i].w) * rn) << 16);
        *(uint4*)&Kn[base + i * 8] = o;
    }
}

// ---------------------------------------------------------------------------
// Vh (bf16, [b][l][h*64+d]) -> VdT (bf16, [bh][64 d][512 l])
// ---------------------------------------------------------------------------
__global__ __launch_bounds__(256) void gather_vT(
    const u16* __restrict__ Vh, u16* __restrict__ VdT)
{
    __shared__ u16 Vs[64 * 72];
    const int bh = blockIdx.y, b = bh >> 4, h = bh & 15;
    const int l0b = blockIdx.x * 64;
    const int t = threadIdx.x;
    {
        const int l = t >> 2, d0 = (t & 3) << 4;
        const size_t gv = ((size_t)(b * 512 + l0b + l)) * 1024 + h * 64 + d0;
        *(uint4*)&Vs[l * 72 + d0]     = *(const uint4*)&Vh[gv];
        *(uint4*)&Vs[l * 72 + d0 + 8] = *(const uint4*)&Vh[gv + 8];
    }
    __syncthreads();
    {
        const int d = t >> 2, l0 = (t & 3) << 4;
        size_t idx = ((size_t)bh * 64 + d) * 512 + l0b + l0;
        #pragma unroll
        for (int i = 0; i < 16; i += 4) {
            uint2 u;
            u.x = Vs[(l0 + i + 0) * 72 + d] | ((u32)Vs[(l0 + i + 1) * 72 + d] << 16);
            u.y = Vs[(l0 + i + 2) * 72 + d] | ((u32)Vs[(l0 + i + 3) * 72 + d] << 16);
            *(uint2*)&VdT[idx + i] = u;
        }
    }
}

// ---------------------------------------------------------------------------
// Fused QGFD: WhT = bf16( (1-a) V^T + a * Dinv.(E @ V)^T ) per head,
// E = exp(cos-sim/8) computed on the fly (flash-style, no P materialized).
// Math: W = (1-a)V + a(1-a)PV + a^2 P^2 V;  P^2V-PV = (P-I)delta ~ 1e-3
// => a^2-term folds into a*PV with error ~1e-6 (P rows sum to 1 exactly).
// Scores bounded in [-1/8,1/8] -> no running max. grid (8 rtiles, 128 bh).
// ---------------------------------------------------------------------------
__global__ __launch_bounds__(256) void qgfd_mfma(
    const u16* __restrict__ Kn_g, const u16* __restrict__ VdT,
    u16* __restrict__ WhT)
{
    __shared__ u16 Rs[64 * 64];            // Kn rows r0.. (B operand)
    __shared__ u16 Js[64 * 64];            // Kn rows jt.. (A operand)
    __shared__ u16 Vs[64 * 64];            // VdT tile [64 d][64 j]
    __shared__ u16 Eh[4][16 * PSTR];       // per-wave E relay (C->A layout)
    const int bh = blockIdx.y, b = bh >> 4, h = bh & 15;
    const int r0 = blockIdx.x * 64;
    const int t = threadIdx.x;
    const int w = t >> 6, lane = t & 63, l15 = lane & 15, g = lane >> 4;
    const int r7 = l15 & 7;

    #pragma unroll
    for (int q = 0; q < 2; ++q) {
        const int rb = w * 16 + q * 8;
        stage8_swz(&Kn_g[((size_t)(b * 512 + r0 + rb)) * 1024 + h * 64], 1024,
                   &Rs[rb * 64], lane);
    }
    __syncthreads();
    bf16x8 rbf[2];
    rbf[0] = *(const bf16x8*)&Rs[(w * 16 + l15) * 64 + ((g ^ r7) * 8)];
    rbf[1] = *(const bf16x8*)&Rs[(w * 16 + l15) * 64 + (((4 + g) ^ r7) * 8)];

    float rsum = 0.f;
    f32x4 O[4] = {{0,0,0,0},{0,0,0,0},{0,0,0,0},{0,0,0,0}};

    for (int jt = 0; jt < 512; jt += 64) {
        __syncthreads();
        #pragma unroll
        for (int q = 0; q < 2; ++q) {
            const int rb = w * 16 + q * 8;
            stage8_swz(&Kn_g[((size_t)(b * 512 + jt + rb)) * 1024 + h * 64], 1024,
                       &Js[rb * 64], lane);
            stage8_swz(&VdT[((size_t)(bh * 64 + rb)) * 512 + jt], 512,
                       &Vs[rb * 64], lane);
        }
        __syncthreads();
        // E^T tiles: rows j, cols r (lane l15 = r)
        #pragma unroll
        for (int tk = 0; tk < 4; ++tk) {
            f32x4 a = {0.f, 0.f, 0.f, 0.f};
            #pragma unroll
            for (int c = 0; c < 2; ++c) {
                bf16x8 ka = *(const bf16x8*)&Js[(tk * 16 + l15) * 64 + (((c * 4 + g) ^ r7) * 8)];
                a = MFMA16(ka, rbf[c], a);
            }
            const float e0 = __expf(a[0] * 0.125f);
            const float e1 = __expf(a[1] * 0.125f);
            const float e2 = __expf(a[2] * 0.125f);
            const float e3 = __expf(a[3] * 0.125f);
            rsum += e0 + e1 + e2 + e3;
            uint2 u;
            u.x = f2bf_rne(e0) | (f2bf_rne(e1) << 16);
            u.y = f2bf_rne(e2) | (f2bf_rne(e3) << 16);
            *(uint2*)&Eh[w][l15 * PSTR + tk * 16 + g * 4] = u;   // E[r-local][j]
        }
        // O += E_tile @ V_tile   (A = Eh rows r, B = Vs rows d)
        bf16x8 pah[2];
        pah[0] = *(const bf16x8*)&Eh[w][l15 * PSTR + 8 * g];
        pah[1] = *(const bf16x8*)&Eh[w][l15 * PSTR + 32 + 8 * g];
        #pragma unroll
        for (int td = 0; td < 4; ++td) {
            #pragma unroll
            for (int c = 0; c < 2; ++c) {
                bf16x8 vb = *(const bf16x8*)&Vs[(td * 16 + l15) * 64 + (((c * 4 + g) ^ r7) * 8)];
                O[td] = MFMA16(pah[c], vb, O[td]);
            }
        }
    }
    // epilogue: Dinv from rsum (lane l15 holds row r0+w*16+l15)
    rsum += __shfl_xor(rsum, 16);
    rsum += __shfl_xor(rsum, 32);
    const float dinv = (1.0f - 1e-6f) / rsum;
    float dv[4];
    #pragma unroll
    for (int r = 0; r < 4; ++r) dv[r] = __shfl(dinv, g * 4 + r) * ALPHA_;
    #pragma unroll
    for (int td = 0; td < 4; ++td) {
        const int d = td * 16 + l15;
        const size_t idx = ((size_t)bh * 64 + d) * 512 + r0 + w * 16 + g * 4;
        uint2 vv = *(const uint2*)&VdT[idx];
        uint2 wu;
        wu.x = f2bf_rne((1.0f - ALPHA_) * bf_lo(vv.x) + dv[0] * O[td][0])
             | (f2bf_rne((1.0f - ALPHA_) * bf_hi(vv.x) + dv[1] * O[td][1]) << 16);
        wu.y = f2bf_rne((1.0f - ALPHA_) * bf_lo(vv.y) + dv[2] * O[td][2])
             | (f2bf_rne((1.0f - ALPHA_) * bf_hi(vv.y) + dv[3] * O[td][3]) << 16);
        *(uint2*)&WhT[idx] = wu;
    }
}

// ---------------------------------------------------------------------------
// attn = softmax(QK^T/8) @ W, flash-style. QK x1, PV x2 (Ph+Pl).Wh.
// Q/K/W tiles: swizzled gl_lds, linear [64][64] LDS.
// ---------------------------------------------------------------------------
__global__ __launch_bounds__(256) void attn_mfma(
    const u16* __restrict__ Qh_g, const u16* __restrict__ Kh_g,
    const u16* __restrict__ Wh_g,
    u16* __restrict__ attnh, u16* __restrict__ attnl)
{
    __shared__ u16 Qs[64 * 64];
    __shared__ u16 Ks[64 * 64];
    __shared__ u16 Wsh[64 * 64];
    __shared__ u16 Ph[4][16 * PSTR], Pl[4][16 * PSTR];
    const int bh = blockIdx.y, b = bh >> 4, h = bh & 15;
    const int q0 = blockIdx.x * 64;
    const int t = threadIdx.x;
    const int w = t >> 6, lane = t & 63, l15 = lane & 15, g = lane >> 4;
    const int r7 = l15 & 7;

    #pragma unroll
    for (int q = 0; q < 2; ++q) {
        const int rb = w * 16 + q * 8;
        stage8_swz(&Qh_g[((size_t)(b * 512 + q0 + rb)) * 1024 + h * 64], 1024,
                   &Qs[rb * 64], lane);
    }
    __syncthreads();
    bf16x8 qbh[2];
    qbh[0] = *(const bf16x8*)&Qs[(w * 16 + l15) * 64 + ((g ^ r7) * 8)];
    qbh[1] = *(const bf16x8*)&Qs[(w * 16 + l15) * 64 + (((4 + g) ^ r7) * 8)];

    float m_run = -1e30f, l_run = 0.f;
    f32x4 O[4] = {{0,0,0,0},{0,0,0,0},{0,0,0,0},{0,0,0,0}};

    for (int kt = 0; kt < 512; kt += 64) {
        __syncthreads();
        #pragma unroll
        for (int q = 0; q < 2; ++q) {
            const int rb = w * 16 + q * 8;
            stage8_swz(&Kh_g[((size_t)(b * 512 + kt + rb)) * 1024 + h * 64], 1024,
                       &Ks[rb * 64], lane);
            stage8_swz(&Wh_g[((size_t)(bh * 64 + rb)) * 512 + kt], 512,
                       &Wsh[rb * 64], lane);
        }
        __syncthreads();
        f32x4 st[4];
        #pragma unroll
        for (int tk = 0; tk < 4; ++tk) {
            f32x4 a = {0.f, 0.f, 0.f, 0.f};
            #pragma unroll
            for (int c = 0; c < 2; ++c) {
                bf16x8 kah = *(const bf16x8*)&Ks[(tk * 16 + l15) * 64 + (((c * 4 + g) ^ r7) * 8)];
                a = MFMA16(kah, qbh[c], a);
            }
            st[tk] = a;
        }
        float mt = st[0][0];
        #pragma unroll
        for (int tk = 0; tk < 4; ++tk)
            #pragma unroll
            for (int r = 0; r < 4; ++r) mt = fmaxf(mt, st[tk][r]);
        mt = fmaxf(mt, __shfl_xor(mt, 16));
        mt = fmaxf(mt, __shfl_xor(mt, 32));
        const float m_new = fmaxf(m_run, mt);
        const float scale = __expf((m_run - m_new) * 0.125f);
        float rsum = 0.f;
        #pragma unroll
        for (int tk = 0; tk < 4; ++tk) {
            float p0_ = __expf((st[tk][0] - m_new) * 0.125f);
            float p1_ = __expf((st[tk][1] - m_new) * 0.125f);
            float p2_ = __expf((st[tk][2] - m_new) * 0.125f);
            float p3_ = __expf((st[tk][3] - m_new) * 0.125f);
            rsum += p0_ + p1_ + p2_ + p3_;
            u32 h0 = f2bf_rne(p0_), h1 = f2bf_rne(p1_), h2 = f2bf_rne(p2_), h3 = f2bf_rne(p3_);
            uint2 hw; hw.x = h0 | (h1 << 16); hw.y = h2 | (h3 << 16);
            uint2 lw;
            lw.x = f2bf_rne(p0_ - bf_lo(h0)) | (f2bf_rne(p1_ - bf_lo(h1)) << 16);
            lw.y = f2bf_rne(p2_ - bf_lo(h2)) | (f2bf_rne(p3_ - bf_lo(h3)) << 16);
            const int poff = l15 * PSTR + tk * 16 + g * 4;
            *(uint2*)&Ph[w][poff] = hw;
            *(uint2*)&Pl[w][poff] = lw;
        }
        rsum += __shfl_xor(rsum, 16);
        rsum += __shfl_xor(rsum, 32);
        l_run = l_run * scale + rsum;
        m_run = m_new;
        float sc[4];
        #pragma unroll
        for (int r = 0; r < 4; ++r) sc[r] = __shfl(scale, g * 4 + r);
        #pragma unroll
        for (int td = 0; td < 4; ++td)
            #pragma unroll
            for (int r = 0; r < 4; ++r) O[td][r] *= sc[r];
        bf16x8 pah[2], pal[2];
        #pragma unroll
        for (int c = 0; c < 2; ++c) {
            pah[c] = *(const bf16x8*)&Ph[w][l15 * PSTR + c * 32 + 8 * g];
            pal[c] = *(const bf16x8*)&Pl[w][l15 * PSTR + c * 32 + 8 * g];
        }
        #pragma unroll
        for (int td = 0; td < 4; ++td) {
            #pragma unroll
            for (int c = 0; c < 2; ++c) {
                bf16x8 wbh = *(const bf16x8*)&Wsh[(td * 16 + l15) * 64 + (((c * 4 + g) ^ r7) * 8)];
                O[td] = MFMA16(pah[c], wbh, O[td]);
                O[td] = MFMA16(pal[c], wbh, O[td]);
            }
        }
    }
    const float linv = 1.f / l_run;
    float li[4];
    #pragma unroll
    for (int r = 0; r < 4; ++r) li[r] = __shfl(linv, g * 4 + r);
    #pragma unroll
    for (int td = 0; td < 4; ++td)
        #pragma unroll
        for (int r = 0; r < 4; ++r) {
            const float v = O[td][r] * li[r];
            const size_t idx = ((size_t)(b * 512 + q0 + w * 16 + g * 4 + r)) * 1024
                             + h * 64 + td * 16 + l15;
            const u32 hh = f2bf_rne(v);
            attnh[idx] = (u16)hh;
            attnl[idx] = (u16)f2bf_rne(v - bf_lo(hh));
        }
}

// ---------------------------------------------------------------------------
extern "C" void kernel_launch(void* const* d_in, const int* in_sizes, int n_in,
                              void* d_out, int out_size, void* d_ws, size_t ws_size,
                              hipStream_t stream) {
    const float* X  = (const float*)d_in[0];
    const float* Wq = (const float*)d_in[1];
    const float* bq = (const float*)d_in[2];
    const float* Wk = (const float*)d_in[3];
    const float* bk = (const float*)d_in[4];
    const float* Wv = (const float*)d_in[5];
    const float* bv = (const float*)d_in[6];
    const float* Wo = (const float*)d_in[7];
    const float* bo = (const float*)d_in[8];
    float* out = (float*)d_out;

    char* ws = (char*)d_ws;
    size_t off = 0;
    auto alloc = [&](size_t bytes) -> void* {
        void* p = ws + off;
        off += (bytes + 255) & ~(size_t)255;
        return p;
    };
    const size_t NE = (size_t)NR_ * D_;               // 4,194,304
    const size_t HE = (size_t)BH_ * 64 * 512;         // 4,194,304
    u16*   Xh    = (u16*)alloc(NE * 2);
    u16*   WTh   = (u16*)alloc((size_t)4 * 1024 * 1024 * 2);
    u16*   QKVh  = (u16*)alloc(3 * NE * 2);           // [which][4096][1024]
    u16*   Kn    = (u16*)alloc(NE * 2);
    u16*   VdT   = (u16*)alloc(HE * 2);
    u16*   WhT   = (u16*)alloc(HE * 2);
    u16*   attnh = (u16*)alloc(NE * 2);
    u16*   attnl = (u16*)alloc(NE * 2);

    const u16* Qh_g = QKVh;
    const u16* Kh_g = QKVh + NE;
    const u16* Vh_g = QKVh + 2 * NE;

    dim3 blk(256);
    cast_bf16<<<dim3(2048), blk, 0, stream>>>(X, Xh, (int)(NE / 8));
    wT_bf16<<<dim3(16, 16, 4), blk, 0, stream>>>(Wq, Wk, Wv, Wo, WTh);
    gemm_mfma<1><<<dim3(32, 24), blk, 0, stream>>>(Xh, nullptr, WTh, bq, bk, bv,
                                                   nullptr, QKVh, 1);
    knorm_kn<<<dim3(256), blk, 0, stream>>>(Kh_g, Kn);
    gather_vT<<<dim3(8, BH_), blk, 0, stream>>>(Vh_g, VdT);
    qgfd_mfma<<<dim3(8, BH_), blk, 0, stream>>>(Kn, VdT, WhT);
    attn_mfma<<<dim3(8, BH_), blk, 0, stream>>>(Qh_g, Kh_g, WhT, attnh, attnl);
    gemm_mfma<2><<<dim3(32, 8), blk, 0, stream>>>(attnh, attnl,
                                                  WTh + ((size_t)3 << 20),
                                                  bo, bo, bo, out, nullptr, 0);
}

// Round 8
// 140.127 us; speedup vs baseline: 9.4574x; 1.0627x over previous
//
#include <hip/hip_runtime.h>
#include <stdint.h>

#define B_ 8
#define L_ 512
#define D_ 1024
#define H_ 16
#define HD_ 64
#define BH_ (B_*H_)      // 128
#define NR_ (B_*L_)      // 4096 rows
#define ALPHA_ 0.02f
#define PSTR 72          // padded LDS stride for per-lane-written P/E tiles

typedef unsigned int u32;
typedef unsigned short u16;
typedef __attribute__((ext_vector_type(8))) short bf16x8;
typedef __attribute__((ext_vector_type(4))) float f32x4;

#define MFMA16(a, b, c) __builtin_amdgcn_mfma_f32_16x16x32_bf16((a), (b), (c), 0, 0, 0)

__device__ __forceinline__ u32 f2bf_rne(float f) {
    u32 x = __float_as_uint(f);
    return (x + 0x7fffu + ((x >> 16) & 1u)) >> 16;
}
__device__ __forceinline__ float bf_lo(u32 u) { return __uint_as_float(u << 16); }
__device__ __forceinline__ float bf_hi(u32 u) { return __uint_as_float(u & 0xffff0000u); }

__device__ __forceinline__ void pack4_store(float4 v, u16* p) {
    uint2 u;
    u.x = f2bf_rne(v.x) | (f2bf_rne(v.y) << 16);
    u.y = f2bf_rne(v.z) | (f2bf_rne(v.w) << 16);
    *(uint2*)p = u;
}

// global->LDS DMA, 16B/lane; LDS dest = wave-uniform base + lane*16 (linear).
__device__ __forceinline__ void gl_lds16(const u16* g, u16* l) {
    auto gp = reinterpret_cast<const __attribute__((address_space(1))) void*>(
        reinterpret_cast<uintptr_t>(g));
    auto lp = reinterpret_cast<__attribute__((address_space(3))) void*>(
        reinterpret_cast<uintptr_t>(l));
    __builtin_amdgcn_global_load_lds(gp, lp, 16, 0, 0);
}

// XOR-swizzle (T2 / rule #21): linear LDS [rows][64 u16]; 16B-unit index within
// each row permuted by unit ^= (row & 7); staging pre-swizzles the per-lane
// GLOBAL source, reads apply the same XOR (involution => exact).
__device__ __forceinline__ void stage8_swz(const u16* g, size_t gpitch, u16* lds, int lane) {
    const int lrow = lane >> 3;              // 0..7 == row&7 (chunks 8-aligned)
    const int su = (lane & 7) ^ lrow;        // swizzled source 16B-unit
    gl_lds16(&g[(size_t)lrow * gpitch + su * 8], lds);
}

// ---------------------------------------------------------------------------
// X (fp32) -> bf16 (hi only)
// ---------------------------------------------------------------------------
__global__ __launch_bounds__(256) void cast_bf16(
    const float* __restrict__ src, u16* __restrict__ dst, int n8)
{
    int i = blockIdx.x * 256 + threadIdx.x;
    if (i < n8) {
        float4 a = ((const float4*)src)[(size_t)i * 2];
        float4 b = ((const float4*)src)[(size_t)i * 2 + 1];
        uint4 o;
        o.x = f2bf_rne(a.x) | (f2bf_rne(a.y) << 16);
        o.y = f2bf_rne(a.z) | (f2bf_rne(a.w) << 16);
        o.z = f2bf_rne(b.x) | (f2bf_rne(b.y) << 16);
        o.w = f2bf_rne(b.z) | (f2bf_rne(b.w) << 16);
        ((uint4*)dst)[i] = o;
    }
}

// ---------------------------------------------------------------------------
// W[k][n] fp32 -> WTh[w][n][k] bf16 (transposed, hi only). grid (16,16,4)
// ---------------------------------------------------------------------------
__global__ __launch_bounds__(256) void wT_bf16(
    const float* __restrict__ W0, const float* __restrict__ W1,
    const float* __restrict__ W2, const float* __restrict__ W3,
    u16* __restrict__ WTh)
{
    __shared__ float Ws[64][65];
    const int wsel = blockIdx.z;
    const float* W = (wsel == 0) ? W0 : (wsel == 1) ? W1 : (wsel == 2) ? W2 : W3;
    const int k0 = blockIdx.x * 64, n0 = blockIdx.y * 64;
    const int t = threadIdx.x;
    {
        const int r = t >> 2, c0 = (t & 3) << 4;
        #pragma unroll
        for (int i = 0; i < 4; ++i)
            *(float4*)&Ws[r][c0 + i * 4] = *(const float4*)&W[(size_t)(k0 + r) * 1024 + n0 + c0 + i * 4];
    }
    __syncthreads();
    {
        const int n = t >> 2, kc0 = (t & 3) << 4;
        size_t base = ((size_t)wsel << 20) + (size_t)(n0 + n) * 1024 + k0 + kc0;
        #pragma unroll
        for (int j = 0; j < 4; ++j) {
            float4 v;
            v.x = Ws[kc0 + j * 4 + 0][n]; v.y = Ws[kc0 + j * 4 + 1][n];
            v.z = Ws[kc0 + j * 4 + 2][n]; v.w = Ws[kc0 + j * 4 + 3][n];
            pack4_store(v, &WTh[base + j * 4]);
        }
    }
}

// ---------------------------------------------------------------------------
// MFMA GEMM, swizzled global_load_lds staging, linear LDS [128][64].
// TERMS=1: C = Ah@B^T'. TERMS=2: C = (Ah+Al)@B^T'.
// qkv_mode=1 (TERMS=1): fused QKV epilogue --
//   which 0 (Q): bf16 -> Ch[0 .. )
//   which 1 (K): bf16 Kh -> Ch[NE ..) AND Kn = bf16(K/max(||K_head||,eps))
//                (norm over the wave's 64-col head span, fp32 accs, shfl reduce)
//   which 2 (V): write VdT[bh][d][l] transposed directly (lane's 4 acc rows
//                are 4 consecutive l -> one uint2 store). No row-major V.
// qkv_mode=0: fp32 out + bias (out-projection).
// ---------------------------------------------------------------------------
template<int TERMS>
__global__ __launch_bounds__(256) void gemm_mfma(
    const u16* __restrict__ Ah, const u16* __restrict__ Al,
    const u16* __restrict__ WTh,
    const float* __restrict__ b0, const float* __restrict__ b1, const float* __restrict__ b2,
    float* __restrict__ Cf, u16* __restrict__ Ch,
    u16* __restrict__ Kn, u16* __restrict__ VdT, int qkv_mode)
{
    __shared__ u16 Ash[128 * 64];
    __shared__ u16 Als[TERMS == 2 ? 128 * 64 : 8];
    __shared__ u16 Bsh[128 * 64];
    const int bm = blockIdx.x;
    const int which = blockIdx.y >> 3;
    const int bn = blockIdx.y & 7;
    const float* bias = (which == 0) ? b0 : (which == 1) ? b1 : b2;
    const int t = threadIdx.x;
    const int w = t >> 6, lane = t & 63, l15 = lane & 15, g = lane >> 4;
    const int wr = w >> 1, wc = w & 1;
    const int row0 = bm * 128, col0 = bn * 128;
    const u16* Bg = WTh + ((size_t)which << 20);
    const int r7 = l15 & 7;

    f32x4 acc[4][4];
    #pragma unroll
    for (int i = 0; i < 4; ++i)
        #pragma unroll
        for (int j = 0; j < 4; ++j) acc[i][j] = (f32x4){0.f, 0.f, 0.f, 0.f};

    for (int kt = 0; kt < 1024; kt += 64) {
        __syncthreads();
        #pragma unroll
        for (int q = 0; q < 4; ++q) {
            const int rb = w * 32 + q * 8;
            stage8_swz(&Ah[(size_t)(row0 + rb) * 1024 + kt], 1024, &Ash[rb * 64], lane);
            if constexpr (TERMS == 2)
                stage8_swz(&Al[(size_t)(row0 + rb) * 1024 + kt], 1024, &Als[rb * 64], lane);
            stage8_swz(&Bg[(size_t)(col0 + rb) * 1024 + kt], 1024, &Bsh[rb * 64], lane);
        }
        __syncthreads();
        #pragma unroll
        for (int c = 0; c < 2; ++c) {
            const int uo = ((c * 4 + g) ^ r7) * 8;
            bf16x8 ah[4], al[4], bh[4];
            #pragma unroll
            for (int mf = 0; mf < 4; ++mf) {
                const int ro = (wr * 64 + mf * 16 + l15) * 64 + uo;
                ah[mf] = *(const bf16x8*)&Ash[ro];
                if constexpr (TERMS == 2) al[mf] = *(const bf16x8*)&Als[ro];
            }
            #pragma unroll
            for (int nf = 0; nf < 4; ++nf)
                bh[nf] = *(const bf16x8*)&Bsh[(wc * 64 + nf * 16 + l15) * 64 + uo];
            #pragma unroll
            for (int mf = 0; mf < 4; ++mf)
                #pragma unroll
                for (int nf = 0; nf < 4; ++nf) {
                    acc[mf][nf] = MFMA16(ah[mf], bh[nf], acc[mf][nf]);
                    if constexpr (TERMS == 2)
                        acc[mf][nf] = MFMA16(al[mf], bh[nf], acc[mf][nf]);
                }
        }
    }

    if (!qkv_mode) {
        #pragma unroll
        for (int mf = 0; mf < 4; ++mf)
            #pragma unroll
            for (int nf = 0; nf < 4; ++nf) {
                const int n = col0 + wc * 64 + nf * 16 + l15;
                const float bv = bias[n];
                #pragma unroll
                for (int r = 0; r < 4; ++r) {
                    const int m = row0 + wr * 64 + mf * 16 + g * 4 + r;
                    Cf[(size_t)m * 1024 + n] = acc[mf][nf][r] + bv;
                }
            }
        return;
    }
    if (which == 0) {               // Q: plain bf16
        #pragma unroll
        for (int mf = 0; mf < 4; ++mf)
            #pragma unroll
            for (int nf = 0; nf < 4; ++nf) {
                const int n = col0 + wc * 64 + nf * 16 + l15;
                const float bv = bias[n];
                #pragma unroll
                for (int r = 0; r < 4; ++r) {
                    const int m = row0 + wr * 64 + mf * 16 + g * 4 + r;
                    Ch[(size_t)m * 1024 + n] = (u16)f2bf_rne(acc[mf][nf][r] + bv);
                }
            }
    } else if (which == 1) {        // K: Kh + Kn (row-norm over head span)
        #pragma unroll
        for (int mf = 0; mf < 4; ++mf) {
            float v[4][4];          // [nf][r]
            float sq[4] = {0.f, 0.f, 0.f, 0.f};
            #pragma unroll
            for (int nf = 0; nf < 4; ++nf) {
                const int n = col0 + wc * 64 + nf * 16 + l15;
                const float bv = bias[n];
                #pragma unroll
                for (int r = 0; r < 4; ++r) {
                    v[nf][r] = acc[mf][nf][r] + bv;
                    sq[r] += v[nf][r] * v[nf][r];
                }
            }
            #pragma unroll
            for (int r = 0; r < 4; ++r) {
                sq[r] += __shfl_xor(sq[r], 1);
                sq[r] += __shfl_xor(sq[r], 2);
                sq[r] += __shfl_xor(sq[r], 4);
                sq[r] += __shfl_xor(sq[r], 8);
            }
            float rn[4];
            #pragma unroll
            for (int r = 0; r < 4; ++r)
                rn[r] = 1.f / fmaxf(sqrtf(sq[r]), 1e-6f);
            #pragma unroll
            for (int nf = 0; nf < 4; ++nf) {
                const int n = col0 + wc * 64 + nf * 16 + l15;
                #pragma unroll
                for (int r = 0; r < 4; ++r) {
                    const int m = row0 + wr * 64 + mf * 16 + g * 4 + r;
                    Ch[((size_t)1 << 22) + (size_t)m * 1024 + n] = (u16)f2bf_rne(v[nf][r]);
                    Kn[(size_t)m * 1024 + n] = (u16)f2bf_rne(v[nf][r] * rn[r]);
                }
            }
        }
    } else {                        // V: transposed per-head store
        #pragma unroll
        for (int mf = 0; mf < 4; ++mf) {
            const int m0 = row0 + wr * 64 + mf * 16 + g * 4;
            const int bb = m0 >> 9, l0v = m0 & 511;
            #pragma unroll
            for (int nf = 0; nf < 4; ++nf) {
                const int n = col0 + wc * 64 + nf * 16 + l15;
                const float bv = bias[n];
                const int hh = n >> 6, dd = n & 63;
                const size_t idx = (((size_t)(bb * 16 + hh) * 64 + dd) * 512) + l0v;
                uint2 u;
                u.x = f2bf_rne(acc[mf][nf][0] + bv) | (f2bf_rne(acc[mf][nf][1] + bv) << 16);
                u.y = f2bf_rne(acc[mf][nf][2] + bv) | (f2bf_rne(acc[mf][nf][3] + bv) << 16);
                *(uint2*)&VdT[idx] = u;
            }
        }
    }
}

// ---------------------------------------------------------------------------
// Fused QGFD: WhT = bf16( (1-a) V^T + a * Dinv.(E @ V)^T ) per head,
// E = exp(cos-sim/8) computed on the fly (flash-style, no P materialized).
// W = (1-a)V + a(1-a)PV + a^2 P^2 V;  P^2V-PV = (P-I)delta ~1e-3 => a^2-term
// folds into a*PV with ~1e-6 error (P rows sum to 1 exactly).
// Scores bounded in [-1/8,1/8] -> no running max. grid (8 rtiles, 128 bh).
// ---------------------------------------------------------------------------
__global__ __launch_bounds__(256) void qgfd_mfma(
    const u16* __restrict__ Kn_g, const u16* __restrict__ VdT,
    u16* __restrict__ WhT)
{
    __shared__ u16 Rs[64 * 64];            // Kn rows r0.. (B operand)
    __shared__ u16 Js[64 * 64];            // Kn rows jt.. (A operand)
    __shared__ u16 Vs[64 * 64];            // VdT tile [64 d][64 j]
    __shared__ u16 Eh[4][16 * PSTR];       // per-wave E relay (C->A layout)
    const int bh = blockIdx.y, b = bh >> 4, h = bh & 15;
    const int r0 = blockIdx.x * 64;
    const int t = threadIdx.x;
    const int w = t >> 6, lane = t & 63, l15 = lane & 15, g = lane >> 4;
    const int r7 = l15 & 7;

    #pragma unroll
    for (int q = 0; q < 2; ++q) {
        const int rb = w * 16 + q * 8;
        stage8_swz(&Kn_g[((size_t)(b * 512 + r0 + rb)) * 1024 + h * 64], 1024,
                   &Rs[rb * 64], lane);
    }
    __syncthreads();
    bf16x8 rbf[2];
    rbf[0] = *(const bf16x8*)&Rs[(w * 16 + l15) * 64 + ((g ^ r7) * 8)];
    rbf[1] = *(const bf16x8*)&Rs[(w * 16 + l15) * 64 + (((4 + g) ^ r7) * 8)];

    float rsum = 0.f;
    f32x4 O[4] = {{0,0,0,0},{0,0,0,0},{0,0,0,0},{0,0,0,0}};

    for (int jt = 0; jt < 512; jt += 64) {
        __syncthreads();
        #pragma unroll
        for (int q = 0; q < 2; ++q) {
            const int rb = w * 16 + q * 8;
            stage8_swz(&Kn_g[((size_t)(b * 512 + jt + rb)) * 1024 + h * 64], 1024,
                       &Js[rb * 64], lane);
            stage8_swz(&VdT[((size_t)(bh * 64 + rb)) * 512 + jt], 512,
                       &Vs[rb * 64], lane);
        }
        __syncthreads();
        // E^T tiles: rows j, cols r (lane l15 = r)
        #pragma unroll
        for (int tk = 0; tk < 4; ++tk) {
            f32x4 a = {0.f, 0.f, 0.f, 0.f};
            #pragma unroll
            for (int c = 0; c < 2; ++c) {
                bf16x8 ka = *(const bf16x8*)&Js[(tk * 16 + l15) * 64 + (((c * 4 + g) ^ r7) * 8)];
                a = MFMA16(ka, rbf[c], a);
            }
            const float e0 = __expf(a[0] * 0.125f);
            const float e1 = __expf(a[1] * 0.125f);
            const float e2 = __expf(a[2] * 0.125f);
            const float e3 = __expf(a[3] * 0.125f);
            rsum += e0 + e1 + e2 + e3;
            uint2 u;
            u.x = f2bf_rne(e0) | (f2bf_rne(e1) << 16);
            u.y = f2bf_rne(e2) | (f2bf_rne(e3) << 16);
            *(uint2*)&Eh[w][l15 * PSTR + tk * 16 + g * 4] = u;   // E[r-local][j]
        }
        // O += E_tile @ V_tile
        bf16x8 pah[2];
        pah[0] = *(const bf16x8*)&Eh[w][l15 * PSTR + 8 * g];
        pah[1] = *(const bf16x8*)&Eh[w][l15 * PSTR + 32 + 8 * g];
        #pragma unroll
        for (int td = 0; td < 4; ++td) {
            #pragma unroll
            for (int c = 0; c < 2; ++c) {
                bf16x8 vb = *(const bf16x8*)&Vs[(td * 16 + l15) * 64 + (((c * 4 + g) ^ r7) * 8)];
                O[td] = MFMA16(pah[c], vb, O[td]);
            }
        }
    }
    rsum += __shfl_xor(rsum, 16);
    rsum += __shfl_xor(rsum, 32);
    const float dinv = (1.0f - 1e-6f) / rsum;
    float dv[4];
    #pragma unroll
    for (int r = 0; r < 4; ++r) dv[r] = __shfl(dinv, g * 4 + r) * ALPHA_;
    #pragma unroll
    for (int td = 0; td < 4; ++td) {
        const int d = td * 16 + l15;
        const size_t idx = ((size_t)bh * 64 + d) * 512 + r0 + w * 16 + g * 4;
        uint2 vv = *(const uint2*)&VdT[idx];
        uint2 wu;
        wu.x = f2bf_rne((1.0f - ALPHA_) * bf_lo(vv.x) + dv[0] * O[td][0])
             | (f2bf_rne((1.0f - ALPHA_) * bf_hi(vv.x) + dv[1] * O[td][1]) << 16);
        wu.y = f2bf_rne((1.0f - ALPHA_) * bf_lo(vv.y) + dv[2] * O[td][2])
             | (f2bf_rne((1.0f - ALPHA_) * bf_hi(vv.y) + dv[3] * O[td][3]) << 16);
        *(uint2*)&WhT[idx] = wu;
    }
}

// ---------------------------------------------------------------------------
// attn = softmax(QK^T/8) @ W, flash-style. QK x1, PV x1 (Ph only; error
// budget: dP ~2.2e-3 rel * sqrt(sum P^2)~0.05 * |W| -> ~2.5e-4 on out, ok).
// Q/K/W tiles: swizzled gl_lds, linear [64][64] LDS.
// ---------------------------------------------------------------------------
__global__ __launch_bounds__(256) void attn_mfma(
    const u16* __restrict__ Qh_g, const u16* __restrict__ Kh_g,
    const u16* __restrict__ Wh_g,
    u16* __restrict__ attnh, u16* __restrict__ attnl)
{
    __shared__ u16 Qs[64 * 64];
    __shared__ u16 Ks[64 * 64];
    __shared__ u16 Wsh[64 * 64];
    __shared__ u16 Ph[4][16 * PSTR];
    const int bh = blockIdx.y, b = bh >> 4, h = bh & 15;
    const int q0 = blockIdx.x * 64;
    const int t = threadIdx.x;
    const int w = t >> 6, lane = t & 63, l15 = lane & 15, g = lane >> 4;
    const int r7 = l15 & 7;

    #pragma unroll
    for (int q = 0; q < 2; ++q) {
        const int rb = w * 16 + q * 8;
        stage8_swz(&Qh_g[((size_t)(b * 512 + q0 + rb)) * 1024 + h * 64], 1024,
                   &Qs[rb * 64], lane);
    }
    __syncthreads();
    bf16x8 qbh[2];
    qbh[0] = *(const bf16x8*)&Qs[(w * 16 + l15) * 64 + ((g ^ r7) * 8)];
    qbh[1] = *(const bf16x8*)&Qs[(w * 16 + l15) * 64 + (((4 + g) ^ r7) * 8)];

    float m_run = -1e30f, l_run = 0.f;
    f32x4 O[4] = {{0,0,0,0},{0,0,0,0},{0,0,0,0},{0,0,0,0}};

    for (int kt = 0; kt < 512; kt += 64) {
        __syncthreads();
        #pragma unroll
        for (int q = 0; q < 2; ++q) {
            const int rb = w * 16 + q * 8;
            stage8_swz(&Kh_g[((size_t)(b * 512 + kt + rb)) * 1024 + h * 64], 1024,
                       &Ks[rb * 64], lane);
            stage8_swz(&Wh_g[((size_t)(bh * 64 + rb)) * 512 + kt], 512,
                       &Wsh[rb * 64], lane);
        }
        __syncthreads();
        f32x4 st[4];
        #pragma unroll
        for (int tk = 0; tk < 4; ++tk) {
            f32x4 a = {0.f, 0.f, 0.f, 0.f};
            #pragma unroll
            for (int c = 0; c < 2; ++c) {
                bf16x8 kah = *(const bf16x8*)&Ks[(tk * 16 + l15) * 64 + (((c * 4 + g) ^ r7) * 8)];
                a = MFMA16(kah, qbh[c], a);
            }
            st[tk] = a;
        }
        float mt = st[0][0];
        #pragma unroll
        for (int tk = 0; tk < 4; ++tk)
            #pragma unroll
            for (int r = 0; r < 4; ++r) mt = fmaxf(mt, st[tk][r]);
        mt = fmaxf(mt, __shfl_xor(mt, 16));
        mt = fmaxf(mt, __shfl_xor(mt, 32));
        const float m_new = fmaxf(m_run, mt);
        const float scale = __expf((m_run - m_new) * 0.125f);
        float rsum = 0.f;
        #pragma unroll
        for (int tk = 0; tk < 4; ++tk) {
            float p0_ = __expf((st[tk][0] - m_new) * 0.125f);
            float p1_ = __expf((st[tk][1] - m_new) * 0.125f);
            float p2_ = __expf((st[tk][2] - m_new) * 0.125f);
            float p3_ = __expf((st[tk][3] - m_new) * 0.125f);
            rsum += p0_ + p1_ + p2_ + p3_;
            uint2 hw;
            hw.x = f2bf_rne(p0_) | (f2bf_rne(p1_) << 16);
            hw.y = f2bf_rne(p2_) | (f2bf_rne(p3_) << 16);
            *(uint2*)&Ph[w][l15 * PSTR + tk * 16 + g * 4] = hw;
        }
        rsum += __shfl_xor(rsum, 16);
        rsum += __shfl_xor(rsum, 32);
        l_run = l_run * scale + rsum;
        m_run = m_new;
        float sc[4];
        #pragma unroll
        for (int r = 0; r < 4; ++r) sc[r] = __shfl(scale, g * 4 + r);
        #pragma unroll
        for (int td = 0; td < 4; ++td)
            #pragma unroll
            for (int r = 0; r < 4; ++r) O[td][r] *= sc[r];
        bf16x8 pah[2];
        pah[0] = *(const bf16x8*)&Ph[w][l15 * PSTR + 8 * g];
        pah[1] = *(const bf16x8*)&Ph[w][l15 * PSTR + 32 + 8 * g];
        #pragma unroll
        for (int td = 0; td < 4; ++td) {
            #pragma unroll
            for (int c = 0; c < 2; ++c) {
                bf16x8 wbh = *(const bf16x8*)&Wsh[(td * 16 + l15) * 64 + (((c * 4 + g) ^ r7) * 8)];
                O[td] = MFMA16(pah[c], wbh, O[td]);
            }
        }
    }
    const float linv = 1.f / l_run;
    float li[4];
    #pragma unroll
    for (int r = 0; r < 4; ++r) li[r] = __shfl(linv, g * 4 + r);
    #pragma unroll
    for (int td = 0; td < 4; ++td)
        #pragma unroll
        for (int r = 0; r < 4; ++r) {
            const float v = O[td][r] * li[r];
            const size_t idx = ((size_t)(b * 512 + q0 + w * 16 + g * 4 + r)) * 1024
                             + h * 64 + td * 16 + l15;
            const u32 hh = f2bf_rne(v);
            attnh[idx] = (u16)hh;
            attnl[idx] = (u16)f2bf_rne(v - bf_lo(hh));
        }
}

// ---------------------------------------------------------------------------
extern "C" void kernel_launch(void* const* d_in, const int* in_sizes, int n_in,
                              void* d_out, int out_size, void* d_ws, size_t ws_size,
                              hipStream_t stream) {
    const float* X  = (const float*)d_in[0];
    const float* Wq = (const float*)d_in[1];
    const float* bq = (const float*)d_in[2];
    const float* Wk = (const float*)d_in[3];
    const float* bk = (const float*)d_in[4];
    const float* Wv = (const float*)d_in[5];
    const float* bv = (const float*)d_in[6];
    const float* Wo = (const float*)d_in[7];
    const float* bo = (const float*)d_in[8];
    float* out = (float*)d_out;

    char* ws = (char*)d_ws;
    size_t off = 0;
    auto alloc = [&](size_t bytes) -> void* {
        void* p = ws + off;
        off += (bytes + 255) & ~(size_t)255;
        return p;
    };
    const size_t NE = (size_t)NR_ * D_;               // 4,194,304
    const size_t HE = (size_t)BH_ * 64 * 512;         // 4,194,304
    u16*   Xh    = (u16*)alloc(NE * 2);
    u16*   WTh   = (u16*)alloc((size_t)4 * 1024 * 1024 * 2);
    u16*   QKh   = (u16*)alloc(2 * NE * 2);           // [Q|K][4096][1024]
    u16*   Kn    = (u16*)alloc(NE * 2);
    u16*   VdT   = (u16*)alloc(HE * 2);
    u16*   WhT   = (u16*)alloc(HE * 2);
    u16*   attnh = (u16*)alloc(NE * 2);
    u16*   attnl = (u16*)alloc(NE * 2);

    const u16* Qh_g = QKh;
    const u16* Kh_g = QKh + NE;

    dim3 blk(256);
    cast_bf16<<<dim3(2048), blk, 0, stream>>>(X, Xh, (int)(NE / 8));
    wT_bf16<<<dim3(16, 16, 4), blk, 0, stream>>>(Wq, Wk, Wv, Wo, WTh);
    gemm_mfma<1><<<dim3(32, 24), blk, 0, stream>>>(Xh, nullptr, WTh, bq, bk, bv,
                                                   nullptr, QKh, Kn, VdT, 1);
    qgfd_mfma<<<dim3(8, BH_), blk, 0, stream>>>(Kn, VdT, WhT);
    attn_mfma<<<dim3(8, BH_), blk, 0, stream>>>(Qh_g, Kh_g, WhT, attnh, attnl);
    gemm_mfma<2><<<dim3(32, 8), blk, 0, stream>>>(attnh, attnl,
                                                  WTh + ((size_t)3 << 20),
                                                  bo, bo, bo, out, nullptr,
                                                  nullptr, nullptr, 0);
}